// Round 22
// baseline (924.439 us; speedup 1.0000x reference)
//
#include <hip/hip_runtime.h>

#define N 256
#define NN 65536
#define EMB 64
#define BATCH 8
#define NEDGE 32768

typedef unsigned short u16;
typedef unsigned int u32t;
typedef __attribute__((ext_vector_type(8))) short bf16x8;
typedef __attribute__((ext_vector_type(4))) float f32x4;

#define TSTR 72    // LDS act tile row stride in u16 (144 B) — f2 bands only

// pre-split weight buffer offsets (u16 elements)
#define RB0_W2A 0
#define RB0_W2B 4096
#define RB0_SW  8192
#define REG_BASE 12288
#define REG_STRIDE 24576   // per regular block: W1A,W2A,W1B,W2B (4096 each) + SW (8192)
#define WSPLIT_ELEMS 86016

static __device__ __forceinline__ u16 f2bs(float f) {
    u32t u = __float_as_uint(f);
    u32t r = (u + 0x7FFFu + ((u >> 16) & 1u)) >> 16;
    return (u16)r;
}
static __device__ __forceinline__ float b2f(u16 s) {
    return __uint_as_float(((u32t)s) << 16);
}
static __device__ __forceinline__ void split_bf(float a, u16& hi, u16& lo) {
    hi = f2bs(a);
    float r = a - b2f(hi);
    lo = f2bs(r);
}

// ---------------- adjacency scatter ----------------
__global__ void scatter_adj(const int* __restrict__ ei, const int* __restrict__ batch,
                            float* __restrict__ adj) {
    int e = blockIdx.x * blockDim.x + threadIdx.x;
    if (e >= NEDGE) return;
    int src = ei[e];
    int dst = ei[NEDGE + e];
    int g = batch[src];
    int lu = src - g * N;
    int lv = dst - g * N;
    atomicAdd(&adj[(size_t)g * NN + (size_t)lu * N + lv], 1.0f);
}

// ---------------- one-time weight pre-split ----------------
__global__ void prep_w(const float* __restrict__ rb0_m1w2, const float* __restrict__ rb0_m2w2,
                       const float* __restrict__ rb0_sw,
                       const float* __restrict__ rb_m1w1, const float* __restrict__ rb_m1w2,
                       const float* __restrict__ rb_m2w1, const float* __restrict__ rb_m2w2,
                       const float* __restrict__ rb_sw,
                       u16* __restrict__ wh, u16* __restrict__ wl) {
    int idx = blockIdx.x * 256 + threadIdx.x;
    if (idx >= WSPLIT_ELEMS) return;
    float v;
    if (idx < 4096) v = rb0_m1w2[idx];
    else if (idx < 8192) v = rb0_m2w2[idx - 4096];
    else if (idx < 12288) { int e = idx - 8192; v = rb0_sw[(e >> 6) * 66 + 2 + (e & 63)]; }
    else {
        int e = idx - REG_BASE;
        int blk = e / REG_STRIDE, r = e % REG_STRIDE;
        if (r < 4096) v = rb_m1w1[blk * 4096 + r];
        else if (r < 8192) v = rb_m1w2[blk * 4096 + r - 4096];
        else if (r < 12288) v = rb_m2w1[blk * 4096 + r - 8192];
        else if (r < 16384) v = rb_m2w2[blk * 4096 + r - 12288];
        else v = rb_sw[blk * 8192 + r - 16384];
    }
    u16 h, l;
    split_bf(v, h, l);
    wh[idx] = h; wl[idx] = l;
}

// ================= engine building blocks =================

__device__ __forceinline__ void stage_w64(const u16* __restrict__ Wh, const u16* __restrict__ Wl,
                                          u16* dh, u16* dl, int t) {
#pragma unroll
    for (int it = 0; it < 2; ++it) {
        int idx = it * 256 + t;
        int row = idx >> 3, g = idx & 7;
        int4 vh = *(const int4*)&Wh[row * 64 + g * 8];
        int4 vl = *(const int4*)&Wl[row * 64 + g * 8];
        int d = row * 64 + ((g ^ (row & 7)) << 3);
        *(int4*)&dh[d] = vh;
        *(int4*)&dl[d] = vl;
    }
}
__device__ __forceinline__ void stage_w128s(const u16* __restrict__ Wh, const u16* __restrict__ Wl,
                                            u16* dh, u16* dl, int t) {
#pragma unroll
    for (int it = 0; it < 4; ++it) {
        int idx = it * 256 + t;
        int row = idx >> 4, g = idx & 15;
        int4 vh = *(const int4*)&Wh[row * 128 + g * 8];
        int4 vl = *(const int4*)&Wl[row * 128 + g * 8];
        int d = row * 128 + ((g ^ (row & 7)) << 3);
        *(int4*)&dh[d] = vh;
        *(int4*)&dl[d] = vl;
    }
}
__device__ __forceinline__ bf16x8 wfrag64(const u16* w, int row, int k0) {
    int g = k0 >> 3;
    return *(const bf16x8*)&w[row * 64 + ((g ^ (row & 7)) << 3)];
}
__device__ __forceinline__ bf16x8 wfrag128(const u16* w, int row, int k0) {
    int g = k0 >> 3;
    return *(const bf16x8*)&w[row * 128 + ((g ^ (row & 7)) << 3)];
}

// cooperative: stage 64px x 64c act tile from NCHW fp32 -> [px][c] hi/lo (f2_rb0 only)
__device__ __forceinline__ void stage_act_nchw(const float* __restrict__ src, int p0,
                                               u16* ah, u16* al, int t) {
#pragma unroll
    for (int it = 0; it < 8; ++it) {
        int idx = it * 256 + t;
        int px = idx & 63;
        int c0 = (idx >> 6) * 2;
        float v0 = src[(size_t)c0 * NN + p0 + px];
        float v1 = src[(size_t)(c0 + 1) * NN + p0 + px];
        u16 h0, l0, h1, l1;
        split_bf(v0, h0, l0); split_bf(v1, h1, l1);
        *(u32t*)&ah[px * TSTR + c0] = (u32t)h0 | ((u32t)h1 << 16);
        *(u32t*)&al[px * TSTR + c0] = (u32t)l0 | ((u32t)l1 << 16);
    }
}
// wave-local: stage this wave's 16-px band from NCHW fp32 into [px][c] hi/lo
__device__ __forceinline__ void stage_band_nchw(const float* __restrict__ src, int p0,
                                                u16* ah, u16* al, int wband, int lane) {
    int q = lane >> 4, l15 = lane & 15;
    int px = wband * 16 + l15;
    int gpx = p0 + px;
#pragma unroll
    for (int it = 0; it < 8; ++it) {
        int c0 = it * 8 + q * 2;
        float v0 = src[(size_t)c0 * NN + gpx];
        float v1 = src[(size_t)(c0 + 1) * NN + gpx];
        u16 h0, l0, h1, l1;
        split_bf(v0, h0, l0); split_bf(v1, h1, l1);
        *(u32t*)&ah[px * TSTR + c0] = (u32t)h0 | ((u32t)h1 << 16);
        *(u32t*)&al[px * TSTR + c0] = (u32t)l0 | ((u32t)l1 << 16);
    }
}

// build this lane's z fragments (hi/lo) directly from NCHW fp32 global
__device__ __forceinline__ void zfrags_nchw(const float* __restrict__ zp, int px,
                                            int q, bf16x8 zfh[2], bf16x8 zfl[2]) {
#pragma unroll
    for (int ks = 0; ks < 2; ++ks)
#pragma unroll
        for (int j = 0; j < 8; ++j) {
            float v = zp[(size_t)(ks * 32 + q * 8 + j) * NN + px];
            u16 h, l; split_bf(v, h, l);
            zfh[ks][j] = (short)h;
            zfl[ks][j] = (short)l;
        }
}

__device__ __forceinline__ void init_bias(const float* __restrict__ Bb, f32x4* acc, int lane) {
    int q = lane >> 4;
#pragma unroll
    for (int ot = 0; ot < 4; ++ot)
#pragma unroll
        for (int j = 0; j < 4; ++j)
            acc[ot][j] = Bb[ot * 16 + q * 4 + j];
}

// f1 L1 (3-term: z split exact, W split): D[o][px] += W[o][k] * z[px][k]
__device__ __forceinline__ void mfma_L1_64(bf16x8 zfh[2], bf16x8 zfl[2],
                                           const u16* wh, const u16* wl,
                                           f32x4* acc, int lane) {
    int q = lane >> 4, l = lane & 15;
#pragma unroll
    for (int ks = 0; ks < 2; ++ks) {
        int k0 = ks * 32 + q * 8;
#pragma unroll
        for (int ot = 0; ot < 4; ++ot) {
            bf16x8 ahi = wfrag64(wh, ot * 16 + l, k0);
            bf16x8 alo = wfrag64(wl, ot * 16 + l, k0);
            acc[ot] = __builtin_amdgcn_mfma_f32_16x16x32_bf16(ahi, zfh[ks], acc[ot], 0, 0, 0);
            acc[ot] = __builtin_amdgcn_mfma_f32_16x16x32_bf16(ahi, zfl[ks], acc[ot], 0, 0, 0);
            acc[ot] = __builtin_amdgcn_mfma_f32_16x16x32_bf16(alo, zfh[ks], acc[ot], 0, 0, 0);
        }
    }
}
// f2 L1, W split (3-term), K-half of [64][128]
__device__ __forceinline__ void mfma_L1_128(bf16x8 zfh[2], bf16x8 zfl[2],
                                            const u16* wh, const u16* wl, int ak0,
                                            f32x4* acc, int lane) {
    int q = lane >> 4, l = lane & 15;
#pragma unroll
    for (int ks = 0; ks < 2; ++ks) {
        int k0 = ks * 32 + q * 8;
#pragma unroll
        for (int ot = 0; ot < 4; ++ot) {
            bf16x8 ahi = wfrag128(wh, ot * 16 + l, ak0 + k0);
            bf16x8 alo = wfrag128(wl, ot * 16 + l, ak0 + k0);
            acc[ot] = __builtin_amdgcn_mfma_f32_16x16x32_bf16(ahi, zfh[ks], acc[ot], 0, 0, 0);
            acc[ot] = __builtin_amdgcn_mfma_f32_16x16x32_bf16(ahi, zfl[ks], acc[ot], 0, 0, 0);
            acc[ot] = __builtin_amdgcn_mfma_f32_16x16x32_bf16(alo, zfh[ks], acc[ot], 0, 0, 0);
        }
    }
}

// f1 L2 (2-term: h bf16, W split): h read from SWIZZLED stride-64 hbuf
__device__ __forceinline__ void layer_h2(const u16* hbuf,
                                         const u16* wh, const u16* wl,
                                         f32x4* acc, int wv, int lane) {
    int q = lane >> 4, l = lane & 15;
#pragma unroll
    for (int ks = 0; ks < 2; ++ks) {
        int k0 = ks * 32 + q * 8;
        bf16x8 b = wfrag64(hbuf, wv * 16 + l, k0);
#pragma unroll
        for (int ot = 0; ot < 4; ++ot) {
            bf16x8 ahi = wfrag64(wh, ot * 16 + l, k0);
            bf16x8 alo = wfrag64(wl, ot * 16 + l, k0);
            acc[ot] = __builtin_amdgcn_mfma_f32_16x16x32_bf16(ahi, b, acc[ot], 0, 0, 0);
            acc[ot] = __builtin_amdgcn_mfma_f32_16x16x32_bf16(alo, b, acc[ot], 0, 0, 0);
        }
    }
}
// 3-term K-half variant (f2, act band split exact)
__device__ __forceinline__ void layer_half128(const u16* bh, const u16* bl,
                                              const u16* wh, const u16* wl, int ak0,
                                              f32x4* acc, int wv, int lane) {
    int q = lane >> 4, l = lane & 15;
#pragma unroll
    for (int ks = 0; ks < 2; ++ks) {
        int k0 = ks * 32 + q * 8;
        int boff = (wv * 16 + l) * TSTR + k0;
        bf16x8 bhi = *(const bf16x8*)&bh[boff];
        bf16x8 blo = *(const bf16x8*)&bl[boff];
#pragma unroll
        for (int ot = 0; ot < 4; ++ot) {
            bf16x8 ahi = wfrag128(wh, ot * 16 + l, ak0 + k0);
            bf16x8 alo = wfrag128(wl, ot * 16 + l, ak0 + k0);
            acc[ot] = __builtin_amdgcn_mfma_f32_16x16x32_bf16(ahi, bhi, acc[ot], 0, 0, 0);
            acc[ot] = __builtin_amdgcn_mfma_f32_16x16x32_bf16(ahi, blo, acc[ot], 0, 0, 0);
            acc[ot] = __builtin_amdgcn_mfma_f32_16x16x32_bf16(alo, bhi, acc[ot], 0, 0, 0);
        }
    }
}
// 3-term K=64 variant (f2_rb0, act band split exact)
__device__ __forceinline__ void layer_half64(const u16* bh, const u16* bl,
                                             const u16* wh, const u16* wl,
                                             f32x4* acc, int wv, int lane) {
    int q = lane >> 4, l = lane & 15;
#pragma unroll
    for (int ks = 0; ks < 2; ++ks) {
        int k0 = ks * 32 + q * 8;
        int boff = (wv * 16 + l) * TSTR + k0;
        bf16x8 bhi = *(const bf16x8*)&bh[boff];
        bf16x8 blo = *(const bf16x8*)&bl[boff];
#pragma unroll
        for (int ot = 0; ot < 4; ++ot) {
            bf16x8 ahi = wfrag64(wh, ot * 16 + l, k0);
            bf16x8 alo = wfrag64(wl, ot * 16 + l, k0);
            acc[ot] = __builtin_amdgcn_mfma_f32_16x16x32_bf16(ahi, bhi, acc[ot], 0, 0, 0);
            acc[ot] = __builtin_amdgcn_mfma_f32_16x16x32_bf16(ahi, blo, acc[ot], 0, 0, 0);
            acc[ot] = __builtin_amdgcn_mfma_f32_16x16x32_bf16(alo, bhi, acc[ot], 0, 0, 0);
        }
    }
}

// write h = relu(acc) as plain bf16 to SWIZZLED stride-64 own-band rows [px][o]
__device__ __forceinline__ void write_h_bf16(f32x4* acc, u16* hbuf, int wv, int lane) {
    int q = lane >> 4, l = lane & 15;
    int px = wv * 16 + l;
#pragma unroll
    for (int ot = 0; ot < 4; ++ot) {
#pragma unroll
        for (int jp = 0; jp < 2; ++jp) {
            int o = ot * 16 + q * 4 + jp * 2;
            int gaddr = px * 64 + (((o >> 3) ^ (px & 7)) << 3) + (o & 7);
            float v0 = acc[ot][jp * 2];     v0 = v0 > 0.f ? v0 : 0.f;
            float v1 = acc[ot][jp * 2 + 1]; v1 = v1 > 0.f ? v1 : 0.f;
            *(u32t*)&hbuf[gaddr] = (u32t)f2bs(v0) | ((u32t)f2bs(v1) << 16);
        }
    }
}

// store relu(acc) (D[o][px]) as plain bf16 to u16 NCHW plane set
__device__ __forceinline__ void write_m_bf16(f32x4* acc, u16* __restrict__ mh,
                                             int p0, int wv, int lane) {
    int q = lane >> 4, l = lane & 15;
    int px = p0 + wv * 16 + l;
#pragma unroll
    for (int ot = 0; ot < 4; ++ot)
#pragma unroll
        for (int j = 0; j < 4; ++j) {
            int o = ot * 16 + q * 4 + j;
            float v = acc[ot][j]; v = v > 0.f ? v : 0.f;
            mh[(size_t)o * NN + px] = f2bs(v);
        }
}

__device__ __forceinline__ void write_m_lin(f32x4* acc, float* __restrict__ mout,
                                            int p0, int wv, int lane) {
    int q = lane >> 4, l = lane & 15;
    int px = p0 + wv * 16 + l;
#pragma unroll
    for (int ot = 0; ot < 4; ++ot)
#pragma unroll
        for (int j = 0; j < 4; ++j) {
            int o = ot * 16 + q * 4 + j;
            mout[(size_t)o * NN + px] = acc[ot][j];
        }
}

// ---------------- f1 regular: z(NCHW fp32) -> m1,m2 (bf16 NCHW); 3 barriers; 40960 B LDS ----------------
__global__ __launch_bounds__(256, 4) void f1_reg(
    const float* __restrict__ z,
    const u16* __restrict__ wsh, const u16* __restrict__ wsl, int blk,
    const float* __restrict__ B1a, const float* __restrict__ B2a,
    const float* __restrict__ B1b, const float* __restrict__ B2b,
    u16* __restrict__ m1, u16* __restrict__ m2) {
    __shared__ u16 w1h[4096], w1l[4096], w2h[4096], w2l[4096];  // 32 KB
    __shared__ u16 hbuf[4096];                                  // 8 KB -> 40 KB total => 4 blocks/CU
    int bb = blockIdx.y, p0 = blockIdx.x * 64;
    int t = threadIdx.x, lane = t & 63, wv = t >> 6;
    int q = lane >> 4, l15 = lane & 15;
    size_t gofs = (size_t)bb * EMB * NN;
    const float* zp = z + gofs;
    const u16* Wbh = wsh + REG_BASE + blk * REG_STRIDE;
    const u16* Wbl = wsl + REG_BASE + blk * REG_STRIDE;

    bf16x8 zfh[2], zfl[2];
    zfrags_nchw(zp, p0 + wv * 16 + l15, q, zfh, zfl);

    stage_w64(Wbh, Wbl, w1h, w1l, t);               // W1A
    stage_w64(Wbh + 4096, Wbl + 4096, w2h, w2l, t); // W2A
    __syncthreads();

    f32x4 acc[4];
    // ---- branch A (barrier-free: h rows wave-local) ----
    init_bias(B1a, acc, lane);
    mfma_L1_64(zfh, zfl, w1h, w1l, acc, lane);
    write_h_bf16(acc, hbuf, wv, lane);
    init_bias(B2a, acc, lane);
    layer_h2(hbuf, w2h, w2l, acc, wv, lane);
    write_m_bf16(acc, m1 + gofs, p0, wv, lane);

    __syncthreads();
    stage_w64(Wbh + 8192, Wbl + 8192, w1h, w1l, t);    // W1B
    stage_w64(Wbh + 12288, Wbl + 12288, w2h, w2l, t);  // W2B
    __syncthreads();

    // ---- branch B ----
    init_bias(B1b, acc, lane);
    mfma_L1_64(zfh, zfl, w1h, w1l, acc, lane);
    write_h_bf16(acc, hbuf, wv, lane);
    init_bias(B2b, acc, lane);
    layer_h2(hbuf, w2h, w2l, acc, wv, lane);
    write_m_bf16(acc, m2 + gofs, p0, wv, lane);
}

// ---------------- f1 rb0: adj -> m1,m2 (bf16); 1 barrier ----------------
__global__ __launch_bounds__(256, 4) void f1_rb0(
    const float* __restrict__ adj, int b_base,
    const float* __restrict__ w1a, const float* __restrict__ b1a,
    const float* __restrict__ w1b, const float* __restrict__ b1b,
    const u16* __restrict__ wsh, const u16* __restrict__ wsl,
    const float* __restrict__ B2a, const float* __restrict__ B2b,
    u16* __restrict__ m1, u16* __restrict__ m2) {
    __shared__ u16 w1h[4096], w1l[4096], w2h[4096], w2l[4096];
    __shared__ u16 hbuf[4096];
    int bb = blockIdx.y, p0 = blockIdx.x * 64;
    int t = threadIdx.x, lane = t & 63, wv = t >> 6;
    int q = lane >> 4, l15 = lane & 15;
    size_t gofs = (size_t)bb * EMB * NN;
    int pxl = wv * 16 + l15;
    float a = adj[(size_t)(b_base + bb) * NN + p0 + pxl];

    stage_w64(wsh + RB0_W2A, wsl + RB0_W2A, w1h, w1l, t);
    stage_w64(wsh + RB0_W2B, wsl + RB0_W2B, w2h, w2l, t);
#pragma unroll
    for (int it = 0; it < 8; ++it) {
        int o0 = it * 8 + q * 2;
        int gaddr = pxl * 64 + ((it ^ (pxl & 7)) << 3) + q * 2;
        float v0 = w1a[o0 * 2] * a + b1a[o0];             v0 = v0 > 0.f ? v0 : 0.f;
        float v1 = w1a[(o0 + 1) * 2] * a + b1a[o0 + 1];   v1 = v1 > 0.f ? v1 : 0.f;
        *(u32t*)&hbuf[gaddr] = (u32t)f2bs(v0) | ((u32t)f2bs(v1) << 16);
    }
    __syncthreads();

    f32x4 acc[4];
    init_bias(B2a, acc, lane);
    layer_h2(hbuf, w1h, w1l, acc, wv, lane);
    write_m_bf16(acc, m1 + gofs, p0, wv, lane);

#pragma unroll
    for (int it = 0; it < 8; ++it) {
        int o0 = it * 8 + q * 2;
        int gaddr = pxl * 64 + ((it ^ (pxl & 7)) << 3) + q * 2;
        float v0 = w1b[o0 * 2] * a + b1b[o0];             v0 = v0 > 0.f ? v0 : 0.f;
        float v1 = w1b[(o0 + 1) * 2] * a + b1b[o0 + 1];   v1 = v1 > 0.f ? v1 : 0.f;
        *(u32t*)&hbuf[gaddr] = (u32t)f2bs(v0) | ((u32t)f2bs(v1) << 16);
    }
    init_bias(B2b, acc, lane);
    layer_h2(hbuf, w2h, w2l, acc, wv, lane);
    write_m_bf16(acc, m2 + gofs, p0, wv, lane);
}

// ---------------- per-channel NxN matmul, plain bf16 MFMA (unchanged) ----------------
__device__ __forceinline__ int soff(int row, int g) {
    return row * 64 + ((g ^ (row & 7) ^ ((row >> 3) & 7)) << 3);
}

__global__ __launch_bounds__(512) void chanmm_mfma(
    const u16* __restrict__ m1, const u16* __restrict__ m2,
    float* __restrict__ mult) {
    __shared__ u16 Ah[128 * 64];
    __shared__ u16 Bh[64 * 64];
    int t = threadIdx.x, lane = t & 63, wv = t >> 6;
    int l15 = lane & 15, q = lane >> 4;
    int wi = wv >> 1, wj = wv & 1;
    int tile = blockIdx.x;
    int itile = (tile >> 2) * 128, jtile = (tile & 3) * 64;
    int ch = blockIdx.y, bb = blockIdx.z;
    size_t pb = ((size_t)bb * EMB + ch) * NN;
    const u16* A_h = m1 + pb;
    const u16* B_h = m2 + pb;

    int a_i = t >> 3;
    int a_g = t & 7;
    int b_k = t >> 3;
    int b_j8 = (t & 7) * 8;

    int4 rAh0, rAh1, rBh;
#define LOADK(K0)                                                              \
    {                                                                          \
        int k0_ = (K0);                                                        \
        rAh0 = *(const int4*)&A_h[(itile + a_i) * N + k0_ + a_g * 8];          \
        rAh1 = *(const int4*)&A_h[(itile + 64 + a_i) * N + k0_ + a_g * 8];     \
        rBh  = *(const int4*)&B_h[(k0_ + b_k) * N + jtile + b_j8];             \
    }

    f32x4 acc[2][2] = {};
    LOADK(0);
#pragma unroll
    for (int s = 0; s < 4; ++s) {
        *(int4*)&Ah[soff(a_i, a_g)] = rAh0;
        *(int4*)&Ah[soff(a_i + 64, a_g)] = rAh1;
        {
            const u16* ph = (const u16*)&rBh;
            int G = b_k >> 3, kin = b_k & 7;
#pragma unroll
            for (int d = 0; d < 8; ++d) {
                int j = b_j8 + d;
                Bh[soff(j, G) + kin] = ph[d];
            }
        }
        __syncthreads();
        if (s < 3) LOADK((s + 1) * 64);
#pragma unroll
        for (int ks = 0; ks < 2; ++ks) {
            int g = ks * 4 + q;
            bf16x8 bhi[2];
#pragma unroll
            for (int jt = 0; jt < 2; ++jt) {
                int rj = wj * 32 + jt * 16 + l15;
                bhi[jt] = *(const bf16x8*)&Bh[soff(rj, g)];
            }
#pragma unroll
            for (int it = 0; it < 2; ++it) {
                int ri = wi * 32 + it * 16 + l15;
                bf16x8 ahi = *(const bf16x8*)&Ah[soff(ri, g)];
#pragma unroll
                for (int jt = 0; jt < 2; ++jt)
                    acc[it][jt] = __builtin_amdgcn_mfma_f32_16x16x32_bf16(ahi, bhi[jt], acc[it][jt], 0, 0, 0);
            }
        }
        __syncthreads();
    }
#undef LOADK
    float* O = mult + pb;
#pragma unroll
    for (int it = 0; it < 2; ++it)
#pragma unroll
        for (int jt = 0; jt < 2; ++jt)
#pragma unroll
            for (int r = 0; r < 4; ++r) {
                int i = itile + wi * 32 + it * 16 + q * 4 + r;
                int j = jtile + wj * 32 + jt * 16 + l15;
                O[(size_t)i * N + j] = acc[it][jt][r];
            }
}

// ---------------- f2 regular: skip conv K=128 over [z || mult] -> z (in-place NCHW); 1 barrier ----------------
__global__ __launch_bounds__(256, 3) void f2_reg(
    const float* __restrict__ mult,   // NCHW fp32
    const u16* __restrict__ wsh, const u16* __restrict__ wsl, int blk,
    const float* __restrict__ SB,
    float* __restrict__ z) {
    __shared__ u16 wh[8192], wl[8192];            // 32 KB
    __shared__ u16 ah[64 * TSTR], al[64 * TSTR];  // 18.4 KB -> 50.6 KB
    int bb = blockIdx.y, p0 = blockIdx.x * 64;
    int t = threadIdx.x, lane = t & 63, wv = t >> 6;
    int q = lane >> 4, l15 = lane & 15;
    const float* mp = mult + (size_t)bb * EMB * NN;
    float* zp = z + (size_t)bb * EMB * NN;
    const u16* SWh = wsh + REG_BASE + blk * REG_STRIDE + 16384;
    const u16* SWl = wsl + REG_BASE + blk * REG_STRIDE + 16384;

    // z frags direct from NCHW fp32 (read before in-place overwrite)
    bf16x8 zfh[2], zfl[2];
    zfrags_nchw(zp, p0 + wv * 16 + l15, q, zfh, zfl);

    stage_w128s(SWh, SWl, wh, wl, t);
    stage_band_nchw(mp, p0, ah, al, wv, lane);    // wave-local mult band
    __syncthreads();                              // SW visible

    f32x4 acc[4];
    init_bias(SB, acc, lane);
    mfma_L1_128(zfh, zfl, wh, wl, 0, acc, lane);       // z half (k 0..63), frags in regs
    layer_half128(ah, al, wh, wl, 64, acc, wv, lane);  // mult half (k 64..127), own band
    write_m_lin(acc, zp, p0, wv, lane);
}

// ---------------- f2 rb0: skip conv K=64 (mult) + rank-1 adj term -> z ----------------
__global__ __launch_bounds__(256, 3) void f2_rb0(
    const float* __restrict__ adj, int b_base,
    const float* __restrict__ mult,   // NCHW fp32
    const u16* __restrict__ wsh, const u16* __restrict__ wsl,
    const float* __restrict__ SWf, const float* __restrict__ SB,
    float* __restrict__ z) {
    __shared__ u16 ah[64 * TSTR], al[64 * TSTR];
    __shared__ u16 wh[4096], wl[4096];            // 34,816 B
    int bb = blockIdx.y, p0 = blockIdx.x * 64;
    int t = threadIdx.x, lane = t & 63, wv = t >> 6;
    const float* mp = mult + (size_t)bb * EMB * NN;
    float* zp = z + (size_t)bb * EMB * NN;

    stage_w64(wsh + RB0_SW, wsl + RB0_SW, wh, wl, t);
    stage_act_nchw(mp, p0, ah, al, t);
    __syncthreads();

    int q = lane >> 4, l = lane & 15;
    float a = adj[(size_t)(b_base + bb) * NN + p0 + wv * 16 + l];
    f32x4 acc[4];
#pragma unroll
    for (int ot = 0; ot < 4; ++ot)
#pragma unroll
        for (int j = 0; j < 4; ++j) {
            int o = ot * 16 + q * 4 + j;
            acc[ot][j] = SB[o] + SWf[o * 66] * a;
        }
    layer_half64(ah, al, wh, wl, acc, wv, lane);
    write_m_lin(acc, zp, p0, wv, lane);
}

// ---------------- pooling partials (float4 loads, branch-free diag) ----------------
__global__ void pool(const float* __restrict__ z, float* __restrict__ sums, int b_base) {
    int bb = blockIdx.x;
    int c = blockIdx.y;
    size_t base = ((size_t)bb * EMB + c) * NN;
    const float4* z4 = (const float4*)(z + base);
    int t = threadIdx.x;
    float s = 0.0f;
#pragma unroll 4
    for (int it = 0; it < 64; ++it) {
        float4 v = z4[it * 256 + t];
        s += v.x + v.y + v.z + v.w;
    }
    float d = z[base + (size_t)t * 257];
    for (int off = 32; off > 0; off >>= 1) {
        s += __shfl_down(s, off);
        d += __shfl_down(d, off);
    }
    __shared__ float ls[4], ld[4];
    int wid = t >> 6;
    if ((t & 63) == 0) { ls[wid] = s; ld[wid] = d; }
    __syncthreads();
    if (t == 0) {
        s = ls[0] + ls[1] + ls[2] + ls[3];
        d = ld[0] + ld[1] + ld[2] + ld[3];
        int b = b_base + bb;
        sums[b * EMB + c] = s;
        sums[BATCH * EMB + b * EMB + c] = d;
    }
}

// ---------------- final pooled FC ----------------
__global__ void fc(const float* __restrict__ sums,
                   const float* __restrict__ fcw1, const float* __restrict__ fcb1,
                   const float* __restrict__ fcw2, const float* __restrict__ fcb2,
                   float* __restrict__ out) {
    int b = blockIdx.x;
    __shared__ float h[128];
    __shared__ float hh2[64];
    int t = threadIdx.x;
    if (t < 64) {
        h[t] = sums[BATCH * EMB + b * EMB + t] / (float)N;
    } else {
        int c = t - 64;
        float sall = sums[b * EMB + c];
        float sd = sums[BATCH * EMB + b * EMB + c];
        h[t] = (sall - sd) / (float)(N * (N - 1));
    }
    __syncthreads();
    if (t < 64) {
        float acc = fcb1[t];
        for (int k = 0; k < 128; ++k) acc += fcw1[t * 128 + k] * h[k];
        hh2[t] = acc > 0.0f ? acc : 0.0f;
    }
    __syncthreads();
    if (t == 0) {
        float acc = fcb2[0];
        for (int k = 0; k < 64; ++k) acc += fcw2[k] * hh2[k];
        out[b] = acc;
    }
}

extern "C" void kernel_launch(void* const* d_in, const int* in_sizes, int n_in,
                              void* d_out, int out_size, void* d_ws, size_t ws_size,
                              hipStream_t stream) {
    const int* ei       = (const int*)d_in[0];
    const int* batchv   = (const int*)d_in[1];
    const float* rb0_m1w1 = (const float*)d_in[2];
    const float* rb0_m1b1 = (const float*)d_in[3];
    const float* rb0_m1w2 = (const float*)d_in[4];
    const float* rb0_m1b2 = (const float*)d_in[5];
    const float* rb0_m2w1 = (const float*)d_in[6];
    const float* rb0_m2b1 = (const float*)d_in[7];
    const float* rb0_m2w2 = (const float*)d_in[8];
    const float* rb0_m2b2 = (const float*)d_in[9];
    const float* rb0_sw   = (const float*)d_in[10];
    const float* rb0_sb   = (const float*)d_in[11];
    const float* rb_m1w1  = (const float*)d_in[12];
    const float* rb_m1b1  = (const float*)d_in[13];
    const float* rb_m1w2  = (const float*)d_in[14];
    const float* rb_m1b2  = (const float*)d_in[15];
    const float* rb_m2w1  = (const float*)d_in[16];
    const float* rb_m2b1  = (const float*)d_in[17];
    const float* rb_m2w2  = (const float*)d_in[18];
    const float* rb_m2b2  = (const float*)d_in[19];
    const float* rb_sw    = (const float*)d_in[20];
    const float* rb_sb    = (const float*)d_in[21];
    const float* fcw1     = (const float*)d_in[22];
    const float* fcb1     = (const float*)d_in[23];
    const float* fcw2     = (const float*)d_in[24];
    const float* fcb2     = (const float*)d_in[25];

    const size_t P = (size_t)EMB * NN;               // 4,194,304 elems
    const size_t WB = (size_t)WSPLIT_ELEMS * 2ull;
    const size_t fixedBytes = 524288ull * 4ull + 4096ull + 2ull * WB;
    const size_t perGraphBytes = 2ull * P * 2ull + P * 4ull + P * 4ull;
    int g = BATCH;
    while (g > 1) {
        if (fixedBytes + (size_t)g * perGraphBytes <= ws_size) break;
        g >>= 1;
    }

    char* w = (char*)d_ws;
    float* adj   = (float*)w;  w += 524288ull * 4ull;
    float* sums  = (float*)w;  w += 4096;
    u16* wsh     = (u16*)w;    w += WB;
    u16* wsl     = (u16*)w;    w += WB;
    u16* m1      = (u16*)w;    w += (size_t)g * P * 2ull;
    u16* m2      = (u16*)w;    w += (size_t)g * P * 2ull;
    float* mult  = (float*)w;  w += (size_t)g * P * 4ull;
    float* znchw = (float*)w;  w += (size_t)g * P * 4ull;

    hipMemsetAsync(adj, 0, 524288ull * 4ull, stream);
    scatter_adj<<<NEDGE / 256, 256, 0, stream>>>(ei, batchv, adj);
    prep_w<<<(WSPLIT_ELEMS + 255) / 256, 256, 0, stream>>>(
        rb0_m1w2, rb0_m2w2, rb0_sw, rb_m1w1, rb_m1w2, rb_m2w1, rb_m2w2, rb_sw, wsh, wsl);

    for (int b_base = 0; b_base < BATCH; b_base += g) {
        dim3 gridE(NN / 64, g);
        dim3 gridM(8, EMB, g);

        f1_rb0<<<gridE, 256, 0, stream>>>(adj, b_base,
            rb0_m1w1, rb0_m1b1, rb0_m2w1, rb0_m2b1,
            wsh, wsl, rb0_m1b2, rb0_m2b2, m1, m2);
        chanmm_mfma<<<gridM, 512, 0, stream>>>(m1, m2, mult);
        f2_rb0<<<gridE, 256, 0, stream>>>(adj, b_base, mult, wsh, wsl, rb0_sw, rb0_sb, znchw);

        for (int i = 0; i < 3; ++i) {
            f1_reg<<<gridE, 256, 0, stream>>>(znchw, wsh, wsl, i,
                rb_m1b1 + i * 64, rb_m1b2 + i * 64,
                rb_m2b1 + i * 64, rb_m2b2 + i * 64,
                m1, m2);
            chanmm_mfma<<<gridM, 512, 0, stream>>>(m1, m2, mult);
            f2_reg<<<gridE, 256, 0, stream>>>(mult, wsh, wsl, i, rb_sb + i * 64, znchw);
        }

        pool<<<dim3(g, EMB), 256, 0, stream>>>(znchw, sums, b_base);
    }
    fc<<<BATCH, 128, 0, stream>>>(sums, fcw1, fcb1, fcw2, fcb2, (float*)d_out);
}

// Round 23
// 851.312 us; speedup vs baseline: 1.0859x; 1.0859x over previous
//
#include <hip/hip_runtime.h>

#define N 256
#define NN 65536
#define EMB 64
#define BATCH 8
#define NEDGE 32768

typedef unsigned short u16;
typedef unsigned int u32t;
typedef __attribute__((ext_vector_type(8))) short bf16x8;
typedef __attribute__((ext_vector_type(4))) float f32x4;

// pre-split weight buffer offsets (u16 elements)
#define RB0_W2A 0
#define RB0_W2B 4096
#define RB0_SW  8192
#define REG_BASE 12288
#define REG_STRIDE 24576   // per regular block: W1A,W2A,W1B,W2B (4096 each) + SW (8192)
#define WSPLIT_ELEMS 86016

static __device__ __forceinline__ u16 f2bs(float f) {
    u32t u = __float_as_uint(f);
    u32t r = (u + 0x7FFFu + ((u >> 16) & 1u)) >> 16;
    return (u16)r;
}
static __device__ __forceinline__ float b2f(u16 s) {
    return __uint_as_float(((u32t)s) << 16);
}
static __device__ __forceinline__ void split_bf(float a, u16& hi, u16& lo) {
    hi = f2bs(a);
    float r = a - b2f(hi);
    lo = f2bs(r);
}

// ---------------- adjacency scatter ----------------
__global__ void scatter_adj(const int* __restrict__ ei, const int* __restrict__ batch,
                            float* __restrict__ adj) {
    int e = blockIdx.x * blockDim.x + threadIdx.x;
    if (e >= NEDGE) return;
    int src = ei[e];
    int dst = ei[NEDGE + e];
    int g = batch[src];
    int lu = src - g * N;
    int lv = dst - g * N;
    atomicAdd(&adj[(size_t)g * NN + (size_t)lu * N + lv], 1.0f);
}

// ---------------- one-time weight pre-split ----------------
__global__ void prep_w(const float* __restrict__ rb0_m1w2, const float* __restrict__ rb0_m2w2,
                       const float* __restrict__ rb0_sw,
                       const float* __restrict__ rb_m1w1, const float* __restrict__ rb_m1w2,
                       const float* __restrict__ rb_m2w1, const float* __restrict__ rb_m2w2,
                       const float* __restrict__ rb_sw,
                       u16* __restrict__ wh, u16* __restrict__ wl) {
    int idx = blockIdx.x * 256 + threadIdx.x;
    if (idx >= WSPLIT_ELEMS) return;
    float v;
    if (idx < 4096) v = rb0_m1w2[idx];
    else if (idx < 8192) v = rb0_m2w2[idx - 4096];
    else if (idx < 12288) { int e = idx - 8192; v = rb0_sw[(e >> 6) * 66 + 2 + (e & 63)]; }
    else {
        int e = idx - REG_BASE;
        int blk = e / REG_STRIDE, r = e % REG_STRIDE;
        if (r < 4096) v = rb_m1w1[blk * 4096 + r];
        else if (r < 8192) v = rb_m1w2[blk * 4096 + r - 4096];
        else if (r < 12288) v = rb_m2w1[blk * 4096 + r - 8192];
        else if (r < 16384) v = rb_m2w2[blk * 4096 + r - 12288];
        else v = rb_sw[blk * 8192 + r - 16384];
    }
    u16 h, l;
    split_bf(v, h, l);
    wh[idx] = h; wl[idx] = l;
}

// ================= engine building blocks =================

__device__ __forceinline__ void stage_w64(const u16* __restrict__ Wh, const u16* __restrict__ Wl,
                                          u16* dh, u16* dl, int t) {
#pragma unroll
    for (int it = 0; it < 2; ++it) {
        int idx = it * 256 + t;
        int row = idx >> 3, g = idx & 7;
        int4 vh = *(const int4*)&Wh[row * 64 + g * 8];
        int4 vl = *(const int4*)&Wl[row * 64 + g * 8];
        int d = row * 64 + ((g ^ (row & 7)) << 3);
        *(int4*)&dh[d] = vh;
        *(int4*)&dl[d] = vl;
    }
}
__device__ __forceinline__ void stage_w128s(const u16* __restrict__ Wh, const u16* __restrict__ Wl,
                                            u16* dh, u16* dl, int t) {
#pragma unroll
    for (int it = 0; it < 4; ++it) {
        int idx = it * 256 + t;
        int row = idx >> 4, g = idx & 15;
        int4 vh = *(const int4*)&Wh[row * 128 + g * 8];
        int4 vl = *(const int4*)&Wl[row * 128 + g * 8];
        int d = row * 128 + ((g ^ (row & 7)) << 3);
        *(int4*)&dh[d] = vh;
        *(int4*)&dl[d] = vl;
    }
}
__device__ __forceinline__ bf16x8 wfrag64(const u16* w, int row, int k0) {
    int g = k0 >> 3;
    return *(const bf16x8*)&w[row * 64 + ((g ^ (row & 7)) << 3)];
}
__device__ __forceinline__ bf16x8 wfrag128(const u16* w, int row, int k0) {
    int g = k0 >> 3;
    return *(const bf16x8*)&w[row * 128 + ((g ^ (row & 7)) << 3)];
}

// wave-local: stage this wave's 16-px band of bf16 mult (NCHW u16) into swizzled stride-64 rows
__device__ __forceinline__ void stage_band_m(const u16* __restrict__ src, int p0,
                                             u16* mb, int wband, int lane) {
    int q = lane >> 4, l15 = lane & 15;
    int px = wband * 16 + l15;
    int gpx = p0 + px;
#pragma unroll
    for (int it = 0; it < 8; ++it) {
        int c0 = it * 8 + q * 2;                 // granule = it, offset = q*2
        u16 v0 = src[(size_t)c0 * NN + gpx];
        u16 v1 = src[(size_t)(c0 + 1) * NN + gpx];
        int gaddr = px * 64 + ((it ^ (px & 7)) << 3) + q * 2;
        *(u32t*)&mb[gaddr] = (u32t)v0 | ((u32t)v1 << 16);
    }
}
// cooperative: stage 64px x 64c bf16 mult tile into swizzled stride-64 rows (f2_rb0)
__device__ __forceinline__ void stage_act_m(const u16* __restrict__ src, int p0,
                                            u16* mb, int t) {
#pragma unroll
    for (int it = 0; it < 8; ++it) {
        int idx = it * 256 + t;
        int px = idx & 63;
        int c0 = (idx >> 6) * 2;
        u16 v0 = src[(size_t)c0 * NN + p0 + px];
        u16 v1 = src[(size_t)(c0 + 1) * NN + p0 + px];
        int gaddr = px * 64 + ((((c0 >> 3) ^ (px & 7))) << 3) + (c0 & 7);
        *(u32t*)&mb[gaddr] = (u32t)v0 | ((u32t)v1 << 16);
    }
}

// build this lane's z fragments (hi/lo) directly from NCHW fp32 global
__device__ __forceinline__ void zfrags_nchw(const float* __restrict__ zp, int px,
                                            int q, bf16x8 zfh[2], bf16x8 zfl[2]) {
#pragma unroll
    for (int ks = 0; ks < 2; ++ks)
#pragma unroll
        for (int j = 0; j < 8; ++j) {
            float v = zp[(size_t)(ks * 32 + q * 8 + j) * NN + px];
            u16 h, l; split_bf(v, h, l);
            zfh[ks][j] = (short)h;
            zfl[ks][j] = (short)l;
        }
}

__device__ __forceinline__ void init_bias(const float* __restrict__ Bb, f32x4* acc, int lane) {
    int q = lane >> 4;
#pragma unroll
    for (int ot = 0; ot < 4; ++ot)
#pragma unroll
        for (int j = 0; j < 4; ++j)
            acc[ot][j] = Bb[ot * 16 + q * 4 + j];
}

// f1 L1 (3-term: z split exact, W split): D[o][px] += W[o][k] * z[px][k]
__device__ __forceinline__ void mfma_L1_64(bf16x8 zfh[2], bf16x8 zfl[2],
                                           const u16* wh, const u16* wl,
                                           f32x4* acc, int lane) {
    int q = lane >> 4, l = lane & 15;
#pragma unroll
    for (int ks = 0; ks < 2; ++ks) {
        int k0 = ks * 32 + q * 8;
#pragma unroll
        for (int ot = 0; ot < 4; ++ot) {
            bf16x8 ahi = wfrag64(wh, ot * 16 + l, k0);
            bf16x8 alo = wfrag64(wl, ot * 16 + l, k0);
            acc[ot] = __builtin_amdgcn_mfma_f32_16x16x32_bf16(ahi, zfh[ks], acc[ot], 0, 0, 0);
            acc[ot] = __builtin_amdgcn_mfma_f32_16x16x32_bf16(ahi, zfl[ks], acc[ot], 0, 0, 0);
            acc[ot] = __builtin_amdgcn_mfma_f32_16x16x32_bf16(alo, zfh[ks], acc[ot], 0, 0, 0);
        }
    }
}
// f2 L1, W split (3-term), K-half of [64][128]
__device__ __forceinline__ void mfma_L1_128(bf16x8 zfh[2], bf16x8 zfl[2],
                                            const u16* wh, const u16* wl, int ak0,
                                            f32x4* acc, int lane) {
    int q = lane >> 4, l = lane & 15;
#pragma unroll
    for (int ks = 0; ks < 2; ++ks) {
        int k0 = ks * 32 + q * 8;
#pragma unroll
        for (int ot = 0; ot < 4; ++ot) {
            bf16x8 ahi = wfrag128(wh, ot * 16 + l, ak0 + k0);
            bf16x8 alo = wfrag128(wl, ot * 16 + l, ak0 + k0);
            acc[ot] = __builtin_amdgcn_mfma_f32_16x16x32_bf16(ahi, zfh[ks], acc[ot], 0, 0, 0);
            acc[ot] = __builtin_amdgcn_mfma_f32_16x16x32_bf16(ahi, zfl[ks], acc[ot], 0, 0, 0);
            acc[ot] = __builtin_amdgcn_mfma_f32_16x16x32_bf16(alo, zfh[ks], acc[ot], 0, 0, 0);
        }
    }
}

// f1 L2 (2-term: h bf16 exact, W split): h from swizzled stride-64 hbuf
__device__ __forceinline__ void layer_h2(const u16* hbuf,
                                         const u16* wh, const u16* wl,
                                         f32x4* acc, int wv, int lane) {
    int q = lane >> 4, l = lane & 15;
#pragma unroll
    for (int ks = 0; ks < 2; ++ks) {
        int k0 = ks * 32 + q * 8;
        bf16x8 b = wfrag64(hbuf, wv * 16 + l, k0);
#pragma unroll
        for (int ot = 0; ot < 4; ++ot) {
            bf16x8 ahi = wfrag64(wh, ot * 16 + l, k0);
            bf16x8 alo = wfrag64(wl, ot * 16 + l, k0);
            acc[ot] = __builtin_amdgcn_mfma_f32_16x16x32_bf16(ahi, b, acc[ot], 0, 0, 0);
            acc[ot] = __builtin_amdgcn_mfma_f32_16x16x32_bf16(alo, b, acc[ot], 0, 0, 0);
        }
    }
}
// f2 mult half (2-term: mult bf16 exact, W split), K-offset 64 of [64][128]
__device__ __forceinline__ void layer_m2_128(const u16* mb,
                                             const u16* wh, const u16* wl,
                                             f32x4* acc, int wv, int lane) {
    int q = lane >> 4, l = lane & 15;
#pragma unroll
    for (int ks = 0; ks < 2; ++ks) {
        int k0 = ks * 32 + q * 8;
        bf16x8 b = wfrag64(mb, wv * 16 + l, k0);
#pragma unroll
        for (int ot = 0; ot < 4; ++ot) {
            bf16x8 ahi = wfrag128(wh, ot * 16 + l, 64 + k0);
            bf16x8 alo = wfrag128(wl, ot * 16 + l, 64 + k0);
            acc[ot] = __builtin_amdgcn_mfma_f32_16x16x32_bf16(ahi, b, acc[ot], 0, 0, 0);
            acc[ot] = __builtin_amdgcn_mfma_f32_16x16x32_bf16(alo, b, acc[ot], 0, 0, 0);
        }
    }
}
// f2_rb0 mult (2-term: mult bf16 exact, W split [64][64])
__device__ __forceinline__ void layer_m2_64(const u16* mb,
                                            const u16* wh, const u16* wl,
                                            f32x4* acc, int wv, int lane) {
    int q = lane >> 4, l = lane & 15;
#pragma unroll
    for (int ks = 0; ks < 2; ++ks) {
        int k0 = ks * 32 + q * 8;
        bf16x8 b = wfrag64(mb, wv * 16 + l, k0);
#pragma unroll
        for (int ot = 0; ot < 4; ++ot) {
            bf16x8 ahi = wfrag64(wh, ot * 16 + l, k0);
            bf16x8 alo = wfrag64(wl, ot * 16 + l, k0);
            acc[ot] = __builtin_amdgcn_mfma_f32_16x16x32_bf16(ahi, b, acc[ot], 0, 0, 0);
            acc[ot] = __builtin_amdgcn_mfma_f32_16x16x32_bf16(alo, b, acc[ot], 0, 0, 0);
        }
    }
}

// write h = relu(acc) as plain bf16 to SWIZZLED stride-64 own-band rows [px][o]
__device__ __forceinline__ void write_h_bf16(f32x4* acc, u16* hbuf, int wv, int lane) {
    int q = lane >> 4, l = lane & 15;
    int px = wv * 16 + l;
#pragma unroll
    for (int ot = 0; ot < 4; ++ot) {
#pragma unroll
        for (int jp = 0; jp < 2; ++jp) {
            int o = ot * 16 + q * 4 + jp * 2;
            int gaddr = px * 64 + (((o >> 3) ^ (px & 7)) << 3) + (o & 7);
            float v0 = acc[ot][jp * 2];     v0 = v0 > 0.f ? v0 : 0.f;
            float v1 = acc[ot][jp * 2 + 1]; v1 = v1 > 0.f ? v1 : 0.f;
            *(u32t*)&hbuf[gaddr] = (u32t)f2bs(v0) | ((u32t)f2bs(v1) << 16);
        }
    }
}

// store relu(acc) (D[o][px]) as plain bf16 to u16 NCHW plane set
__device__ __forceinline__ void write_m_bf16(f32x4* acc, u16* __restrict__ mh,
                                             int p0, int wv, int lane) {
    int q = lane >> 4, l = lane & 15;
    int px = p0 + wv * 16 + l;
#pragma unroll
    for (int ot = 0; ot < 4; ++ot)
#pragma unroll
        for (int j = 0; j < 4; ++j) {
            int o = ot * 16 + q * 4 + j;
            float v = acc[ot][j]; v = v > 0.f ? v : 0.f;
            mh[(size_t)o * NN + px] = f2bs(v);
        }
}

__device__ __forceinline__ void write_m_lin(f32x4* acc, float* __restrict__ mout,
                                            int p0, int wv, int lane) {
    int q = lane >> 4, l = lane & 15;
    int px = p0 + wv * 16 + l;
#pragma unroll
    for (int ot = 0; ot < 4; ++ot)
#pragma unroll
        for (int j = 0; j < 4; ++j) {
            int o = ot * 16 + q * 4 + j;
            mout[(size_t)o * NN + px] = acc[ot][j];
        }
}

// ---------------- f1 regular: z(NCHW fp32) -> m1,m2 (bf16 NCHW); 3 barriers; 40 KB LDS ----------------
__global__ __launch_bounds__(256, 4) void f1_reg(
    const float* __restrict__ z,
    const u16* __restrict__ wsh, const u16* __restrict__ wsl, int blk,
    const float* __restrict__ B1a, const float* __restrict__ B2a,
    const float* __restrict__ B1b, const float* __restrict__ B2b,
    u16* __restrict__ m1, u16* __restrict__ m2) {
    __shared__ u16 w1h[4096], w1l[4096], w2h[4096], w2l[4096];  // 32 KB
    __shared__ u16 hbuf[4096];                                  // 8 KB
    int bb = blockIdx.y, p0 = blockIdx.x * 64;
    int t = threadIdx.x, lane = t & 63, wv = t >> 6;
    int q = lane >> 4, l15 = lane & 15;
    size_t gofs = (size_t)bb * EMB * NN;
    const float* zp = z + gofs;
    const u16* Wbh = wsh + REG_BASE + blk * REG_STRIDE;
    const u16* Wbl = wsl + REG_BASE + blk * REG_STRIDE;

    bf16x8 zfh[2], zfl[2];
    zfrags_nchw(zp, p0 + wv * 16 + l15, q, zfh, zfl);

    stage_w64(Wbh, Wbl, w1h, w1l, t);               // W1A
    stage_w64(Wbh + 4096, Wbl + 4096, w2h, w2l, t); // W2A
    __syncthreads();

    f32x4 acc[4];
    init_bias(B1a, acc, lane);
    mfma_L1_64(zfh, zfl, w1h, w1l, acc, lane);
    write_h_bf16(acc, hbuf, wv, lane);
    init_bias(B2a, acc, lane);
    layer_h2(hbuf, w2h, w2l, acc, wv, lane);
    write_m_bf16(acc, m1 + gofs, p0, wv, lane);

    __syncthreads();
    stage_w64(Wbh + 8192, Wbl + 8192, w1h, w1l, t);    // W1B
    stage_w64(Wbh + 12288, Wbl + 12288, w2h, w2l, t);  // W2B
    __syncthreads();

    init_bias(B1b, acc, lane);
    mfma_L1_64(zfh, zfl, w1h, w1l, acc, lane);
    write_h_bf16(acc, hbuf, wv, lane);
    init_bias(B2b, acc, lane);
    layer_h2(hbuf, w2h, w2l, acc, wv, lane);
    write_m_bf16(acc, m2 + gofs, p0, wv, lane);
}

// ---------------- f1 rb0: adj -> m1,m2 (bf16); 1 barrier ----------------
__global__ __launch_bounds__(256, 4) void f1_rb0(
    const float* __restrict__ adj, int b_base,
    const float* __restrict__ w1a, const float* __restrict__ b1a,
    const float* __restrict__ w1b, const float* __restrict__ b1b,
    const u16* __restrict__ wsh, const u16* __restrict__ wsl,
    const float* __restrict__ B2a, const float* __restrict__ B2b,
    u16* __restrict__ m1, u16* __restrict__ m2) {
    __shared__ u16 w1h[4096], w1l[4096], w2h[4096], w2l[4096];
    __shared__ u16 hbuf[4096];
    int bb = blockIdx.y, p0 = blockIdx.x * 64;
    int t = threadIdx.x, lane = t & 63, wv = t >> 6;
    int q = lane >> 4, l15 = lane & 15;
    size_t gofs = (size_t)bb * EMB * NN;
    int pxl = wv * 16 + l15;
    float a = adj[(size_t)(b_base + bb) * NN + p0 + pxl];

    stage_w64(wsh + RB0_W2A, wsl + RB0_W2A, w1h, w1l, t);
    stage_w64(wsh + RB0_W2B, wsl + RB0_W2B, w2h, w2l, t);
#pragma unroll
    for (int it = 0; it < 8; ++it) {
        int o0 = it * 8 + q * 2;
        int gaddr = pxl * 64 + ((it ^ (pxl & 7)) << 3) + q * 2;
        float v0 = w1a[o0 * 2] * a + b1a[o0];             v0 = v0 > 0.f ? v0 : 0.f;
        float v1 = w1a[(o0 + 1) * 2] * a + b1a[o0 + 1];   v1 = v1 > 0.f ? v1 : 0.f;
        *(u32t*)&hbuf[gaddr] = (u32t)f2bs(v0) | ((u32t)f2bs(v1) << 16);
    }
    __syncthreads();

    f32x4 acc[4];
    init_bias(B2a, acc, lane);
    layer_h2(hbuf, w1h, w1l, acc, wv, lane);
    write_m_bf16(acc, m1 + gofs, p0, wv, lane);

#pragma unroll
    for (int it = 0; it < 8; ++it) {
        int o0 = it * 8 + q * 2;
        int gaddr = pxl * 64 + ((it ^ (pxl & 7)) << 3) + q * 2;
        float v0 = w1b[o0 * 2] * a + b1b[o0];             v0 = v0 > 0.f ? v0 : 0.f;
        float v1 = w1b[(o0 + 1) * 2] * a + b1b[o0 + 1];   v1 = v1 > 0.f ? v1 : 0.f;
        *(u32t*)&hbuf[gaddr] = (u32t)f2bs(v0) | ((u32t)f2bs(v1) << 16);
    }
    init_bias(B2b, acc, lane);
    layer_h2(hbuf, w2h, w2l, acc, wv, lane);
    write_m_bf16(acc, m2 + gofs, p0, wv, lane);
}

// ---------------- per-channel NxN matmul, plain bf16 MFMA; mult out bf16 ----------------
__device__ __forceinline__ int soff(int row, int g) {
    return row * 64 + ((g ^ (row & 7) ^ ((row >> 3) & 7)) << 3);
}

__global__ __launch_bounds__(512) void chanmm_mfma(
    const u16* __restrict__ m1, const u16* __restrict__ m2,
    u16* __restrict__ mult) {
    __shared__ u16 Ah[128 * 64];
    __shared__ u16 Bh[64 * 64];
    int t = threadIdx.x, lane = t & 63, wv = t >> 6;
    int l15 = lane & 15, q = lane >> 4;
    int wi = wv >> 1, wj = wv & 1;
    int tile = blockIdx.x;
    int itile = (tile >> 2) * 128, jtile = (tile & 3) * 64;
    int ch = blockIdx.y, bb = blockIdx.z;
    size_t pb = ((size_t)bb * EMB + ch) * NN;
    const u16* A_h = m1 + pb;
    const u16* B_h = m2 + pb;

    int a_i = t >> 3;
    int a_g = t & 7;
    int b_k = t >> 3;
    int b_j8 = (t & 7) * 8;

    int4 rAh0, rAh1, rBh;
#define LOADK(K0)                                                              \
    {                                                                          \
        int k0_ = (K0);                                                        \
        rAh0 = *(const int4*)&A_h[(itile + a_i) * N + k0_ + a_g * 8];          \
        rAh1 = *(const int4*)&A_h[(itile + 64 + a_i) * N + k0_ + a_g * 8];     \
        rBh  = *(const int4*)&B_h[(k0_ + b_k) * N + jtile + b_j8];             \
    }

    f32x4 acc[2][2] = {};
    LOADK(0);
#pragma unroll
    for (int s = 0; s < 4; ++s) {
        *(int4*)&Ah[soff(a_i, a_g)] = rAh0;
        *(int4*)&Ah[soff(a_i + 64, a_g)] = rAh1;
        {
            const u16* ph = (const u16*)&rBh;
            int G = b_k >> 3, kin = b_k & 7;
#pragma unroll
            for (int d = 0; d < 8; ++d) {
                int j = b_j8 + d;
                Bh[soff(j, G) + kin] = ph[d];
            }
        }
        __syncthreads();
        if (s < 3) LOADK((s + 1) * 64);
#pragma unroll
        for (int ks = 0; ks < 2; ++ks) {
            int g = ks * 4 + q;
            bf16x8 bhi[2];
#pragma unroll
            for (int jt = 0; jt < 2; ++jt) {
                int rj = wj * 32 + jt * 16 + l15;
                bhi[jt] = *(const bf16x8*)&Bh[soff(rj, g)];
            }
#pragma unroll
            for (int it = 0; it < 2; ++it) {
                int ri = wi * 32 + it * 16 + l15;
                bf16x8 ahi = *(const bf16x8*)&Ah[soff(ri, g)];
#pragma unroll
                for (int jt = 0; jt < 2; ++jt)
                    acc[it][jt] = __builtin_amdgcn_mfma_f32_16x16x32_bf16(ahi, bhi[jt], acc[it][jt], 0, 0, 0);
            }
        }
        __syncthreads();
    }
#undef LOADK
    u16* O = mult + pb;
#pragma unroll
    for (int it = 0; it < 2; ++it)
#pragma unroll
        for (int jt = 0; jt < 2; ++jt)
#pragma unroll
            for (int r = 0; r < 4; ++r) {
                int i = itile + wi * 32 + it * 16 + q * 4 + r;
                int j = jtile + wj * 32 + jt * 16 + l15;
                O[(size_t)i * N + j] = f2bs(acc[it][jt][r]);
            }
}

// ---------------- f2 regular: skip conv K=128 over [z || mult] -> z (in-place NCHW); 40 KB LDS ----------------
__global__ __launch_bounds__(256, 4) void f2_reg(
    const u16* __restrict__ mult,   // NCHW bf16
    const u16* __restrict__ wsh, const u16* __restrict__ wsl, int blk,
    const float* __restrict__ SB,
    float* __restrict__ z) {
    __shared__ u16 wh[8192], wl[8192];   // 32 KB
    __shared__ u16 mb[4096];             // 8 KB -> 40 KB total
    int bb = blockIdx.y, p0 = blockIdx.x * 64;
    int t = threadIdx.x, lane = t & 63, wv = t >> 6;
    int q = lane >> 4, l15 = lane & 15;
    const u16* mp = mult + (size_t)bb * EMB * NN;
    float* zp = z + (size_t)bb * EMB * NN;
    const u16* SWh = wsh + REG_BASE + blk * REG_STRIDE + 16384;
    const u16* SWl = wsl + REG_BASE + blk * REG_STRIDE + 16384;

    // z frags direct from NCHW fp32 (read before in-place overwrite)
    bf16x8 zfh[2], zfl[2];
    zfrags_nchw(zp, p0 + wv * 16 + l15, q, zfh, zfl);

    stage_w128s(SWh, SWl, wh, wl, t);
    stage_band_m(mp, p0, mb, wv, lane);           // wave-local bf16 mult band
    __syncthreads();                              // SW visible

    f32x4 acc[4];
    init_bias(SB, acc, lane);
    mfma_L1_128(zfh, zfl, wh, wl, 0, acc, lane);  // z half (k 0..63)
    layer_m2_128(mb, wh, wl, acc, wv, lane);      // mult half (k 64..127), 2-term
    write_m_lin(acc, zp, p0, wv, lane);
}

// ---------------- f2 rb0: skip conv K=64 (mult) + rank-1 adj term -> z; 24 KB LDS ----------------
__global__ __launch_bounds__(256, 4) void f2_rb0(
    const float* __restrict__ adj, int b_base,
    const u16* __restrict__ mult,   // NCHW bf16
    const u16* __restrict__ wsh, const u16* __restrict__ wsl,
    const float* __restrict__ SWf, const float* __restrict__ SB,
    float* __restrict__ z) {
    __shared__ u16 wh[4096], wl[4096];   // 16 KB
    __shared__ u16 mb[4096];             // 8 KB -> 24 KB
    int bb = blockIdx.y, p0 = blockIdx.x * 64;
    int t = threadIdx.x, lane = t & 63, wv = t >> 6;
    const u16* mp = mult + (size_t)bb * EMB * NN;
    float* zp = z + (size_t)bb * EMB * NN;

    stage_w64(wsh + RB0_SW, wsl + RB0_SW, wh, wl, t);
    stage_act_m(mp, p0, mb, t);
    __syncthreads();

    int q = lane >> 4, l = lane & 15;
    float a = adj[(size_t)(b_base + bb) * NN + p0 + wv * 16 + l];
    f32x4 acc[4];
#pragma unroll
    for (int ot = 0; ot < 4; ++ot)
#pragma unroll
        for (int j = 0; j < 4; ++j) {
            int o = ot * 16 + q * 4 + j;
            acc[ot][j] = SB[o] + SWf[o * 66] * a;
        }
    layer_m2_64(mb, wh, wl, acc, wv, lane);
    write_m_lin(acc, zp, p0, wv, lane);
}

// ---------------- pooling partials (float4 loads, branch-free diag) ----------------
__global__ void pool(const float* __restrict__ z, float* __restrict__ sums, int b_base) {
    int bb = blockIdx.x;
    int c = blockIdx.y;
    size_t base = ((size_t)bb * EMB + c) * NN;
    const float4* z4 = (const float4*)(z + base);
    int t = threadIdx.x;
    float s = 0.0f;
#pragma unroll 4
    for (int it = 0; it < 64; ++it) {
        float4 v = z4[it * 256 + t];
        s += v.x + v.y + v.z + v.w;
    }
    float d = z[base + (size_t)t * 257];
    for (int off = 32; off > 0; off >>= 1) {
        s += __shfl_down(s, off);
        d += __shfl_down(d, off);
    }
    __shared__ float ls[4], ld[4];
    int wid = t >> 6;
    if ((t & 63) == 0) { ls[wid] = s; ld[wid] = d; }
    __syncthreads();
    if (t == 0) {
        s = ls[0] + ls[1] + ls[2] + ls[3];
        d = ld[0] + ld[1] + ld[2] + ld[3];
        int b = b_base + bb;
        sums[b * EMB + c] = s;
        sums[BATCH * EMB + b * EMB + c] = d;
    }
}

// ---------------- final pooled FC ----------------
__global__ void fc(const float* __restrict__ sums,
                   const float* __restrict__ fcw1, const float* __restrict__ fcb1,
                   const float* __restrict__ fcw2, const float* __restrict__ fcb2,
                   float* __restrict__ out) {
    int b = blockIdx.x;
    __shared__ float h[128];
    __shared__ float hh2[64];
    int t = threadIdx.x;
    if (t < 64) {
        h[t] = sums[BATCH * EMB + b * EMB + t] / (float)N;
    } else {
        int c = t - 64;
        float sall = sums[b * EMB + c];
        float sd = sums[BATCH * EMB + b * EMB + c];
        h[t] = (sall - sd) / (float)(N * (N - 1));
    }
    __syncthreads();
    if (t < 64) {
        float acc = fcb1[t];
        for (int k = 0; k < 128; ++k) acc += fcw1[t * 128 + k] * h[k];
        hh2[t] = acc > 0.0f ? acc : 0.0f;
    }
    __syncthreads();
    if (t == 0) {
        float acc = fcb2[0];
        for (int k = 0; k < 64; ++k) acc += fcw2[k] * hh2[k];
        out[b] = acc;
    }
}

extern "C" void kernel_launch(void* const* d_in, const int* in_sizes, int n_in,
                              void* d_out, int out_size, void* d_ws, size_t ws_size,
                              hipStream_t stream) {
    const int* ei       = (const int*)d_in[0];
    const int* batchv   = (const int*)d_in[1];
    const float* rb0_m1w1 = (const float*)d_in[2];
    const float* rb0_m1b1 = (const float*)d_in[3];
    const float* rb0_m1w2 = (const float*)d_in[4];
    const float* rb0_m1b2 = (const float*)d_in[5];
    const float* rb0_m2w1 = (const float*)d_in[6];
    const float* rb0_m2b1 = (const float*)d_in[7];
    const float* rb0_m2w2 = (const float*)d_in[8];
    const float* rb0_m2b2 = (const float*)d_in[9];
    const float* rb0_sw   = (const float*)d_in[10];
    const float* rb0_sb   = (const float*)d_in[11];
    const float* rb_m1w1  = (const float*)d_in[12];
    const float* rb_m1b1  = (const float*)d_in[13];
    const float* rb_m1w2  = (const float*)d_in[14];
    const float* rb_m1b2  = (const float*)d_in[15];
    const float* rb_m2w1  = (const float*)d_in[16];
    const float* rb_m2b1  = (const float*)d_in[17];
    const float* rb_m2w2  = (const float*)d_in[18];
    const float* rb_m2b2  = (const float*)d_in[19];
    const float* rb_sw    = (const float*)d_in[20];
    const float* rb_sb    = (const float*)d_in[21];
    const float* fcw1     = (const float*)d_in[22];
    const float* fcb1     = (const float*)d_in[23];
    const float* fcw2     = (const float*)d_in[24];
    const float* fcb2     = (const float*)d_in[25];

    const size_t P = (size_t)EMB * NN;               // 4,194,304 elems
    const size_t WB = (size_t)WSPLIT_ELEMS * 2ull;
    const size_t fixedBytes = 524288ull * 4ull + 4096ull + 2ull * WB;
    // per graph: m1,m2 bf16 (16.8) + mult bf16 (8.4) + z fp32 (16.8) = 42 MB
    const size_t perGraphBytes = 2ull * P * 2ull + P * 2ull + P * 4ull;
    int g = BATCH;
    while (g > 1) {
        if (fixedBytes + (size_t)g * perGraphBytes <= ws_size) break;
        g >>= 1;
    }

    char* w = (char*)d_ws;
    float* adj   = (float*)w;  w += 524288ull * 4ull;
    float* sums  = (float*)w;  w += 4096;
    u16* wsh     = (u16*)w;    w += WB;
    u16* wsl     = (u16*)w;    w += WB;
    u16* m1      = (u16*)w;    w += (size_t)g * P * 2ull;
    u16* m2      = (u16*)w;    w += (size_t)g * P * 2ull;
    u16* mult    = (u16*)w;    w += (size_t)g * P * 2ull;
    float* znchw = (float*)w;  w += (size_t)g * P * 4ull;

    hipMemsetAsync(adj, 0, 524288ull * 4ull, stream);
    scatter_adj<<<NEDGE / 256, 256, 0, stream>>>(ei, batchv, adj);
    prep_w<<<(WSPLIT_ELEMS + 255) / 256, 256, 0, stream>>>(
        rb0_m1w2, rb0_m2w2, rb0_sw, rb_m1w1, rb_m1w2, rb_m2w1, rb_m2w2, rb_sw, wsh, wsl);

    for (int b_base = 0; b_base < BATCH; b_base += g) {
        dim3 gridE(NN / 64, g);
        dim3 gridM(8, EMB, g);

        f1_rb0<<<gridE, 256, 0, stream>>>(adj, b_base,
            rb0_m1w1, rb0_m1b1, rb0_m2w1, rb0_m2b1,
            wsh, wsl, rb0_m1b2, rb0_m2b2, m1, m2);
        chanmm_mfma<<<gridM, 512, 0, stream>>>(m1, m2, mult);
        f2_rb0<<<gridE, 256, 0, stream>>>(adj, b_base, mult, wsh, wsl, rb0_sw, rb0_sb, znchw);

        for (int i = 0; i < 3; ++i) {
            f1_reg<<<gridE, 256, 0, stream>>>(znchw, wsh, wsl, i,
                rb_m1b1 + i * 64, rb_m1b2 + i * 64,
                rb_m2b1 + i * 64, rb_m2b2 + i * 64,
                m1, m2);
            chanmm_mfma<<<gridM, 512, 0, stream>>>(m1, m2, mult);
            f2_reg<<<gridE, 256, 0, stream>>>(mult, wsh, wsl, i, rb_sb + i * 64, znchw);
        }

        pool<<<dim3(g, EMB), 256, 0, stream>>>(znchw, sums, b_base);
    }
    fc<<<BATCH, 128, 0, stream>>>(sums, fcw1, fcb1, fcw2, fcb2, (float*)d_out);
}

// Round 24
// 820.441 us; speedup vs baseline: 1.1268x; 1.0376x over previous
//
#include <hip/hip_runtime.h>

#define N 256
#define NN 65536
#define EMB 64
#define BATCH 8
#define NEDGE 32768

typedef unsigned short u16;
typedef unsigned int u32t;
typedef __attribute__((ext_vector_type(8))) short bf16x8;
typedef __attribute__((ext_vector_type(4))) float f32x4;

// pre-split weight buffer offsets (u16 elements)
#define RB0_W2A 0
#define RB0_W2B 4096
#define RB0_SW  8192
#define REG_BASE 12288
#define REG_STRIDE 24576   // per regular block: W1A,W2A,W1B,W2B (4096 each) + SW (8192)
#define WSPLIT_ELEMS 86016

static __device__ __forceinline__ u16 f2bs(float f) {
    u32t u = __float_as_uint(f);
    u32t r = (u + 0x7FFFu + ((u >> 16) & 1u)) >> 16;
    return (u16)r;
}
static __device__ __forceinline__ float b2f(u16 s) {
    return __uint_as_float(((u32t)s) << 16);
}
static __device__ __forceinline__ void split_bf(float a, u16& hi, u16& lo) {
    hi = f2bs(a);
    float r = a - b2f(hi);
    lo = f2bs(r);
}

// ---------------- adjacency scatter ----------------
__global__ void scatter_adj(const int* __restrict__ ei, const int* __restrict__ batch,
                            float* __restrict__ adj) {
    int e = blockIdx.x * blockDim.x + threadIdx.x;
    if (e >= NEDGE) return;
    int src = ei[e];
    int dst = ei[NEDGE + e];
    int g = batch[src];
    int lu = src - g * N;
    int lv = dst - g * N;
    atomicAdd(&adj[(size_t)g * NN + (size_t)lu * N + lv], 1.0f);
}

// ---------------- one-time weight pre-split ----------------
__global__ void prep_w(const float* __restrict__ rb0_m1w2, const float* __restrict__ rb0_m2w2,
                       const float* __restrict__ rb0_sw,
                       const float* __restrict__ rb_m1w1, const float* __restrict__ rb_m1w2,
                       const float* __restrict__ rb_m2w1, const float* __restrict__ rb_m2w2,
                       const float* __restrict__ rb_sw,
                       u16* __restrict__ wh, u16* __restrict__ wl) {
    int idx = blockIdx.x * 256 + threadIdx.x;
    if (idx >= WSPLIT_ELEMS) return;
    float v;
    if (idx < 4096) v = rb0_m1w2[idx];
    else if (idx < 8192) v = rb0_m2w2[idx - 4096];
    else if (idx < 12288) { int e = idx - 8192; v = rb0_sw[(e >> 6) * 66 + 2 + (e & 63)]; }
    else {
        int e = idx - REG_BASE;
        int blk = e / REG_STRIDE, r = e % REG_STRIDE;
        if (r < 4096) v = rb_m1w1[blk * 4096 + r];
        else if (r < 8192) v = rb_m1w2[blk * 4096 + r - 4096];
        else if (r < 12288) v = rb_m2w1[blk * 4096 + r - 8192];
        else if (r < 16384) v = rb_m2w2[blk * 4096 + r - 12288];
        else v = rb_sw[blk * 8192 + r - 16384];
    }
    u16 h, l;
    split_bf(v, h, l);
    wh[idx] = h; wl[idx] = l;
}

// ================= engine building blocks =================

// 256-thread variant (f2 kernels)
__device__ __forceinline__ void stage_w64(const u16* __restrict__ Wh, const u16* __restrict__ Wl,
                                          u16* dh, u16* dl, int t) {
#pragma unroll
    for (int it = 0; it < 2; ++it) {
        int idx = it * 256 + t;
        int row = idx >> 3, g = idx & 7;
        int4 vh = *(const int4*)&Wh[row * 64 + g * 8];
        int4 vl = *(const int4*)&Wl[row * 64 + g * 8];
        int d = row * 64 + ((g ^ (row & 7)) << 3);
        *(int4*)&dh[d] = vh;
        *(int4*)&dl[d] = vl;
    }
}
// 512-thread variant (f1 kernels): 512 chunks in one pass
__device__ __forceinline__ void stage_w64_512(const u16* __restrict__ Wh, const u16* __restrict__ Wl,
                                              u16* dh, u16* dl, int t) {
    int row = t >> 3, g = t & 7;
    int4 vh = *(const int4*)&Wh[row * 64 + g * 8];
    int4 vl = *(const int4*)&Wl[row * 64 + g * 8];
    int d = row * 64 + ((g ^ (row & 7)) << 3);
    *(int4*)&dh[d] = vh;
    *(int4*)&dl[d] = vl;
}
__device__ __forceinline__ void stage_w128s(const u16* __restrict__ Wh, const u16* __restrict__ Wl,
                                            u16* dh, u16* dl, int t) {
#pragma unroll
    for (int it = 0; it < 4; ++it) {
        int idx = it * 256 + t;
        int row = idx >> 4, g = idx & 15;
        int4 vh = *(const int4*)&Wh[row * 128 + g * 8];
        int4 vl = *(const int4*)&Wl[row * 128 + g * 8];
        int d = row * 128 + ((g ^ (row & 7)) << 3);
        *(int4*)&dh[d] = vh;
        *(int4*)&dl[d] = vl;
    }
}
__device__ __forceinline__ bf16x8 wfrag64(const u16* w, int row, int k0) {
    int g = k0 >> 3;
    return *(const bf16x8*)&w[row * 64 + ((g ^ (row & 7)) << 3)];
}
__device__ __forceinline__ bf16x8 wfrag128(const u16* w, int row, int k0) {
    int g = k0 >> 3;
    return *(const bf16x8*)&w[row * 128 + ((g ^ (row & 7)) << 3)];
}

// wave-local: stage this wave's 16-px band of bf16 mult (NCHW u16) into swizzled stride-64 rows
__device__ __forceinline__ void stage_band_m(const u16* __restrict__ src, int p0,
                                             u16* mb, int wband, int lane) {
    int q = lane >> 4, l15 = lane & 15;
    int px = wband * 16 + l15;
    int gpx = p0 + px;
#pragma unroll
    for (int it = 0; it < 8; ++it) {
        int c0 = it * 8 + q * 2;
        u16 v0 = src[(size_t)c0 * NN + gpx];
        u16 v1 = src[(size_t)(c0 + 1) * NN + gpx];
        int gaddr = px * 64 + ((it ^ (px & 7)) << 3) + q * 2;
        *(u32t*)&mb[gaddr] = (u32t)v0 | ((u32t)v1 << 16);
    }
}
// cooperative: stage 64px x 64c bf16 mult tile into swizzled stride-64 rows (f2_rb0)
__device__ __forceinline__ void stage_act_m(const u16* __restrict__ src, int p0,
                                            u16* mb, int t) {
#pragma unroll
    for (int it = 0; it < 8; ++it) {
        int idx = it * 256 + t;
        int px = idx & 63;
        int c0 = (idx >> 6) * 2;
        u16 v0 = src[(size_t)c0 * NN + p0 + px];
        u16 v1 = src[(size_t)(c0 + 1) * NN + p0 + px];
        int gaddr = px * 64 + ((((c0 >> 3) ^ (px & 7))) << 3) + (c0 & 7);
        *(u32t*)&mb[gaddr] = (u32t)v0 | ((u32t)v1 << 16);
    }
}

// build this lane's z fragments (hi/lo) directly from NCHW fp32 global
__device__ __forceinline__ void zfrags_nchw(const float* __restrict__ zp, int px,
                                            int q, bf16x8 zfh[2], bf16x8 zfl[2]) {
#pragma unroll
    for (int ks = 0; ks < 2; ++ks)
#pragma unroll
        for (int j = 0; j < 8; ++j) {
            float v = zp[(size_t)(ks * 32 + q * 8 + j) * NN + px];
            u16 h, l; split_bf(v, h, l);
            zfh[ks][j] = (short)h;
            zfl[ks][j] = (short)l;
        }
}

__device__ __forceinline__ void init_bias(const float* __restrict__ Bb, f32x4* acc, int lane) {
    int q = lane >> 4;
#pragma unroll
    for (int ot = 0; ot < 4; ++ot)
#pragma unroll
        for (int j = 0; j < 4; ++j)
            acc[ot][j] = Bb[ot * 16 + q * 4 + j];
}

// f1 L1 (3-term: z split exact, W split): D[o][px] += W[o][k] * z[px][k]
__device__ __forceinline__ void mfma_L1_64(bf16x8 zfh[2], bf16x8 zfl[2],
                                           const u16* wh, const u16* wl,
                                           f32x4* acc, int lane) {
    int q = lane >> 4, l = lane & 15;
#pragma unroll
    for (int ks = 0; ks < 2; ++ks) {
        int k0 = ks * 32 + q * 8;
#pragma unroll
        for (int ot = 0; ot < 4; ++ot) {
            bf16x8 ahi = wfrag64(wh, ot * 16 + l, k0);
            bf16x8 alo = wfrag64(wl, ot * 16 + l, k0);
            acc[ot] = __builtin_amdgcn_mfma_f32_16x16x32_bf16(ahi, zfh[ks], acc[ot], 0, 0, 0);
            acc[ot] = __builtin_amdgcn_mfma_f32_16x16x32_bf16(ahi, zfl[ks], acc[ot], 0, 0, 0);
            acc[ot] = __builtin_amdgcn_mfma_f32_16x16x32_bf16(alo, zfh[ks], acc[ot], 0, 0, 0);
        }
    }
}
// f2 L1, W split (3-term), K-half of [64][128]
__device__ __forceinline__ void mfma_L1_128(bf16x8 zfh[2], bf16x8 zfl[2],
                                            const u16* wh, const u16* wl, int ak0,
                                            f32x4* acc, int lane) {
    int q = lane >> 4, l = lane & 15;
#pragma unroll
    for (int ks = 0; ks < 2; ++ks) {
        int k0 = ks * 32 + q * 8;
#pragma unroll
        for (int ot = 0; ot < 4; ++ot) {
            bf16x8 ahi = wfrag128(wh, ot * 16 + l, ak0 + k0);
            bf16x8 alo = wfrag128(wl, ot * 16 + l, ak0 + k0);
            acc[ot] = __builtin_amdgcn_mfma_f32_16x16x32_bf16(ahi, zfh[ks], acc[ot], 0, 0, 0);
            acc[ot] = __builtin_amdgcn_mfma_f32_16x16x32_bf16(ahi, zfl[ks], acc[ot], 0, 0, 0);
            acc[ot] = __builtin_amdgcn_mfma_f32_16x16x32_bf16(alo, zfh[ks], acc[ot], 0, 0, 0);
        }
    }
}

// f1 L2 (2-term: h bf16 exact, W split): h from swizzled stride-64 hbuf
__device__ __forceinline__ void layer_h2(const u16* hbuf,
                                         const u16* wh, const u16* wl,
                                         f32x4* acc, int wv, int lane) {
    int q = lane >> 4, l = lane & 15;
#pragma unroll
    for (int ks = 0; ks < 2; ++ks) {
        int k0 = ks * 32 + q * 8;
        bf16x8 b = wfrag64(hbuf, wv * 16 + l, k0);
#pragma unroll
        for (int ot = 0; ot < 4; ++ot) {
            bf16x8 ahi = wfrag64(wh, ot * 16 + l, k0);
            bf16x8 alo = wfrag64(wl, ot * 16 + l, k0);
            acc[ot] = __builtin_amdgcn_mfma_f32_16x16x32_bf16(ahi, b, acc[ot], 0, 0, 0);
            acc[ot] = __builtin_amdgcn_mfma_f32_16x16x32_bf16(alo, b, acc[ot], 0, 0, 0);
        }
    }
}
// f2 mult half (2-term: mult bf16 exact, W split), K-offset 64 of [64][128]
__device__ __forceinline__ void layer_m2_128(const u16* mb,
                                             const u16* wh, const u16* wl,
                                             f32x4* acc, int wv, int lane) {
    int q = lane >> 4, l = lane & 15;
#pragma unroll
    for (int ks = 0; ks < 2; ++ks) {
        int k0 = ks * 32 + q * 8;
        bf16x8 b = wfrag64(mb, wv * 16 + l, k0);
#pragma unroll
        for (int ot = 0; ot < 4; ++ot) {
            bf16x8 ahi = wfrag128(wh, ot * 16 + l, 64 + k0);
            bf16x8 alo = wfrag128(wl, ot * 16 + l, 64 + k0);
            acc[ot] = __builtin_amdgcn_mfma_f32_16x16x32_bf16(ahi, b, acc[ot], 0, 0, 0);
            acc[ot] = __builtin_amdgcn_mfma_f32_16x16x32_bf16(alo, b, acc[ot], 0, 0, 0);
        }
    }
}
// f2_rb0 mult (2-term: mult bf16 exact, W split [64][64])
__device__ __forceinline__ void layer_m2_64(const u16* mb,
                                            const u16* wh, const u16* wl,
                                            f32x4* acc, int wv, int lane) {
    int q = lane >> 4, l = lane & 15;
#pragma unroll
    for (int ks = 0; ks < 2; ++ks) {
        int k0 = ks * 32 + q * 8;
        bf16x8 b = wfrag64(mb, wv * 16 + l, k0);
#pragma unroll
        for (int ot = 0; ot < 4; ++ot) {
            bf16x8 ahi = wfrag64(wh, ot * 16 + l, k0);
            bf16x8 alo = wfrag64(wl, ot * 16 + l, k0);
            acc[ot] = __builtin_amdgcn_mfma_f32_16x16x32_bf16(ahi, b, acc[ot], 0, 0, 0);
            acc[ot] = __builtin_amdgcn_mfma_f32_16x16x32_bf16(alo, b, acc[ot], 0, 0, 0);
        }
    }
}

// write h = relu(acc) as plain bf16 to SWIZZLED stride-64 own-band rows [px][o]
__device__ __forceinline__ void write_h_bf16(f32x4* acc, u16* hbuf, int wv, int lane) {
    int q = lane >> 4, l = lane & 15;
    int px = wv * 16 + l;
#pragma unroll
    for (int ot = 0; ot < 4; ++ot) {
#pragma unroll
        for (int jp = 0; jp < 2; ++jp) {
            int o = ot * 16 + q * 4 + jp * 2;
            int gaddr = px * 64 + (((o >> 3) ^ (px & 7)) << 3) + (o & 7);
            float v0 = acc[ot][jp * 2];     v0 = v0 > 0.f ? v0 : 0.f;
            float v1 = acc[ot][jp * 2 + 1]; v1 = v1 > 0.f ? v1 : 0.f;
            *(u32t*)&hbuf[gaddr] = (u32t)f2bs(v0) | ((u32t)f2bs(v1) << 16);
        }
    }
}

// store relu(acc) (D[o][px]) as plain bf16 to u16 NCHW plane set
__device__ __forceinline__ void write_m_bf16(f32x4* acc, u16* __restrict__ mh,
                                             int p0, int wv, int lane) {
    int q = lane >> 4, l = lane & 15;
    int px = p0 + wv * 16 + l;
#pragma unroll
    for (int ot = 0; ot < 4; ++ot)
#pragma unroll
        for (int j = 0; j < 4; ++j) {
            int o = ot * 16 + q * 4 + j;
            float v = acc[ot][j]; v = v > 0.f ? v : 0.f;
            mh[(size_t)o * NN + px] = f2bs(v);
        }
}

__device__ __forceinline__ void write_m_lin(f32x4* acc, float* __restrict__ mout,
                                            int p0, int wv, int lane) {
    int q = lane >> 4, l = lane & 15;
    int px = p0 + wv * 16 + l;
#pragma unroll
    for (int ot = 0; ot < 4; ++ot)
#pragma unroll
        for (int j = 0; j < 4; ++j) {
            int o = ot * 16 + q * 4 + j;
            mout[(size_t)o * NN + px] = acc[ot][j];
        }
}

// ---------------- f1 regular: z(NCHW fp32) -> m1,m2 (bf16 NCHW); 512 thr, 128 px/WG ----------------
__global__ __launch_bounds__(512, 3) void f1_reg(
    const float* __restrict__ z,
    const u16* __restrict__ wsh, const u16* __restrict__ wsl, int blk,
    const float* __restrict__ B1a, const float* __restrict__ B2a,
    const float* __restrict__ B1b, const float* __restrict__ B2b,
    u16* __restrict__ m1, u16* __restrict__ m2) {
    __shared__ u16 w1h[4096], w1l[4096], w2h[4096], w2l[4096];  // 32 KB
    __shared__ u16 hbuf[8192];                                  // 16 KB -> 48 KB total
    int bb = blockIdx.y, p0 = blockIdx.x * 128;
    int t = threadIdx.x, lane = t & 63, wv = t >> 6;            // wv 0..7
    int q = lane >> 4, l15 = lane & 15;
    size_t gofs = (size_t)bb * EMB * NN;
    const float* zp = z + gofs;
    const u16* Wbh = wsh + REG_BASE + blk * REG_STRIDE;
    const u16* Wbl = wsl + REG_BASE + blk * REG_STRIDE;

    bf16x8 zfh[2], zfl[2];
    zfrags_nchw(zp, p0 + wv * 16 + l15, q, zfh, zfl);

    stage_w64_512(Wbh, Wbl, w1h, w1l, t);               // W1A
    stage_w64_512(Wbh + 4096, Wbl + 4096, w2h, w2l, t); // W2A
    __syncthreads();

    f32x4 acc[4];
    init_bias(B1a, acc, lane);
    mfma_L1_64(zfh, zfl, w1h, w1l, acc, lane);
    write_h_bf16(acc, hbuf, wv, lane);
    init_bias(B2a, acc, lane);
    layer_h2(hbuf, w2h, w2l, acc, wv, lane);
    write_m_bf16(acc, m1 + gofs, p0, wv, lane);

    __syncthreads();
    stage_w64_512(Wbh + 8192, Wbl + 8192, w1h, w1l, t);    // W1B
    stage_w64_512(Wbh + 12288, Wbl + 12288, w2h, w2l, t);  // W2B
    __syncthreads();

    init_bias(B1b, acc, lane);
    mfma_L1_64(zfh, zfl, w1h, w1l, acc, lane);
    write_h_bf16(acc, hbuf, wv, lane);
    init_bias(B2b, acc, lane);
    layer_h2(hbuf, w2h, w2l, acc, wv, lane);
    write_m_bf16(acc, m2 + gofs, p0, wv, lane);
}

// ---------------- f1 rb0: adj -> m1,m2 (bf16); 512 thr, 128 px/WG; 1 barrier ----------------
__global__ __launch_bounds__(512, 3) void f1_rb0(
    const float* __restrict__ adj, int b_base,
    const float* __restrict__ w1a, const float* __restrict__ b1a,
    const float* __restrict__ w1b, const float* __restrict__ b1b,
    const u16* __restrict__ wsh, const u16* __restrict__ wsl,
    const float* __restrict__ B2a, const float* __restrict__ B2b,
    u16* __restrict__ m1, u16* __restrict__ m2) {
    __shared__ u16 w1h[4096], w1l[4096], w2h[4096], w2l[4096];
    __shared__ u16 hbuf[8192];
    int bb = blockIdx.y, p0 = blockIdx.x * 128;
    int t = threadIdx.x, lane = t & 63, wv = t >> 6;
    int q = lane >> 4, l15 = lane & 15;
    size_t gofs = (size_t)bb * EMB * NN;
    int pxl = wv * 16 + l15;
    float a = adj[(size_t)(b_base + bb) * NN + p0 + pxl];

    stage_w64_512(wsh + RB0_W2A, wsl + RB0_W2A, w1h, w1l, t);
    stage_w64_512(wsh + RB0_W2B, wsl + RB0_W2B, w2h, w2l, t);
#pragma unroll
    for (int it = 0; it < 8; ++it) {
        int o0 = it * 8 + q * 2;
        int gaddr = pxl * 64 + ((it ^ (pxl & 7)) << 3) + q * 2;
        float v0 = w1a[o0 * 2] * a + b1a[o0];             v0 = v0 > 0.f ? v0 : 0.f;
        float v1 = w1a[(o0 + 1) * 2] * a + b1a[o0 + 1];   v1 = v1 > 0.f ? v1 : 0.f;
        *(u32t*)&hbuf[gaddr] = (u32t)f2bs(v0) | ((u32t)f2bs(v1) << 16);
    }
    __syncthreads();

    f32x4 acc[4];
    init_bias(B2a, acc, lane);
    layer_h2(hbuf, w1h, w1l, acc, wv, lane);
    write_m_bf16(acc, m1 + gofs, p0, wv, lane);

#pragma unroll
    for (int it = 0; it < 8; ++it) {
        int o0 = it * 8 + q * 2;
        int gaddr = pxl * 64 + ((it ^ (pxl & 7)) << 3) + q * 2;
        float v0 = w1b[o0 * 2] * a + b1b[o0];             v0 = v0 > 0.f ? v0 : 0.f;
        float v1 = w1b[(o0 + 1) * 2] * a + b1b[o0 + 1];   v1 = v1 > 0.f ? v1 : 0.f;
        *(u32t*)&hbuf[gaddr] = (u32t)f2bs(v0) | ((u32t)f2bs(v1) << 16);
    }
    init_bias(B2b, acc, lane);
    layer_h2(hbuf, w2h, w2l, acc, wv, lane);
    write_m_bf16(acc, m2 + gofs, p0, wv, lane);
}

// ---------------- per-channel NxN matmul, plain bf16 MFMA; mult out bf16 (unchanged) ----------------
__device__ __forceinline__ int soff(int row, int g) {
    return row * 64 + ((g ^ (row & 7) ^ ((row >> 3) & 7)) << 3);
}

__global__ __launch_bounds__(512) void chanmm_mfma(
    const u16* __restrict__ m1, const u16* __restrict__ m2,
    u16* __restrict__ mult) {
    __shared__ u16 Ah[128 * 64];
    __shared__ u16 Bh[64 * 64];
    int t = threadIdx.x, lane = t & 63, wv = t >> 6;
    int l15 = lane & 15, q = lane >> 4;
    int wi = wv >> 1, wj = wv & 1;
    int tile = blockIdx.x;
    int itile = (tile >> 2) * 128, jtile = (tile & 3) * 64;
    int ch = blockIdx.y, bb = blockIdx.z;
    size_t pb = ((size_t)bb * EMB + ch) * NN;
    const u16* A_h = m1 + pb;
    const u16* B_h = m2 + pb;

    int a_i = t >> 3;
    int a_g = t & 7;
    int b_k = t >> 3;
    int b_j8 = (t & 7) * 8;

    int4 rAh0, rAh1, rBh;
#define LOADK(K0)                                                              \
    {                                                                          \
        int k0_ = (K0);                                                        \
        rAh0 = *(const int4*)&A_h[(itile + a_i) * N + k0_ + a_g * 8];          \
        rAh1 = *(const int4*)&A_h[(itile + 64 + a_i) * N + k0_ + a_g * 8];     \
        rBh  = *(const int4*)&B_h[(k0_ + b_k) * N + jtile + b_j8];             \
    }

    f32x4 acc[2][2] = {};
    LOADK(0);
#pragma unroll
    for (int s = 0; s < 4; ++s) {
        *(int4*)&Ah[soff(a_i, a_g)] = rAh0;
        *(int4*)&Ah[soff(a_i + 64, a_g)] = rAh1;
        {
            const u16* ph = (const u16*)&rBh;
            int G = b_k >> 3, kin = b_k & 7;
#pragma unroll
            for (int d = 0; d < 8; ++d) {
                int j = b_j8 + d;
                Bh[soff(j, G) + kin] = ph[d];
            }
        }
        __syncthreads();
        if (s < 3) LOADK((s + 1) * 64);
#pragma unroll
        for (int ks = 0; ks < 2; ++ks) {
            int g = ks * 4 + q;
            bf16x8 bhi[2];
#pragma unroll
            for (int jt = 0; jt < 2; ++jt) {
                int rj = wj * 32 + jt * 16 + l15;
                bhi[jt] = *(const bf16x8*)&Bh[soff(rj, g)];
            }
#pragma unroll
            for (int it = 0; it < 2; ++it) {
                int ri = wi * 32 + it * 16 + l15;
                bf16x8 ahi = *(const bf16x8*)&Ah[soff(ri, g)];
#pragma unroll
                for (int jt = 0; jt < 2; ++jt)
                    acc[it][jt] = __builtin_amdgcn_mfma_f32_16x16x32_bf16(ahi, bhi[jt], acc[it][jt], 0, 0, 0);
            }
        }
        __syncthreads();
    }
#undef LOADK
    u16* O = mult + pb;
#pragma unroll
    for (int it = 0; it < 2; ++it)
#pragma unroll
        for (int jt = 0; jt < 2; ++jt)
#pragma unroll
            for (int r = 0; r < 4; ++r) {
                int i = itile + wi * 32 + it * 16 + q * 4 + r;
                int j = jtile + wj * 32 + jt * 16 + l15;
                O[(size_t)i * N + j] = f2bs(acc[it][jt][r]);
            }
}

// ---------------- f2 regular: skip conv K=128 over [z || mult] -> z (in-place NCHW); 40 KB LDS ----------------
__global__ __launch_bounds__(256, 4) void f2_reg(
    const u16* __restrict__ mult,   // NCHW bf16
    const u16* __restrict__ wsh, const u16* __restrict__ wsl, int blk,
    const float* __restrict__ SB,
    float* __restrict__ z) {
    __shared__ u16 wh[8192], wl[8192];   // 32 KB
    __shared__ u16 mb[4096];             // 8 KB -> 40 KB total
    int bb = blockIdx.y, p0 = blockIdx.x * 64;
    int t = threadIdx.x, lane = t & 63, wv = t >> 6;
    int q = lane >> 4, l15 = lane & 15;
    const u16* mp = mult + (size_t)bb * EMB * NN;
    float* zp = z + (size_t)bb * EMB * NN;
    const u16* SWh = wsh + REG_BASE + blk * REG_STRIDE + 16384;
    const u16* SWl = wsl + REG_BASE + blk * REG_STRIDE + 16384;

    // z frags direct from NCHW fp32 (read before in-place overwrite)
    bf16x8 zfh[2], zfl[2];
    zfrags_nchw(zp, p0 + wv * 16 + l15, q, zfh, zfl);

    stage_w128s(SWh, SWl, wh, wl, t);
    stage_band_m(mp, p0, mb, wv, lane);           // wave-local bf16 mult band
    __syncthreads();                              // SW visible

    f32x4 acc[4];
    init_bias(SB, acc, lane);
    mfma_L1_128(zfh, zfl, wh, wl, 0, acc, lane);  // z half (k 0..63)
    layer_m2_128(mb, wh, wl, acc, wv, lane);      // mult half (k 64..127), 2-term
    write_m_lin(acc, zp, p0, wv, lane);
}

// ---------------- f2 rb0: skip conv K=64 (mult) + rank-1 adj term -> z; 24 KB LDS ----------------
__global__ __launch_bounds__(256, 4) void f2_rb0(
    const float* __restrict__ adj, int b_base,
    const u16* __restrict__ mult,   // NCHW bf16
    const u16* __restrict__ wsh, const u16* __restrict__ wsl,
    const float* __restrict__ SWf, const float* __restrict__ SB,
    float* __restrict__ z) {
    __shared__ u16 wh[4096], wl[4096];   // 16 KB
    __shared__ u16 mb[4096];             // 8 KB -> 24 KB
    int bb = blockIdx.y, p0 = blockIdx.x * 64;
    int t = threadIdx.x, lane = t & 63, wv = t >> 6;
    const u16* mp = mult + (size_t)bb * EMB * NN;
    float* zp = z + (size_t)bb * EMB * NN;

    stage_w64(wsh + RB0_SW, wsl + RB0_SW, wh, wl, t);
    stage_act_m(mp, p0, mb, t);
    __syncthreads();

    int q = lane >> 4, l = lane & 15;
    float a = adj[(size_t)(b_base + bb) * NN + p0 + wv * 16 + l];
    f32x4 acc[4];
#pragma unroll
    for (int ot = 0; ot < 4; ++ot)
#pragma unroll
        for (int j = 0; j < 4; ++j) {
            int o = ot * 16 + q * 4 + j;
            acc[ot][j] = SB[o] + SWf[o * 66] * a;
        }
    layer_m2_64(mb, wh, wl, acc, wv, lane);
    write_m_lin(acc, zp, p0, wv, lane);
}

// ---------------- pooling partials (float4 loads, branch-free diag) ----------------
__global__ void pool(const float* __restrict__ z, float* __restrict__ sums, int b_base) {
    int bb = blockIdx.x;
    int c = blockIdx.y;
    size_t base = ((size_t)bb * EMB + c) * NN;
    const float4* z4 = (const float4*)(z + base);
    int t = threadIdx.x;
    float s = 0.0f;
#pragma unroll 4
    for (int it = 0; it < 64; ++it) {
        float4 v = z4[it * 256 + t];
        s += v.x + v.y + v.z + v.w;
    }
    float d = z[base + (size_t)t * 257];
    for (int off = 32; off > 0; off >>= 1) {
        s += __shfl_down(s, off);
        d += __shfl_down(d, off);
    }
    __shared__ float ls[4], ld[4];
    int wid = t >> 6;
    if ((t & 63) == 0) { ls[wid] = s; ld[wid] = d; }
    __syncthreads();
    if (t == 0) {
        s = ls[0] + ls[1] + ls[2] + ls[3];
        d = ld[0] + ld[1] + ld[2] + ld[3];
        int b = b_base + bb;
        sums[b * EMB + c] = s;
        sums[BATCH * EMB + b * EMB + c] = d;
    }
}

// ---------------- final pooled FC ----------------
__global__ void fc(const float* __restrict__ sums,
                   const float* __restrict__ fcw1, const float* __restrict__ fcb1,
                   const float* __restrict__ fcw2, const float* __restrict__ fcb2,
                   float* __restrict__ out) {
    int b = blockIdx.x;
    __shared__ float h[128];
    __shared__ float hh2[64];
    int t = threadIdx.x;
    if (t < 64) {
        h[t] = sums[BATCH * EMB + b * EMB + t] / (float)N;
    } else {
        int c = t - 64;
        float sall = sums[b * EMB + c];
        float sd = sums[BATCH * EMB + b * EMB + c];
        h[t] = (sall - sd) / (float)(N * (N - 1));
    }
    __syncthreads();
    if (t < 64) {
        float acc = fcb1[t];
        for (int k = 0; k < 128; ++k) acc += fcw1[t * 128 + k] * h[k];
        hh2[t] = acc > 0.0f ? acc : 0.0f;
    }
    __syncthreads();
    if (t == 0) {
        float acc = fcb2[0];
        for (int k = 0; k < 64; ++k) acc += fcw2[k] * hh2[k];
        out[b] = acc;
    }
}

extern "C" void kernel_launch(void* const* d_in, const int* in_sizes, int n_in,
                              void* d_out, int out_size, void* d_ws, size_t ws_size,
                              hipStream_t stream) {
    const int* ei       = (const int*)d_in[0];
    const int* batchv   = (const int*)d_in[1];
    const float* rb0_m1w1 = (const float*)d_in[2];
    const float* rb0_m1b1 = (const float*)d_in[3];
    const float* rb0_m1w2 = (const float*)d_in[4];
    const float* rb0_m1b2 = (const float*)d_in[5];
    const float* rb0_m2w1 = (const float*)d_in[6];
    const float* rb0_m2b1 = (const float*)d_in[7];
    const float* rb0_m2w2 = (const float*)d_in[8];
    const float* rb0_m2b2 = (const float*)d_in[9];
    const float* rb0_sw   = (const float*)d_in[10];
    const float* rb0_sb   = (const float*)d_in[11];
    const float* rb_m1w1  = (const float*)d_in[12];
    const float* rb_m1b1  = (const float*)d_in[13];
    const float* rb_m1w2  = (const float*)d_in[14];
    const float* rb_m1b2  = (const float*)d_in[15];
    const float* rb_m2w1  = (const float*)d_in[16];
    const float* rb_m2b1  = (const float*)d_in[17];
    const float* rb_m2w2  = (const float*)d_in[18];
    const float* rb_m2b2  = (const float*)d_in[19];
    const float* rb_sw    = (const float*)d_in[20];
    const float* rb_sb    = (const float*)d_in[21];
    const float* fcw1     = (const float*)d_in[22];
    const float* fcb1     = (const float*)d_in[23];
    const float* fcw2     = (const float*)d_in[24];
    const float* fcb2     = (const float*)d_in[25];

    const size_t P = (size_t)EMB * NN;               // 4,194,304 elems
    const size_t WB = (size_t)WSPLIT_ELEMS * 2ull;
    const size_t fixedBytes = 524288ull * 4ull + 4096ull + 2ull * WB;
    const size_t perGraphBytes = 2ull * P * 2ull + P * 2ull + P * 4ull;
    int g = BATCH;
    while (g > 1) {
        if (fixedBytes + (size_t)g * perGraphBytes <= ws_size) break;
        g >>= 1;
    }

    char* w = (char*)d_ws;
    float* adj   = (float*)w;  w += 524288ull * 4ull;
    float* sums  = (float*)w;  w += 4096;
    u16* wsh     = (u16*)w;    w += WB;
    u16* wsl     = (u16*)w;    w += WB;
    u16* m1      = (u16*)w;    w += (size_t)g * P * 2ull;
    u16* m2      = (u16*)w;    w += (size_t)g * P * 2ull;
    u16* mult    = (u16*)w;    w += (size_t)g * P * 2ull;
    float* znchw = (float*)w;  w += (size_t)g * P * 4ull;

    hipMemsetAsync(adj, 0, 524288ull * 4ull, stream);
    scatter_adj<<<NEDGE / 256, 256, 0, stream>>>(ei, batchv, adj);
    prep_w<<<(WSPLIT_ELEMS + 255) / 256, 256, 0, stream>>>(
        rb0_m1w2, rb0_m2w2, rb0_sw, rb_m1w1, rb_m1w2, rb_m2w1, rb_m2w2, rb_sw, wsh, wsl);

    for (int b_base = 0; b_base < BATCH; b_base += g) {
        dim3 gridE(NN / 64, g);
        dim3 gridF(NN / 128, g);
        dim3 gridM(8, EMB, g);

        f1_rb0<<<gridF, 512, 0, stream>>>(adj, b_base,
            rb0_m1w1, rb0_m1b1, rb0_m2w1, rb0_m2b1,
            wsh, wsl, rb0_m1b2, rb0_m2b2, m1, m2);
        chanmm_mfma<<<gridM, 512, 0, stream>>>(m1, m2, mult);
        f2_rb0<<<gridE, 256, 0, stream>>>(adj, b_base, mult, wsh, wsl, rb0_sw, rb0_sb, znchw);

        for (int i = 0; i < 3; ++i) {
            f1_reg<<<gridF, 512, 0, stream>>>(znchw, wsh, wsl, i,
                rb_m1b1 + i * 64, rb_m1b2 + i * 64,
                rb_m2b1 + i * 64, rb_m2b2 + i * 64,
                m1, m2);
            chanmm_mfma<<<gridM, 512, 0, stream>>>(m1, m2, mult);
            f2_reg<<<gridE, 256, 0, stream>>>(mult, wsh, wsl, i, rb_sb + i * 64, znchw);
        }

        pool<<<dim3(g, EMB), 256, 0, stream>>>(znchw, sums, b_base);
    }
    fc<<<BATCH, 128, 0, stream>>>(sums, fcw1, fcb1, fcw2, fcb2, (float*)d_out);
}

// Round 25
// 818.240 us; speedup vs baseline: 1.1298x; 1.0027x over previous
//
#include <hip/hip_runtime.h>

#define N 256
#define NN 65536
#define EMB 64
#define BATCH 8
#define NEDGE 32768

typedef unsigned short u16;
typedef unsigned int u32t;
typedef __attribute__((ext_vector_type(8))) short bf16x8;
typedef __attribute__((ext_vector_type(4))) float f32x4;

// pre-split weight buffer offsets (u16 elements)
#define RB0_W2A 0
#define RB0_W2B 4096
#define RB0_SW  8192
#define REG_BASE 12288
#define REG_STRIDE 24576   // per regular block: W1A,W2A,W1B,W2B (4096 each) + SW (8192)
#define WSPLIT_ELEMS 86016

static __device__ __forceinline__ u16 f2bs(float f) {
    u32t u = __float_as_uint(f);
    u32t r = (u + 0x7FFFu + ((u >> 16) & 1u)) >> 16;
    return (u16)r;
}
static __device__ __forceinline__ float b2f(u16 s) {
    return __uint_as_float(((u32t)s) << 16);
}
static __device__ __forceinline__ void split_bf(float a, u16& hi, u16& lo) {
    hi = f2bs(a);
    float r = a - b2f(hi);
    lo = f2bs(r);
}

// ---------------- adjacency scatter ----------------
__global__ void scatter_adj(const int* __restrict__ ei, const int* __restrict__ batch,
                            float* __restrict__ adj) {
    int e = blockIdx.x * blockDim.x + threadIdx.x;
    if (e >= NEDGE) return;
    int src = ei[e];
    int dst = ei[NEDGE + e];
    int g = batch[src];
    int lu = src - g * N;
    int lv = dst - g * N;
    atomicAdd(&adj[(size_t)g * NN + (size_t)lu * N + lv], 1.0f);
}

// ---------------- one-time weight pre-split ----------------
__global__ void prep_w(const float* __restrict__ rb0_m1w2, const float* __restrict__ rb0_m2w2,
                       const float* __restrict__ rb0_sw,
                       const float* __restrict__ rb_m1w1, const float* __restrict__ rb_m1w2,
                       const float* __restrict__ rb_m2w1, const float* __restrict__ rb_m2w2,
                       const float* __restrict__ rb_sw,
                       u16* __restrict__ wh, u16* __restrict__ wl) {
    int idx = blockIdx.x * 256 + threadIdx.x;
    if (idx >= WSPLIT_ELEMS) return;
    float v;
    if (idx < 4096) v = rb0_m1w2[idx];
    else if (idx < 8192) v = rb0_m2w2[idx - 4096];
    else if (idx < 12288) { int e = idx - 8192; v = rb0_sw[(e >> 6) * 66 + 2 + (e & 63)]; }
    else {
        int e = idx - REG_BASE;
        int blk = e / REG_STRIDE, r = e % REG_STRIDE;
        if (r < 4096) v = rb_m1w1[blk * 4096 + r];
        else if (r < 8192) v = rb_m1w2[blk * 4096 + r - 4096];
        else if (r < 12288) v = rb_m2w1[blk * 4096 + r - 8192];
        else if (r < 16384) v = rb_m2w2[blk * 4096 + r - 12288];
        else v = rb_sw[blk * 8192 + r - 16384];
    }
    u16 h, l;
    split_bf(v, h, l);
    wh[idx] = h; wl[idx] = l;
}

// ================= engine building blocks =================

// 512-thread stage of [64][64] pre-split W into XOR-swizzled LDS
__device__ __forceinline__ void stage_w64_512(const u16* __restrict__ Wh, const u16* __restrict__ Wl,
                                              u16* dh, u16* dl, int t) {
    int row = t >> 3, g = t & 7;
    int4 vh = *(const int4*)&Wh[row * 64 + g * 8];
    int4 vl = *(const int4*)&Wl[row * 64 + g * 8];
    int d = row * 64 + ((g ^ (row & 7)) << 3);
    *(int4*)&dh[d] = vh;
    *(int4*)&dl[d] = vl;
}
// 512-thread stage of [64][128] pre-split W into XOR-swizzled LDS
__device__ __forceinline__ void stage_w128s_512(const u16* __restrict__ Wh, const u16* __restrict__ Wl,
                                                u16* dh, u16* dl, int t) {
#pragma unroll
    for (int it = 0; it < 2; ++it) {
        int idx = it * 512 + t;
        int row = idx >> 4, g = idx & 15;
        int4 vh = *(const int4*)&Wh[row * 128 + g * 8];
        int4 vl = *(const int4*)&Wl[row * 128 + g * 8];
        int d = row * 128 + ((g ^ (row & 7)) << 3);
        *(int4*)&dh[d] = vh;
        *(int4*)&dl[d] = vl;
    }
}
__device__ __forceinline__ bf16x8 wfrag64(const u16* w, int row, int k0) {
    int g = k0 >> 3;
    return *(const bf16x8*)&w[row * 64 + ((g ^ (row & 7)) << 3)];
}
__device__ __forceinline__ bf16x8 wfrag128(const u16* w, int row, int k0) {
    int g = k0 >> 3;
    return *(const bf16x8*)&w[row * 128 + ((g ^ (row & 7)) << 3)];
}

// wave-local: stage this wave's 16-px band of bf16 mult (NCHW u16) into swizzled stride-64 rows
__device__ __forceinline__ void stage_band_m(const u16* __restrict__ src, int p0,
                                             u16* mb, int wband, int lane) {
    int q = lane >> 4, l15 = lane & 15;
    int px = wband * 16 + l15;
    int gpx = p0 + px;
#pragma unroll
    for (int it = 0; it < 8; ++it) {
        int c0 = it * 8 + q * 2;
        u16 v0 = src[(size_t)c0 * NN + gpx];
        u16 v1 = src[(size_t)(c0 + 1) * NN + gpx];
        int gaddr = px * 64 + ((it ^ (px & 7)) << 3) + q * 2;
        *(u32t*)&mb[gaddr] = (u32t)v0 | ((u32t)v1 << 16);
    }
}

// build this lane's z fragments (hi/lo) directly from NCHW fp32 global
__device__ __forceinline__ void zfrags_nchw(const float* __restrict__ zp, int px,
                                            int q, bf16x8 zfh[2], bf16x8 zfl[2]) {
#pragma unroll
    for (int ks = 0; ks < 2; ++ks)
#pragma unroll
        for (int j = 0; j < 8; ++j) {
            float v = zp[(size_t)(ks * 32 + q * 8 + j) * NN + px];
            u16 h, l; split_bf(v, h, l);
            zfh[ks][j] = (short)h;
            zfl[ks][j] = (short)l;
        }
}

__device__ __forceinline__ void init_bias(const float* __restrict__ Bb, f32x4* acc, int lane) {
    int q = lane >> 4;
#pragma unroll
    for (int ot = 0; ot < 4; ++ot)
#pragma unroll
        for (int j = 0; j < 4; ++j)
            acc[ot][j] = Bb[ot * 16 + q * 4 + j];
}

// f1 L1 (3-term: z split exact, W split): D[o][px] += W[o][k] * z[px][k]
__device__ __forceinline__ void mfma_L1_64(bf16x8 zfh[2], bf16x8 zfl[2],
                                           const u16* wh, const u16* wl,
                                           f32x4* acc, int lane) {
    int q = lane >> 4, l = lane & 15;
#pragma unroll
    for (int ks = 0; ks < 2; ++ks) {
        int k0 = ks * 32 + q * 8;
#pragma unroll
        for (int ot = 0; ot < 4; ++ot) {
            bf16x8 ahi = wfrag64(wh, ot * 16 + l, k0);
            bf16x8 alo = wfrag64(wl, ot * 16 + l, k0);
            acc[ot] = __builtin_amdgcn_mfma_f32_16x16x32_bf16(ahi, zfh[ks], acc[ot], 0, 0, 0);
            acc[ot] = __builtin_amdgcn_mfma_f32_16x16x32_bf16(ahi, zfl[ks], acc[ot], 0, 0, 0);
            acc[ot] = __builtin_amdgcn_mfma_f32_16x16x32_bf16(alo, zfh[ks], acc[ot], 0, 0, 0);
        }
    }
}
// f2 L1, W split (3-term), K-half of [64][128]
__device__ __forceinline__ void mfma_L1_128(bf16x8 zfh[2], bf16x8 zfl[2],
                                            const u16* wh, const u16* wl, int ak0,
                                            f32x4* acc, int lane) {
    int q = lane >> 4, l = lane & 15;
#pragma unroll
    for (int ks = 0; ks < 2; ++ks) {
        int k0 = ks * 32 + q * 8;
#pragma unroll
        for (int ot = 0; ot < 4; ++ot) {
            bf16x8 ahi = wfrag128(wh, ot * 16 + l, ak0 + k0);
            bf16x8 alo = wfrag128(wl, ot * 16 + l, ak0 + k0);
            acc[ot] = __builtin_amdgcn_mfma_f32_16x16x32_bf16(ahi, zfh[ks], acc[ot], 0, 0, 0);
            acc[ot] = __builtin_amdgcn_mfma_f32_16x16x32_bf16(ahi, zfl[ks], acc[ot], 0, 0, 0);
            acc[ot] = __builtin_amdgcn_mfma_f32_16x16x32_bf16(alo, zfh[ks], acc[ot], 0, 0, 0);
        }
    }
}

// f1 L2 (2-term: h bf16 exact, W split): h from swizzled stride-64 hbuf
__device__ __forceinline__ void layer_h2(const u16* hbuf,
                                         const u16* wh, const u16* wl,
                                         f32x4* acc, int wv, int lane) {
    int q = lane >> 4, l = lane & 15;
#pragma unroll
    for (int ks = 0; ks < 2; ++ks) {
        int k0 = ks * 32 + q * 8;
        bf16x8 b = wfrag64(hbuf, wv * 16 + l, k0);
#pragma unroll
        for (int ot = 0; ot < 4; ++ot) {
            bf16x8 ahi = wfrag64(wh, ot * 16 + l, k0);
            bf16x8 alo = wfrag64(wl, ot * 16 + l, k0);
            acc[ot] = __builtin_amdgcn_mfma_f32_16x16x32_bf16(ahi, b, acc[ot], 0, 0, 0);
            acc[ot] = __builtin_amdgcn_mfma_f32_16x16x32_bf16(alo, b, acc[ot], 0, 0, 0);
        }
    }
}
// f2 mult half (2-term), K-offset 64 of [64][128]
__device__ __forceinline__ void layer_m2_128(const u16* mb,
                                             const u16* wh, const u16* wl,
                                             f32x4* acc, int wv, int lane) {
    int q = lane >> 4, l = lane & 15;
#pragma unroll
    for (int ks = 0; ks < 2; ++ks) {
        int k0 = ks * 32 + q * 8;
        bf16x8 b = wfrag64(mb, wv * 16 + l, k0);
#pragma unroll
        for (int ot = 0; ot < 4; ++ot) {
            bf16x8 ahi = wfrag128(wh, ot * 16 + l, 64 + k0);
            bf16x8 alo = wfrag128(wl, ot * 16 + l, 64 + k0);
            acc[ot] = __builtin_amdgcn_mfma_f32_16x16x32_bf16(ahi, b, acc[ot], 0, 0, 0);
            acc[ot] = __builtin_amdgcn_mfma_f32_16x16x32_bf16(alo, b, acc[ot], 0, 0, 0);
        }
    }
}
// f2_rb0 mult (2-term, W split [64][64])
__device__ __forceinline__ void layer_m2_64(const u16* mb,
                                            const u16* wh, const u16* wl,
                                            f32x4* acc, int wv, int lane) {
    int q = lane >> 4, l = lane & 15;
#pragma unroll
    for (int ks = 0; ks < 2; ++ks) {
        int k0 = ks * 32 + q * 8;
        bf16x8 b = wfrag64(mb, wv * 16 + l, k0);
#pragma unroll
        for (int ot = 0; ot < 4; ++ot) {
            bf16x8 ahi = wfrag64(wh, ot * 16 + l, k0);
            bf16x8 alo = wfrag64(wl, ot * 16 + l, k0);
            acc[ot] = __builtin_amdgcn_mfma_f32_16x16x32_bf16(ahi, b, acc[ot], 0, 0, 0);
            acc[ot] = __builtin_amdgcn_mfma_f32_16x16x32_bf16(alo, b, acc[ot], 0, 0, 0);
        }
    }
}

// write h = relu(acc) as plain bf16 to SWIZZLED stride-64 own-band rows [px][o]
__device__ __forceinline__ void write_h_bf16(f32x4* acc, u16* hbuf, int wv, int lane) {
    int q = lane >> 4, l = lane & 15;
    int px = wv * 16 + l;
#pragma unroll
    for (int ot = 0; ot < 4; ++ot) {
#pragma unroll
        for (int jp = 0; jp < 2; ++jp) {
            int o = ot * 16 + q * 4 + jp * 2;
            int gaddr = px * 64 + (((o >> 3) ^ (px & 7)) << 3) + (o & 7);
            float v0 = acc[ot][jp * 2];     v0 = v0 > 0.f ? v0 : 0.f;
            float v1 = acc[ot][jp * 2 + 1]; v1 = v1 > 0.f ? v1 : 0.f;
            *(u32t*)&hbuf[gaddr] = (u32t)f2bs(v0) | ((u32t)f2bs(v1) << 16);
        }
    }
}

// store relu(acc) (D[o][px]) as plain bf16 to u16 NCHW plane set
__device__ __forceinline__ void write_m_bf16(f32x4* acc, u16* __restrict__ mh,
                                             int p0, int wv, int lane) {
    int q = lane >> 4, l = lane & 15;
    int px = p0 + wv * 16 + l;
#pragma unroll
    for (int ot = 0; ot < 4; ++ot)
#pragma unroll
        for (int j = 0; j < 4; ++j) {
            int o = ot * 16 + q * 4 + j;
            float v = acc[ot][j]; v = v > 0.f ? v : 0.f;
            mh[(size_t)o * NN + px] = f2bs(v);
        }
}

__device__ __forceinline__ void write_m_lin(f32x4* acc, float* __restrict__ mout,
                                            int p0, int wv, int lane) {
    int q = lane >> 4, l = lane & 15;
    int px = p0 + wv * 16 + l;
#pragma unroll
    for (int ot = 0; ot < 4; ++ot)
#pragma unroll
        for (int j = 0; j < 4; ++j) {
            int o = ot * 16 + q * 4 + j;
            mout[(size_t)o * NN + px] = acc[ot][j];
        }
}

// ---------------- f1 regular: z(NCHW fp32) -> m1,m2 (bf16 NCHW); 512 thr, 128 px/WG ----------------
__global__ __launch_bounds__(512, 3) void f1_reg(
    const float* __restrict__ z,
    const u16* __restrict__ wsh, const u16* __restrict__ wsl, int blk,
    const float* __restrict__ B1a, const float* __restrict__ B2a,
    const float* __restrict__ B1b, const float* __restrict__ B2b,
    u16* __restrict__ m1, u16* __restrict__ m2) {
    __shared__ u16 w1h[4096], w1l[4096], w2h[4096], w2l[4096];  // 32 KB
    __shared__ u16 hbuf[8192];                                  // 16 KB -> 48 KB total
    int bb = blockIdx.y, p0 = blockIdx.x * 128;
    int t = threadIdx.x, lane = t & 63, wv = t >> 6;
    int q = lane >> 4, l15 = lane & 15;
    size_t gofs = (size_t)bb * EMB * NN;
    const float* zp = z + gofs;
    const u16* Wbh = wsh + REG_BASE + blk * REG_STRIDE;
    const u16* Wbl = wsl + REG_BASE + blk * REG_STRIDE;

    bf16x8 zfh[2], zfl[2];
    zfrags_nchw(zp, p0 + wv * 16 + l15, q, zfh, zfl);

    stage_w64_512(Wbh, Wbl, w1h, w1l, t);               // W1A
    stage_w64_512(Wbh + 4096, Wbl + 4096, w2h, w2l, t); // W2A
    __syncthreads();

    f32x4 acc[4];
    init_bias(B1a, acc, lane);
    mfma_L1_64(zfh, zfl, w1h, w1l, acc, lane);
    write_h_bf16(acc, hbuf, wv, lane);
    init_bias(B2a, acc, lane);
    layer_h2(hbuf, w2h, w2l, acc, wv, lane);
    write_m_bf16(acc, m1 + gofs, p0, wv, lane);

    __syncthreads();
    stage_w64_512(Wbh + 8192, Wbl + 8192, w1h, w1l, t);    // W1B
    stage_w64_512(Wbh + 12288, Wbl + 12288, w2h, w2l, t);  // W2B
    __syncthreads();

    init_bias(B1b, acc, lane);
    mfma_L1_64(zfh, zfl, w1h, w1l, acc, lane);
    write_h_bf16(acc, hbuf, wv, lane);
    init_bias(B2b, acc, lane);
    layer_h2(hbuf, w2h, w2l, acc, wv, lane);
    write_m_bf16(acc, m2 + gofs, p0, wv, lane);
}

// ---------------- f1 rb0: adj -> m1,m2 (bf16); 512 thr, 128 px/WG; 1 barrier ----------------
__global__ __launch_bounds__(512, 3) void f1_rb0(
    const float* __restrict__ adj, int b_base,
    const float* __restrict__ w1a, const float* __restrict__ b1a,
    const float* __restrict__ w1b, const float* __restrict__ b1b,
    const u16* __restrict__ wsh, const u16* __restrict__ wsl,
    const float* __restrict__ B2a, const float* __restrict__ B2b,
    u16* __restrict__ m1, u16* __restrict__ m2) {
    __shared__ u16 w1h[4096], w1l[4096], w2h[4096], w2l[4096];
    __shared__ u16 hbuf[8192];
    int bb = blockIdx.y, p0 = blockIdx.x * 128;
    int t = threadIdx.x, lane = t & 63, wv = t >> 6;
    int q = lane >> 4, l15 = lane & 15;
    size_t gofs = (size_t)bb * EMB * NN;
    int pxl = wv * 16 + l15;
    float a = adj[(size_t)(b_base + bb) * NN + p0 + pxl];

    stage_w64_512(wsh + RB0_W2A, wsl + RB0_W2A, w1h, w1l, t);
    stage_w64_512(wsh + RB0_W2B, wsl + RB0_W2B, w2h, w2l, t);
#pragma unroll
    for (int it = 0; it < 8; ++it) {
        int o0 = it * 8 + q * 2;
        int gaddr = pxl * 64 + ((it ^ (pxl & 7)) << 3) + q * 2;
        float v0 = w1a[o0 * 2] * a + b1a[o0];             v0 = v0 > 0.f ? v0 : 0.f;
        float v1 = w1a[(o0 + 1) * 2] * a + b1a[o0 + 1];   v1 = v1 > 0.f ? v1 : 0.f;
        *(u32t*)&hbuf[gaddr] = (u32t)f2bs(v0) | ((u32t)f2bs(v1) << 16);
    }
    __syncthreads();

    f32x4 acc[4];
    init_bias(B2a, acc, lane);
    layer_h2(hbuf, w1h, w1l, acc, wv, lane);
    write_m_bf16(acc, m1 + gofs, p0, wv, lane);

#pragma unroll
    for (int it = 0; it < 8; ++it) {
        int o0 = it * 8 + q * 2;
        int gaddr = pxl * 64 + ((it ^ (pxl & 7)) << 3) + q * 2;
        float v0 = w1b[o0 * 2] * a + b1b[o0];             v0 = v0 > 0.f ? v0 : 0.f;
        float v1 = w1b[(o0 + 1) * 2] * a + b1b[o0 + 1];   v1 = v1 > 0.f ? v1 : 0.f;
        *(u32t*)&hbuf[gaddr] = (u32t)f2bs(v0) | ((u32t)f2bs(v1) << 16);
    }
    init_bias(B2b, acc, lane);
    layer_h2(hbuf, w2h, w2l, acc, wv, lane);
    write_m_bf16(acc, m2 + gofs, p0, wv, lane);
}

// ---------------- per-channel NxN matmul, plain bf16 MFMA; mult out bf16 (unchanged) ----------------
__device__ __forceinline__ int soff(int row, int g) {
    return row * 64 + ((g ^ (row & 7) ^ ((row >> 3) & 7)) << 3);
}

__global__ __launch_bounds__(512) void chanmm_mfma(
    const u16* __restrict__ m1, const u16* __restrict__ m2,
    u16* __restrict__ mult) {
    __shared__ u16 Ah[128 * 64];
    __shared__ u16 Bh[64 * 64];
    int t = threadIdx.x, lane = t & 63, wv = t >> 6;
    int l15 = lane & 15, q = lane >> 4;
    int wi = wv >> 1, wj = wv & 1;
    int tile = blockIdx.x;
    int itile = (tile >> 2) * 128, jtile = (tile & 3) * 64;
    int ch = blockIdx.y, bb = blockIdx.z;
    size_t pb = ((size_t)bb * EMB + ch) * NN;
    const u16* A_h = m1 + pb;
    const u16* B_h = m2 + pb;

    int a_i = t >> 3;
    int a_g = t & 7;
    int b_k = t >> 3;
    int b_j8 = (t & 7) * 8;

    int4 rAh0, rAh1, rBh;
#define LOADK(K0)                                                              \
    {                                                                          \
        int k0_ = (K0);                                                        \
        rAh0 = *(const int4*)&A_h[(itile + a_i) * N + k0_ + a_g * 8];          \
        rAh1 = *(const int4*)&A_h[(itile + 64 + a_i) * N + k0_ + a_g * 8];     \
        rBh  = *(const int4*)&B_h[(k0_ + b_k) * N + jtile + b_j8];             \
    }

    f32x4 acc[2][2] = {};
    LOADK(0);
#pragma unroll
    for (int s = 0; s < 4; ++s) {
        *(int4*)&Ah[soff(a_i, a_g)] = rAh0;
        *(int4*)&Ah[soff(a_i + 64, a_g)] = rAh1;
        {
            const u16* ph = (const u16*)&rBh;
            int G = b_k >> 3, kin = b_k & 7;
#pragma unroll
            for (int d = 0; d < 8; ++d) {
                int j = b_j8 + d;
                Bh[soff(j, G) + kin] = ph[d];
            }
        }
        __syncthreads();
        if (s < 3) LOADK((s + 1) * 64);
#pragma unroll
        for (int ks = 0; ks < 2; ++ks) {
            int g = ks * 4 + q;
            bf16x8 bhi[2];
#pragma unroll
            for (int jt = 0; jt < 2; ++jt) {
                int rj = wj * 32 + jt * 16 + l15;
                bhi[jt] = *(const bf16x8*)&Bh[soff(rj, g)];
            }
#pragma unroll
            for (int it = 0; it < 2; ++it) {
                int ri = wi * 32 + it * 16 + l15;
                bf16x8 ahi = *(const bf16x8*)&Ah[soff(ri, g)];
#pragma unroll
                for (int jt = 0; jt < 2; ++jt)
                    acc[it][jt] = __builtin_amdgcn_mfma_f32_16x16x32_bf16(ahi, bhi[jt], acc[it][jt], 0, 0, 0);
            }
        }
        __syncthreads();
    }
#undef LOADK
    u16* O = mult + pb;
#pragma unroll
    for (int it = 0; it < 2; ++it)
#pragma unroll
        for (int jt = 0; jt < 2; ++jt)
#pragma unroll
            for (int r = 0; r < 4; ++r) {
                int i = itile + wi * 32 + it * 16 + q * 4 + r;
                int j = jtile + wj * 32 + jt * 16 + l15;
                O[(size_t)i * N + j] = f2bs(acc[it][jt][r]);
            }
}

// ---------------- f2 regular: skip conv K=128 -> z (in-place NCHW); 512 thr, 128 px/WG ----------------
__global__ __launch_bounds__(512, 3) void f2_reg(
    const u16* __restrict__ mult,   // NCHW bf16
    const u16* __restrict__ wsh, const u16* __restrict__ wsl, int blk,
    const float* __restrict__ SB,
    float* __restrict__ z) {
    __shared__ u16 wh[8192], wl[8192];   // 32 KB
    __shared__ u16 mb[8192];             // 16 KB -> 48 KB total
    int bb = blockIdx.y, p0 = blockIdx.x * 128;
    int t = threadIdx.x, lane = t & 63, wv = t >> 6;
    int q = lane >> 4, l15 = lane & 15;
    const u16* mp = mult + (size_t)bb * EMB * NN;
    float* zp = z + (size_t)bb * EMB * NN;
    const u16* SWh = wsh + REG_BASE + blk * REG_STRIDE + 16384;
    const u16* SWl = wsl + REG_BASE + blk * REG_STRIDE + 16384;

    // z frags direct from NCHW fp32 (read before in-place overwrite)
    bf16x8 zfh[2], zfl[2];
    zfrags_nchw(zp, p0 + wv * 16 + l15, q, zfh, zfl);

    stage_w128s_512(SWh, SWl, wh, wl, t);
    stage_band_m(mp, p0, mb, wv, lane);           // wave-local bf16 mult band
    __syncthreads();                              // SW visible

    f32x4 acc[4];
    init_bias(SB, acc, lane);
    mfma_L1_128(zfh, zfl, wh, wl, 0, acc, lane);  // z half (k 0..63)
    layer_m2_128(mb, wh, wl, acc, wv, lane);      // mult half (k 64..127), 2-term
    write_m_lin(acc, zp, p0, wv, lane);
}

// ---------------- f2 rb0: skip conv K=64 (mult) + rank-1 adj -> z; 512 thr, 128 px/WG ----------------
__global__ __launch_bounds__(512, 3) void f2_rb0(
    const float* __restrict__ adj, int b_base,
    const u16* __restrict__ mult,   // NCHW bf16
    const u16* __restrict__ wsh, const u16* __restrict__ wsl,
    const float* __restrict__ SWf, const float* __restrict__ SB,
    float* __restrict__ z) {
    __shared__ u16 wh[4096], wl[4096];   // 16 KB
    __shared__ u16 mb[8192];             // 16 KB -> 32 KB total
    int bb = blockIdx.y, p0 = blockIdx.x * 128;
    int t = threadIdx.x, lane = t & 63, wv = t >> 6;
    int q = lane >> 4, l15 = lane & 15;
    const u16* mp = mult + (size_t)bb * EMB * NN;
    float* zp = z + (size_t)bb * EMB * NN;

    stage_w64_512(wsh + RB0_SW, wsl + RB0_SW, wh, wl, t);
    stage_band_m(mp, p0, mb, wv, lane);
    __syncthreads();

    float a = adj[(size_t)(b_base + bb) * NN + p0 + wv * 16 + l15];
    f32x4 acc[4];
#pragma unroll
    for (int ot = 0; ot < 4; ++ot)
#pragma unroll
        for (int j = 0; j < 4; ++j) {
            int o = ot * 16 + q * 4 + j;
            acc[ot][j] = SB[o] + SWf[o * 66] * a;
        }
    layer_m2_64(mb, wh, wl, acc, wv, lane);
    write_m_lin(acc, zp, p0, wv, lane);
}

// ---------------- pooling partials (float4 loads, branch-free diag) ----------------
__global__ void pool(const float* __restrict__ z, float* __restrict__ sums, int b_base) {
    int bb = blockIdx.x;
    int c = blockIdx.y;
    size_t base = ((size_t)bb * EMB + c) * NN;
    const float4* z4 = (const float4*)(z + base);
    int t = threadIdx.x;
    float s = 0.0f;
#pragma unroll 4
    for (int it = 0; it < 64; ++it) {
        float4 v = z4[it * 256 + t];
        s += v.x + v.y + v.z + v.w;
    }
    float d = z[base + (size_t)t * 257];
    for (int off = 32; off > 0; off >>= 1) {
        s += __shfl_down(s, off);
        d += __shfl_down(d, off);
    }
    __shared__ float ls[4], ld[4];
    int wid = t >> 6;
    if ((t & 63) == 0) { ls[wid] = s; ld[wid] = d; }
    __syncthreads();
    if (t == 0) {
        s = ls[0] + ls[1] + ls[2] + ls[3];
        d = ld[0] + ld[1] + ld[2] + ld[3];
        int b = b_base + bb;
        sums[b * EMB + c] = s;
        sums[BATCH * EMB + b * EMB + c] = d;
    }
}

// ---------------- final pooled FC ----------------
__global__ void fc(const float* __restrict__ sums,
                   const float* __restrict__ fcw1, const float* __restrict__ fcb1,
                   const float* __restrict__ fcw2, const float* __restrict__ fcb2,
                   float* __restrict__ out) {
    int b = blockIdx.x;
    __shared__ float h[128];
    __shared__ float hh2[64];
    int t = threadIdx.x;
    if (t < 64) {
        h[t] = sums[BATCH * EMB + b * EMB + t] / (float)N;
    } else {
        int c = t - 64;
        float sall = sums[b * EMB + c];
        float sd = sums[BATCH * EMB + b * EMB + c];
        h[t] = (sall - sd) / (float)(N * (N - 1));
    }
    __syncthreads();
    if (t < 64) {
        float acc = fcb1[t];
        for (int k = 0; k < 128; ++k) acc += fcw1[t * 128 + k] * h[k];
        hh2[t] = acc > 0.0f ? acc : 0.0f;
    }
    __syncthreads();
    if (t == 0) {
        float acc = fcb2[0];
        for (int k = 0; k < 64; ++k) acc += fcw2[k] * hh2[k];
        out[b] = acc;
    }
}

extern "C" void kernel_launch(void* const* d_in, const int* in_sizes, int n_in,
                              void* d_out, int out_size, void* d_ws, size_t ws_size,
                              hipStream_t stream) {
    const int* ei       = (const int*)d_in[0];
    const int* batchv   = (const int*)d_in[1];
    const float* rb0_m1w1 = (const float*)d_in[2];
    const float* rb0_m1b1 = (const float*)d_in[3];
    const float* rb0_m1w2 = (const float*)d_in[4];
    const float* rb0_m1b2 = (const float*)d_in[5];
    const float* rb0_m2w1 = (const float*)d_in[6];
    const float* rb0_m2b1 = (const float*)d_in[7];
    const float* rb0_m2w2 = (const float*)d_in[8];
    const float* rb0_m2b2 = (const float*)d_in[9];
    const float* rb0_sw   = (const float*)d_in[10];
    const float* rb0_sb   = (const float*)d_in[11];
    const float* rb_m1w1  = (const float*)d_in[12];
    const float* rb_m1b1  = (const float*)d_in[13];
    const float* rb_m1w2  = (const float*)d_in[14];
    const float* rb_m1b2  = (const float*)d_in[15];
    const float* rb_m2w1  = (const float*)d_in[16];
    const float* rb_m2b1  = (const float*)d_in[17];
    const float* rb_m2w2  = (const float*)d_in[18];
    const float* rb_m2b2  = (const float*)d_in[19];
    const float* rb_sw    = (const float*)d_in[20];
    const float* rb_sb    = (const float*)d_in[21];
    const float* fcw1     = (const float*)d_in[22];
    const float* fcb1     = (const float*)d_in[23];
    const float* fcw2     = (const float*)d_in[24];
    const float* fcb2     = (const float*)d_in[25];

    const size_t P = (size_t)EMB * NN;               // 4,194,304 elems
    const size_t WB = (size_t)WSPLIT_ELEMS * 2ull;
    const size_t fixedBytes = 524288ull * 4ull + 4096ull + 2ull * WB;
    const size_t perGraphBytes = 2ull * P * 2ull + P * 2ull + P * 4ull;
    int g = BATCH;
    while (g > 1) {
        if (fixedBytes + (size_t)g * perGraphBytes <= ws_size) break;
        g >>= 1;
    }

    char* w = (char*)d_ws;
    float* adj   = (float*)w;  w += 524288ull * 4ull;
    float* sums  = (float*)w;  w += 4096;
    u16* wsh     = (u16*)w;    w += WB;
    u16* wsl     = (u16*)w;    w += WB;
    u16* m1      = (u16*)w;    w += (size_t)g * P * 2ull;
    u16* m2      = (u16*)w;    w += (size_t)g * P * 2ull;
    u16* mult    = (u16*)w;    w += (size_t)g * P * 2ull;
    float* znchw = (float*)w;  w += (size_t)g * P * 4ull;

    hipMemsetAsync(adj, 0, 524288ull * 4ull, stream);
    scatter_adj<<<NEDGE / 256, 256, 0, stream>>>(ei, batchv, adj);
    prep_w<<<(WSPLIT_ELEMS + 255) / 256, 256, 0, stream>>>(
        rb0_m1w2, rb0_m2w2, rb0_sw, rb_m1w1, rb_m1w2, rb_m2w1, rb_m2w2, rb_sw, wsh, wsl);

    for (int b_base = 0; b_base < BATCH; b_base += g) {
        dim3 gridF(NN / 128, g);
        dim3 gridM(8, EMB, g);

        f1_rb0<<<gridF, 512, 0, stream>>>(adj, b_base,
            rb0_m1w1, rb0_m1b1, rb0_m2w1, rb0_m2b1,
            wsh, wsl, rb0_m1b2, rb0_m2b2, m1, m2);
        chanmm_mfma<<<gridM, 512, 0, stream>>>(m1, m2, mult);
        f2_rb0<<<gridF, 512, 0, stream>>>(adj, b_base, mult, wsh, wsl, rb0_sw, rb0_sb, znchw);

        for (int i = 0; i < 3; ++i) {
            f1_reg<<<gridF, 512, 0, stream>>>(znchw, wsh, wsl, i,
                rb_m1b1 + i * 64, rb_m1b2 + i * 64,
                rb_m2b1 + i * 64, rb_m2b2 + i * 64,
                m1, m2);
            chanmm_mfma<<<gridM, 512, 0, stream>>>(m1, m2, mult);
            f2_reg<<<gridF, 512, 0, stream>>>(mult, wsh, wsl, i, rb_sb + i * 64, znchw);
        }

        pool<<<dim3(g, EMB), 256, 0, stream>>>(znchw, sums, b_base);
    }
    fc<<<BATCH, 128, 0, stream>>>(sums, fcw1, fcb1, fcw2, fcb2, (float*)d_out);
}

// Round 26
// 812.780 us; speedup vs baseline: 1.1374x; 1.0067x over previous
//
#include <hip/hip_runtime.h>

#define N 256
#define NN 65536
#define EMB 64
#define BATCH 8
#define NEDGE 32768

typedef unsigned short u16;
typedef unsigned int u32t;
typedef __attribute__((ext_vector_type(8))) short bf16x8;
typedef __attribute__((ext_vector_type(4))) float f32x4;

// pre-split weight buffer offsets (u16 elements)
#define RB0_W2A 0
#define RB0_W2B 4096
#define RB0_SW  8192
#define REG_BASE 12288
#define REG_STRIDE 24576   // per regular block: W1A,W2A,W1B,W2B (4096 each) + SW (8192)
#define WSPLIT_ELEMS 86016

static __device__ __forceinline__ u16 f2bs(float f) {
    u32t u = __float_as_uint(f);
    u32t r = (u + 0x7FFFu + ((u >> 16) & 1u)) >> 16;
    return (u16)r;
}
static __device__ __forceinline__ float b2f(u16 s) {
    return __uint_as_float(((u32t)s) << 16);
}
static __device__ __forceinline__ void split_bf(float a, u16& hi, u16& lo) {
    hi = f2bs(a);
    float r = a - b2f(hi);
    lo = f2bs(r);
}

// ---------------- adjacency scatter ----------------
__global__ void scatter_adj(const int* __restrict__ ei, const int* __restrict__ batch,
                            float* __restrict__ adj) {
    int e = blockIdx.x * blockDim.x + threadIdx.x;
    if (e >= NEDGE) return;
    int src = ei[e];
    int dst = ei[NEDGE + e];
    int g = batch[src];
    int lu = src - g * N;
    int lv = dst - g * N;
    atomicAdd(&adj[(size_t)g * NN + (size_t)lu * N + lv], 1.0f);
}

// ---------------- one-time weight pre-split ----------------
__global__ void prep_w(const float* __restrict__ rb0_m1w2, const float* __restrict__ rb0_m2w2,
                       const float* __restrict__ rb0_sw,
                       const float* __restrict__ rb_m1w1, const float* __restrict__ rb_m1w2,
                       const float* __restrict__ rb_m2w1, const float* __restrict__ rb_m2w2,
                       const float* __restrict__ rb_sw,
                       u16* __restrict__ wh, u16* __restrict__ wl) {
    int idx = blockIdx.x * 256 + threadIdx.x;
    if (idx >= WSPLIT_ELEMS) return;
    float v;
    if (idx < 4096) v = rb0_m1w2[idx];
    else if (idx < 8192) v = rb0_m2w2[idx - 4096];
    else if (idx < 12288) { int e = idx - 8192; v = rb0_sw[(e >> 6) * 66 + 2 + (e & 63)]; }
    else {
        int e = idx - REG_BASE;
        int blk = e / REG_STRIDE, r = e % REG_STRIDE;
        if (r < 4096) v = rb_m1w1[blk * 4096 + r];
        else if (r < 8192) v = rb_m1w2[blk * 4096 + r - 4096];
        else if (r < 12288) v = rb_m2w1[blk * 4096 + r - 8192];
        else if (r < 16384) v = rb_m2w2[blk * 4096 + r - 12288];
        else v = rb_sw[blk * 8192 + r - 16384];
    }
    u16 h, l;
    split_bf(v, h, l);
    wh[idx] = h; wl[idx] = l;
}

// ================= engine building blocks =================

__device__ __forceinline__ void stage_w64_512(const u16* __restrict__ Wh, const u16* __restrict__ Wl,
                                              u16* dh, u16* dl, int t) {
    int row = t >> 3, g = t & 7;
    int4 vh = *(const int4*)&Wh[row * 64 + g * 8];
    int4 vl = *(const int4*)&Wl[row * 64 + g * 8];
    int d = row * 64 + ((g ^ (row & 7)) << 3);
    *(int4*)&dh[d] = vh;
    *(int4*)&dl[d] = vl;
}
__device__ __forceinline__ void stage_w128s_512(const u16* __restrict__ Wh, const u16* __restrict__ Wl,
                                                u16* dh, u16* dl, int t) {
#pragma unroll
    for (int it = 0; it < 2; ++it) {
        int idx = it * 512 + t;
        int row = idx >> 4, g = idx & 15;
        int4 vh = *(const int4*)&Wh[row * 128 + g * 8];
        int4 vl = *(const int4*)&Wl[row * 128 + g * 8];
        int d = row * 128 + ((g ^ (row & 7)) << 3);
        *(int4*)&dh[d] = vh;
        *(int4*)&dl[d] = vl;
    }
}
__device__ __forceinline__ bf16x8 wfrag64(const u16* w, int row, int k0) {
    int g = k0 >> 3;
    return *(const bf16x8*)&w[row * 64 + ((g ^ (row & 7)) << 3)];
}
__device__ __forceinline__ bf16x8 wfrag128(const u16* w, int row, int k0) {
    int g = k0 >> 3;
    return *(const bf16x8*)&w[row * 128 + ((g ^ (row & 7)) << 3)];
}

// wave-local: stage this wave's 16-px band of bf16 mult (NCHW u16) into swizzled stride-64 rows
__device__ __forceinline__ void stage_band_m(const u16* __restrict__ src, int p0,
                                             u16* mb, int wband, int lane) {
    int q = lane >> 4, l15 = lane & 15;
    int px = wband * 16 + l15;
    int gpx = p0 + px;
#pragma unroll
    for (int it = 0; it < 8; ++it) {
        int c0 = it * 8 + q * 2;
        u16 v0 = src[(size_t)c0 * NN + gpx];
        u16 v1 = src[(size_t)(c0 + 1) * NN + gpx];
        int gaddr = px * 64 + ((it ^ (px & 7)) << 3) + q * 2;
        *(u32t*)&mb[gaddr] = (u32t)v0 | ((u32t)v1 << 16);
    }
}

// build this lane's z fragments (hi/lo) directly from NCHW fp32 global
__device__ __forceinline__ void zfrags_nchw(const float* __restrict__ zp, int px,
                                            int q, bf16x8 zfh[2], bf16x8 zfl[2]) {
#pragma unroll
    for (int ks = 0; ks < 2; ++ks)
#pragma unroll
        for (int j = 0; j < 8; ++j) {
            float v = zp[(size_t)(ks * 32 + q * 8 + j) * NN + px];
            u16 h, l; split_bf(v, h, l);
            zfh[ks][j] = (short)h;
            zfl[ks][j] = (short)l;
        }
}

__device__ __forceinline__ void init_bias(const float* __restrict__ Bb, f32x4* acc, int lane) {
    int q = lane >> 4;
#pragma unroll
    for (int ot = 0; ot < 4; ++ot)
#pragma unroll
        for (int j = 0; j < 4; ++j)
            acc[ot][j] = Bb[ot * 16 + q * 4 + j];
}

// f1 L1 (3-term: z split exact, W split): D[o][px] += W[o][k] * z[px][k]
__device__ __forceinline__ void mfma_L1_64(bf16x8 zfh[2], bf16x8 zfl[2],
                                           const u16* wh, const u16* wl,
                                           f32x4* acc, int lane) {
    int q = lane >> 4, l = lane & 15;
#pragma unroll
    for (int ks = 0; ks < 2; ++ks) {
        int k0 = ks * 32 + q * 8;
#pragma unroll
        for (int ot = 0; ot < 4; ++ot) {
            bf16x8 ahi = wfrag64(wh, ot * 16 + l, k0);
            bf16x8 alo = wfrag64(wl, ot * 16 + l, k0);
            acc[ot] = __builtin_amdgcn_mfma_f32_16x16x32_bf16(ahi, zfh[ks], acc[ot], 0, 0, 0);
            acc[ot] = __builtin_amdgcn_mfma_f32_16x16x32_bf16(ahi, zfl[ks], acc[ot], 0, 0, 0);
            acc[ot] = __builtin_amdgcn_mfma_f32_16x16x32_bf16(alo, zfh[ks], acc[ot], 0, 0, 0);
        }
    }
}
// f2 L1, W split (3-term), K-half of [64][128]
__device__ __forceinline__ void mfma_L1_128(bf16x8 zfh[2], bf16x8 zfl[2],
                                            const u16* wh, const u16* wl, int ak0,
                                            f32x4* acc, int lane) {
    int q = lane >> 4, l = lane & 15;
#pragma unroll
    for (int ks = 0; ks < 2; ++ks) {
        int k0 = ks * 32 + q * 8;
#pragma unroll
        for (int ot = 0; ot < 4; ++ot) {
            bf16x8 ahi = wfrag128(wh, ot * 16 + l, ak0 + k0);
            bf16x8 alo = wfrag128(wl, ot * 16 + l, ak0 + k0);
            acc[ot] = __builtin_amdgcn_mfma_f32_16x16x32_bf16(ahi, zfh[ks], acc[ot], 0, 0, 0);
            acc[ot] = __builtin_amdgcn_mfma_f32_16x16x32_bf16(ahi, zfl[ks], acc[ot], 0, 0, 0);
            acc[ot] = __builtin_amdgcn_mfma_f32_16x16x32_bf16(alo, zfh[ks], acc[ot], 0, 0, 0);
        }
    }
}

// f1 L2 (2-term: h bf16 exact, W split): h from swizzled stride-64 hbuf
__device__ __forceinline__ void layer_h2(const u16* hbuf,
                                         const u16* wh, const u16* wl,
                                         f32x4* acc, int wv, int lane) {
    int q = lane >> 4, l = lane & 15;
#pragma unroll
    for (int ks = 0; ks < 2; ++ks) {
        int k0 = ks * 32 + q * 8;
        bf16x8 b = wfrag64(hbuf, wv * 16 + l, k0);
#pragma unroll
        for (int ot = 0; ot < 4; ++ot) {
            bf16x8 ahi = wfrag64(wh, ot * 16 + l, k0);
            bf16x8 alo = wfrag64(wl, ot * 16 + l, k0);
            acc[ot] = __builtin_amdgcn_mfma_f32_16x16x32_bf16(ahi, b, acc[ot], 0, 0, 0);
            acc[ot] = __builtin_amdgcn_mfma_f32_16x16x32_bf16(alo, b, acc[ot], 0, 0, 0);
        }
    }
}
// f2 mult half (2-term), K-offset 64 of [64][128]
__device__ __forceinline__ void layer_m2_128(const u16* mb,
                                             const u16* wh, const u16* wl,
                                             f32x4* acc, int wv, int lane) {
    int q = lane >> 4, l = lane & 15;
#pragma unroll
    for (int ks = 0; ks < 2; ++ks) {
        int k0 = ks * 32 + q * 8;
        bf16x8 b = wfrag64(mb, wv * 16 + l, k0);
#pragma unroll
        for (int ot = 0; ot < 4; ++ot) {
            bf16x8 ahi = wfrag128(wh, ot * 16 + l, 64 + k0);
            bf16x8 alo = wfrag128(wl, ot * 16 + l, 64 + k0);
            acc[ot] = __builtin_amdgcn_mfma_f32_16x16x32_bf16(ahi, b, acc[ot], 0, 0, 0);
            acc[ot] = __builtin_amdgcn_mfma_f32_16x16x32_bf16(alo, b, acc[ot], 0, 0, 0);
        }
    }
}
// f2_rb0 mult (2-term, W split [64][64])
__device__ __forceinline__ void layer_m2_64(const u16* mb,
                                            const u16* wh, const u16* wl,
                                            f32x4* acc, int wv, int lane) {
    int q = lane >> 4, l = lane & 15;
#pragma unroll
    for (int ks = 0; ks < 2; ++ks) {
        int k0 = ks * 32 + q * 8;
        bf16x8 b = wfrag64(mb, wv * 16 + l, k0);
#pragma unroll
        for (int ot = 0; ot < 4; ++ot) {
            bf16x8 ahi = wfrag64(wh, ot * 16 + l, k0);
            bf16x8 alo = wfrag64(wl, ot * 16 + l, k0);
            acc[ot] = __builtin_amdgcn_mfma_f32_16x16x32_bf16(ahi, b, acc[ot], 0, 0, 0);
            acc[ot] = __builtin_amdgcn_mfma_f32_16x16x32_bf16(alo, b, acc[ot], 0, 0, 0);
        }
    }
}

// write h = relu(acc) as plain bf16 to SWIZZLED stride-64 own-band rows [px][o]
__device__ __forceinline__ void write_h_bf16(f32x4* acc, u16* hbuf, int wv, int lane) {
    int q = lane >> 4, l = lane & 15;
    int px = wv * 16 + l;
#pragma unroll
    for (int ot = 0; ot < 4; ++ot) {
#pragma unroll
        for (int jp = 0; jp < 2; ++jp) {
            int o = ot * 16 + q * 4 + jp * 2;
            int gaddr = px * 64 + (((o >> 3) ^ (px & 7)) << 3) + (o & 7);
            float v0 = acc[ot][jp * 2];     v0 = v0 > 0.f ? v0 : 0.f;
            float v1 = acc[ot][jp * 2 + 1]; v1 = v1 > 0.f ? v1 : 0.f;
            *(u32t*)&hbuf[gaddr] = (u32t)f2bs(v0) | ((u32t)f2bs(v1) << 16);
        }
    }
}

// store relu(acc) (D[o][px]) as plain bf16 to u16 NCHW plane set
__device__ __forceinline__ void write_m_bf16(f32x4* acc, u16* __restrict__ mh,
                                             int p0, int wv, int lane) {
    int q = lane >> 4, l = lane & 15;
    int px = p0 + wv * 16 + l;
#pragma unroll
    for (int ot = 0; ot < 4; ++ot)
#pragma unroll
        for (int j = 0; j < 4; ++j) {
            int o = ot * 16 + q * 4 + j;
            float v = acc[ot][j]; v = v > 0.f ? v : 0.f;
            mh[(size_t)o * NN + px] = f2bs(v);
        }
}

__device__ __forceinline__ void write_m_lin(f32x4* acc, float* mout,
                                            int p0, int wv, int lane) {
    int q = lane >> 4, l = lane & 15;
    int px = p0 + wv * 16 + l;
#pragma unroll
    for (int ot = 0; ot < 4; ++ot)
#pragma unroll
        for (int j = 0; j < 4; ++j) {
            int o = ot * 16 + q * 4 + j;
            mout[(size_t)o * NN + px] = acc[ot][j];
        }
}

// f1 phase body (shared by fused kernels): new-z frags from global (L2-hot) -> m1,m2
__device__ __forceinline__ void f1_phase(const float* zp, size_t gofs, int p0,
                                         const u16* Wbh, const u16* Wbl,
                                         const float* B1a, const float* B2a,
                                         const float* B1b, const float* B2b,
                                         u16* m1, u16* m2,
                                         u16* wsA, u16* wsB, u16* mbuf,
                                         int t, int lane, int wv, int q, int l15) {
    bf16x8 zfh[2], zfl[2];
    zfrags_nchw(zp, p0 + wv * 16 + l15, q, zfh, zfl);
    stage_w64_512(Wbh, Wbl, wsA, wsA + 4096, t);            // W1A
    stage_w64_512(Wbh + 4096, Wbl + 4096, wsB, wsB + 4096, t); // W2A
    __syncthreads();

    f32x4 acc[4];
    init_bias(B1a, acc, lane);
    mfma_L1_64(zfh, zfl, wsA, wsA + 4096, acc, lane);
    write_h_bf16(acc, mbuf, wv, lane);
    init_bias(B2a, acc, lane);
    layer_h2(mbuf, wsB, wsB + 4096, acc, wv, lane);
    write_m_bf16(acc, m1 + gofs, p0, wv, lane);

    __syncthreads();
    stage_w64_512(Wbh + 8192, Wbl + 8192, wsA, wsA + 4096, t);     // W1B
    stage_w64_512(Wbh + 12288, Wbl + 12288, wsB, wsB + 4096, t);   // W2B
    __syncthreads();

    init_bias(B1b, acc, lane);
    mfma_L1_64(zfh, zfl, wsA, wsA + 4096, acc, lane);
    write_h_bf16(acc, mbuf, wv, lane);
    init_bias(B2b, acc, lane);
    layer_h2(mbuf, wsB, wsB + 4096, acc, wv, lane);
    write_m_bf16(acc, m2 + gofs, p0, wv, lane);
}

// ---------------- f1 rb0: adj -> m1,m2 (bf16); 512 thr, 128 px/WG; 1 barrier ----------------
__global__ __launch_bounds__(512, 3) void f1_rb0(
    const float* __restrict__ adj, int b_base,
    const float* __restrict__ w1a, const float* __restrict__ b1a,
    const float* __restrict__ w1b, const float* __restrict__ b1b,
    const u16* __restrict__ wsh, const u16* __restrict__ wsl,
    const float* __restrict__ B2a, const float* __restrict__ B2b,
    u16* __restrict__ m1, u16* __restrict__ m2) {
    __shared__ u16 w1h[4096], w1l[4096], w2h[4096], w2l[4096];
    __shared__ u16 hbuf[8192];
    int bb = blockIdx.y, p0 = blockIdx.x * 128;
    int t = threadIdx.x, lane = t & 63, wv = t >> 6;
    int q = lane >> 4, l15 = lane & 15;
    size_t gofs = (size_t)bb * EMB * NN;
    int pxl = wv * 16 + l15;
    float a = adj[(size_t)(b_base + bb) * NN + p0 + pxl];

    stage_w64_512(wsh + RB0_W2A, wsl + RB0_W2A, w1h, w1l, t);
    stage_w64_512(wsh + RB0_W2B, wsl + RB0_W2B, w2h, w2l, t);
#pragma unroll
    for (int it = 0; it < 8; ++it) {
        int o0 = it * 8 + q * 2;
        int gaddr = pxl * 64 + ((it ^ (pxl & 7)) << 3) + q * 2;
        float v0 = w1a[o0 * 2] * a + b1a[o0];             v0 = v0 > 0.f ? v0 : 0.f;
        float v1 = w1a[(o0 + 1) * 2] * a + b1a[o0 + 1];   v1 = v1 > 0.f ? v1 : 0.f;
        *(u32t*)&hbuf[gaddr] = (u32t)f2bs(v0) | ((u32t)f2bs(v1) << 16);
    }
    __syncthreads();

    f32x4 acc[4];
    init_bias(B2a, acc, lane);
    layer_h2(hbuf, w1h, w1l, acc, wv, lane);
    write_m_bf16(acc, m1 + gofs, p0, wv, lane);

#pragma unroll
    for (int it = 0; it < 8; ++it) {
        int o0 = it * 8 + q * 2;
        int gaddr = pxl * 64 + ((it ^ (pxl & 7)) << 3) + q * 2;
        float v0 = w1b[o0 * 2] * a + b1b[o0];             v0 = v0 > 0.f ? v0 : 0.f;
        float v1 = w1b[(o0 + 1) * 2] * a + b1b[o0 + 1];   v1 = v1 > 0.f ? v1 : 0.f;
        *(u32t*)&hbuf[gaddr] = (u32t)f2bs(v0) | ((u32t)f2bs(v1) << 16);
    }
    init_bias(B2b, acc, lane);
    layer_h2(hbuf, w2h, w2l, acc, wv, lane);
    write_m_bf16(acc, m2 + gofs, p0, wv, lane);
}

// ---------------- per-channel NxN matmul, plain bf16 MFMA; mult out bf16 (unchanged) ----------------
__device__ __forceinline__ int soff(int row, int g) {
    return row * 64 + ((g ^ (row & 7) ^ ((row >> 3) & 7)) << 3);
}

__global__ __launch_bounds__(512) void chanmm_mfma(
    const u16* __restrict__ m1, const u16* __restrict__ m2,
    u16* __restrict__ mult) {
    __shared__ u16 Ah[128 * 64];
    __shared__ u16 Bh[64 * 64];
    int t = threadIdx.x, lane = t & 63, wv = t >> 6;
    int l15 = lane & 15, q = lane >> 4;
    int wi = wv >> 1, wj = wv & 1;
    int tile = blockIdx.x;
    int itile = (tile >> 2) * 128, jtile = (tile & 3) * 64;
    int ch = blockIdx.y, bb = blockIdx.z;
    size_t pb = ((size_t)bb * EMB + ch) * NN;
    const u16* A_h = m1 + pb;
    const u16* B_h = m2 + pb;

    int a_i = t >> 3;
    int a_g = t & 7;
    int b_k = t >> 3;
    int b_j8 = (t & 7) * 8;

    int4 rAh0, rAh1, rBh;
#define LOADK(K0)                                                              \
    {                                                                          \
        int k0_ = (K0);                                                        \
        rAh0 = *(const int4*)&A_h[(itile + a_i) * N + k0_ + a_g * 8];          \
        rAh1 = *(const int4*)&A_h[(itile + 64 + a_i) * N + k0_ + a_g * 8];     \
        rBh  = *(const int4*)&B_h[(k0_ + b_k) * N + jtile + b_j8];             \
    }

    f32x4 acc[2][2] = {};
    LOADK(0);
#pragma unroll
    for (int s = 0; s < 4; ++s) {
        *(int4*)&Ah[soff(a_i, a_g)] = rAh0;
        *(int4*)&Ah[soff(a_i + 64, a_g)] = rAh1;
        {
            const u16* ph = (const u16*)&rBh;
            int G = b_k >> 3, kin = b_k & 7;
#pragma unroll
            for (int d = 0; d < 8; ++d) {
                int j = b_j8 + d;
                Bh[soff(j, G) + kin] = ph[d];
            }
        }
        __syncthreads();
        if (s < 3) LOADK((s + 1) * 64);
#pragma unroll
        for (int ks = 0; ks < 2; ++ks) {
            int g = ks * 4 + q;
            bf16x8 bhi[2];
#pragma unroll
            for (int jt = 0; jt < 2; ++jt) {
                int rj = wj * 32 + jt * 16 + l15;
                bhi[jt] = *(const bf16x8*)&Bh[soff(rj, g)];
            }
#pragma unroll
            for (int it = 0; it < 2; ++it) {
                int ri = wi * 32 + it * 16 + l15;
                bf16x8 ahi = *(const bf16x8*)&Ah[soff(ri, g)];
#pragma unroll
                for (int jt = 0; jt < 2; ++jt)
                    acc[it][jt] = __builtin_amdgcn_mfma_f32_16x16x32_bf16(ahi, bhi[jt], acc[it][jt], 0, 0, 0);
            }
        }
        __syncthreads();
    }
#undef LOADK
    u16* O = mult + pb;
#pragma unroll
    for (int it = 0; it < 2; ++it)
#pragma unroll
        for (int jt = 0; jt < 2; ++jt)
#pragma unroll
            for (int r = 0; r < 4; ++r) {
                int i = itile + wi * 32 + it * 16 + q * 4 + r;
                int j = jtile + wj * 32 + jt * 16 + l15;
                O[(size_t)i * N + j] = f2bs(acc[it][jt][r]);
            }
}

// ---------------- FUSED: f2_reg(blk2) -> z, then f1_reg(blk1) reading L2-hot z ----------------
__global__ __launch_bounds__(512, 3) void f2f1(
    const u16* __restrict__ mult,   // NCHW bf16
    const u16* __restrict__ wsh, const u16* __restrict__ wsl,
    int blk2, const float* __restrict__ SB2,
    float* z,
    int blk1,
    const float* __restrict__ B1a, const float* __restrict__ B2a,
    const float* __restrict__ B1b, const float* __restrict__ B2b,
    u16* __restrict__ m1, u16* __restrict__ m2) {
    __shared__ u16 wsA[8192], wsB[8192];   // 32 KB
    __shared__ u16 mbuf[8192];             // 16 KB -> 48 KB total
    int bb = blockIdx.y, p0 = blockIdx.x * 128;
    int t = threadIdx.x, lane = t & 63, wv = t >> 6;
    int q = lane >> 4, l15 = lane & 15;
    size_t gofs = (size_t)bb * EMB * NN;
    const u16* mp = mult + gofs;
    float* zp = z + gofs;
    const u16* SWh = wsh + REG_BASE + blk2 * REG_STRIDE + 16384;
    const u16* SWl = wsl + REG_BASE + blk2 * REG_STRIDE + 16384;
    const u16* Wbh = wsh + REG_BASE + blk1 * REG_STRIDE;
    const u16* Wbl = wsl + REG_BASE + blk1 * REG_STRIDE;

    // ---- f2 phase ----
    {
        bf16x8 zfh[2], zfl[2];
        zfrags_nchw(zp, p0 + wv * 16 + l15, q, zfh, zfl);   // OLD z (read before overwrite)
        stage_w128s_512(SWh, SWl, wsA, wsB, t);
        stage_band_m(mp, p0, mbuf, wv, lane);
        __syncthreads();

        f32x4 acc[4];
        init_bias(SB2, acc, lane);
        mfma_L1_128(zfh, zfl, wsA, wsB, 0, acc, lane);
        layer_m2_128(mbuf, wsA, wsB, acc, wv, lane);
        write_m_lin(acc, zp, p0, wv, lane);                 // NEW z to global
    }
    __syncthreads();   // drains vmcnt: WG's z writes L2-visible; LDS free

    // ---- f1 phase (blk1), z re-read is L2-hot ----
    f1_phase(zp, gofs, p0, Wbh, Wbl, B1a, B2a, B1b, B2b, m1, m2,
             wsA, wsB, mbuf, t, lane, wv, q, l15);
}

// ---------------- FUSED: f2_rb0 -> z, then f1_reg(blk 0) ----------------
__global__ __launch_bounds__(512, 3) void f2rb0_f1(
    const float* __restrict__ adj, int b_base,
    const u16* __restrict__ mult,   // NCHW bf16
    const u16* __restrict__ wsh, const u16* __restrict__ wsl,
    const float* __restrict__ SWf, const float* __restrict__ SB2,
    float* z,
    const float* __restrict__ B1a, const float* __restrict__ B2a,
    const float* __restrict__ B1b, const float* __restrict__ B2b,
    u16* __restrict__ m1, u16* __restrict__ m2) {
    __shared__ u16 wsA[8192], wsB[8192];
    __shared__ u16 mbuf[8192];
    int bb = blockIdx.y, p0 = blockIdx.x * 128;
    int t = threadIdx.x, lane = t & 63, wv = t >> 6;
    int q = lane >> 4, l15 = lane & 15;
    size_t gofs = (size_t)bb * EMB * NN;
    const u16* mp = mult + gofs;
    float* zp = z + gofs;
    const u16* Wbh = wsh + REG_BASE;   // blk1 = 0
    const u16* Wbl = wsl + REG_BASE;

    // ---- f2_rb0 phase ----
    {
        stage_w64_512(wsh + RB0_SW, wsl + RB0_SW, wsA, wsA + 4096, t);
        stage_band_m(mp, p0, mbuf, wv, lane);
        __syncthreads();

        float a = adj[(size_t)(b_base + bb) * NN + p0 + wv * 16 + l15];
        f32x4 acc[4];
#pragma unroll
        for (int ot = 0; ot < 4; ++ot)
#pragma unroll
            for (int j = 0; j < 4; ++j) {
                int o = ot * 16 + q * 4 + j;
                acc[ot][j] = SB2[o] + SWf[o * 66] * a;
            }
        layer_m2_64(mbuf, wsA, wsA + 4096, acc, wv, lane);
        write_m_lin(acc, zp, p0, wv, lane);
    }
    __syncthreads();

    // ---- f1 phase (blk 0) ----
    f1_phase(zp, gofs, p0, Wbh, Wbl, B1a, B2a, B1b, B2b, m1, m2,
             wsA, wsB, mbuf, t, lane, wv, q, l15);
}

// ---------------- standalone f2 (last block): skip conv -> z ----------------
__global__ __launch_bounds__(512, 3) void f2_reg(
    const u16* __restrict__ mult,   // NCHW bf16
    const u16* __restrict__ wsh, const u16* __restrict__ wsl, int blk,
    const float* __restrict__ SB,
    float* __restrict__ z) {
    __shared__ u16 wh[8192], wl[8192];
    __shared__ u16 mb[8192];
    int bb = blockIdx.y, p0 = blockIdx.x * 128;
    int t = threadIdx.x, lane = t & 63, wv = t >> 6;
    int q = lane >> 4, l15 = lane & 15;
    const u16* mp = mult + (size_t)bb * EMB * NN;
    float* zp = z + (size_t)bb * EMB * NN;
    const u16* SWh = wsh + REG_BASE + blk * REG_STRIDE + 16384;
    const u16* SWl = wsl + REG_BASE + blk * REG_STRIDE + 16384;

    bf16x8 zfh[2], zfl[2];
    zfrags_nchw(zp, p0 + wv * 16 + l15, q, zfh, zfl);

    stage_w128s_512(SWh, SWl, wh, wl, t);
    stage_band_m(mp, p0, mb, wv, lane);
    __syncthreads();

    f32x4 acc[4];
    init_bias(SB, acc, lane);
    mfma_L1_128(zfh, zfl, wh, wl, 0, acc, lane);
    layer_m2_128(mb, wh, wl, acc, wv, lane);
    write_m_lin(acc, zp, p0, wv, lane);
}

// ---------------- pooling partials (float4 loads, branch-free diag) ----------------
__global__ void pool(const float* __restrict__ z, float* __restrict__ sums, int b_base) {
    int bb = blockIdx.x;
    int c = blockIdx.y;
    size_t base = ((size_t)bb * EMB + c) * NN;
    const float4* z4 = (const float4*)(z + base);
    int t = threadIdx.x;
    float s = 0.0f;
#pragma unroll 4
    for (int it = 0; it < 64; ++it) {
        float4 v = z4[it * 256 + t];
        s += v.x + v.y + v.z + v.w;
    }
    float d = z[base + (size_t)t * 257];
    for (int off = 32; off > 0; off >>= 1) {
        s += __shfl_down(s, off);
        d += __shfl_down(d, off);
    }
    __shared__ float ls[4], ld[4];
    int wid = t >> 6;
    if ((t & 63) == 0) { ls[wid] = s; ld[wid] = d; }
    __syncthreads();
    if (t == 0) {
        s = ls[0] + ls[1] + ls[2] + ls[3];
        d = ld[0] + ld[1] + ld[2] + ld[3];
        int b = b_base + bb;
        sums[b * EMB + c] = s;
        sums[BATCH * EMB + b * EMB + c] = d;
    }
}

// ---------------- final pooled FC ----------------
__global__ void fc(const float* __restrict__ sums,
                   const float* __restrict__ fcw1, const float* __restrict__ fcb1,
                   const float* __restrict__ fcw2, const float* __restrict__ fcb2,
                   float* __restrict__ out) {
    int b = blockIdx.x;
    __shared__ float h[128];
    __shared__ float hh2[64];
    int t = threadIdx.x;
    if (t < 64) {
        h[t] = sums[BATCH * EMB + b * EMB + t] / (float)N;
    } else {
        int c = t - 64;
        float sall = sums[b * EMB + c];
        float sd = sums[BATCH * EMB + b * EMB + c];
        h[t] = (sall - sd) / (float)(N * (N - 1));
    }
    __syncthreads();
    if (t < 64) {
        float acc = fcb1[t];
        for (int k = 0; k < 128; ++k) acc += fcw1[t * 128 + k] * h[k];
        hh2[t] = acc > 0.0f ? acc : 0.0f;
    }
    __syncthreads();
    if (t == 0) {
        float acc = fcb2[0];
        for (int k = 0; k < 64; ++k) acc += fcw2[k] * hh2[k];
        out[b] = acc;
    }
}

extern "C" void kernel_launch(void* const* d_in, const int* in_sizes, int n_in,
                              void* d_out, int out_size, void* d_ws, size_t ws_size,
                              hipStream_t stream) {
    const int* ei       = (const int*)d_in[0];
    const int* batchv   = (const int*)d_in[1];
    const float* rb0_m1w1 = (const float*)d_in[2];
    const float* rb0_m1b1 = (const float*)d_in[3];
    const float* rb0_m1w2 = (const float*)d_in[4];
    const float* rb0_m1b2 = (const float*)d_in[5];
    const float* rb0_m2w1 = (const float*)d_in[6];
    const float* rb0_m2b1 = (const float*)d_in[7];
    const float* rb0_m2w2 = (const float*)d_in[8];
    const float* rb0_m2b2 = (const float*)d_in[9];
    const float* rb0_sw   = (const float*)d_in[10];
    const float* rb0_sb   = (const float*)d_in[11];
    const float* rb_m1w1  = (const float*)d_in[12];
    const float* rb_m1b1  = (const float*)d_in[13];
    const float* rb_m1w2  = (const float*)d_in[14];
    const float* rb_m1b2  = (const float*)d_in[15];
    const float* rb_m2w1  = (const float*)d_in[16];
    const float* rb_m2b1  = (const float*)d_in[17];
    const float* rb_m2w2  = (const float*)d_in[18];
    const float* rb_m2b2  = (const float*)d_in[19];
    const float* rb_sw    = (const float*)d_in[20];
    const float* rb_sb    = (const float*)d_in[21];
    const float* fcw1     = (const float*)d_in[22];
    const float* fcb1     = (const float*)d_in[23];
    const float* fcw2     = (const float*)d_in[24];
    const float* fcb2     = (const float*)d_in[25];

    const size_t P = (size_t)EMB * NN;               // 4,194,304 elems
    const size_t WB = (size_t)WSPLIT_ELEMS * 2ull;
    const size_t fixedBytes = 524288ull * 4ull + 4096ull + 2ull * WB;
    const size_t perGraphBytes = 2ull * P * 2ull + P * 2ull + P * 4ull;
    int g = BATCH;
    while (g > 1) {
        if (fixedBytes + (size_t)g * perGraphBytes <= ws_size) break;
        g >>= 1;
    }

    char* w = (char*)d_ws;
    float* adj   = (float*)w;  w += 524288ull * 4ull;
    float* sums  = (float*)w;  w += 4096;
    u16* wsh     = (u16*)w;    w += WB;
    u16* wsl     = (u16*)w;    w += WB;
    u16* m1      = (u16*)w;    w += (size_t)g * P * 2ull;
    u16* m2      = (u16*)w;    w += (size_t)g * P * 2ull;
    u16* mult    = (u16*)w;    w += (size_t)g * P * 2ull;
    float* znchw = (float*)w;  w += (size_t)g * P * 4ull;

    hipMemsetAsync(adj, 0, 524288ull * 4ull, stream);
    scatter_adj<<<NEDGE / 256, 256, 0, stream>>>(ei, batchv, adj);
    prep_w<<<(WSPLIT_ELEMS + 255) / 256, 256, 0, stream>>>(
        rb0_m1w2, rb0_m2w2, rb0_sw, rb_m1w1, rb_m1w2, rb_m2w1, rb_m2w2, rb_sw, wsh, wsl);

    for (int b_base = 0; b_base < BATCH; b_base += g) {
        dim3 gridF(NN / 128, g);
        dim3 gridM(8, EMB, g);

        f1_rb0<<<gridF, 512, 0, stream>>>(adj, b_base,
            rb0_m1w1, rb0_m1b1, rb0_m2w1, rb0_m2b1,
            wsh, wsl, rb0_m1b2, rb0_m2b2, m1, m2);
        chanmm_mfma<<<gridM, 512, 0, stream>>>(m1, m2, mult);

        // fused: f2_rb0 -> z, then f1(block 0)
        f2rb0_f1<<<gridF, 512, 0, stream>>>(adj, b_base, mult, wsh, wsl,
            rb0_sw, rb0_sb, znchw,
            rb_m1b1, rb_m1b2, rb_m2b1, rb_m2b2, m1, m2);
        chanmm_mfma<<<gridM, 512, 0, stream>>>(m1, m2, mult);

        // fused: f2(block 0) -> z, then f1(block 1)
        f2f1<<<gridF, 512, 0, stream>>>(mult, wsh, wsl, 0, rb_sb, znchw, 1,
            rb_m1b1 + 64, rb_m1b2 + 64, rb_m2b1 + 64, rb_m2b2 + 64, m1, m2);
        chanmm_mfma<<<gridM, 512, 0, stream>>>(m1, m2, mult);

        // fused: f2(block 1) -> z, then f1(block 2)
        f2f1<<<gridF, 512, 0, stream>>>(mult, wsh, wsl, 1, rb_sb + 64, znchw, 2,
            rb_m1b1 + 128, rb_m1b2 + 128, rb_m2b1 + 128, rb_m2b2 + 128, m1, m2);
        chanmm_mfma<<<gridM, 512, 0, stream>>>(m1, m2, mult);

        // last skip conv (block 2) standalone
        f2_reg<<<gridF, 512, 0, stream>>>(mult, wsh, wsl, 2, rb_sb + 128, znchw);

        pool<<<dim3(g, EMB), 256, 0, stream>>>(znchw, sums, b_base);
    }
    fc<<<BATCH, 128, 0, stream>>>(sums, fcw1, fcb1, fcw2, fcb2, (float*)d_out);
}

// Round 27
// 756.999 us; speedup vs baseline: 1.2212x; 1.0737x over previous
//
#include <hip/hip_runtime.h>

#define N 256
#define NN 65536
#define EMB 64
#define BATCH 8
#define NEDGE 32768

typedef unsigned short u16;
typedef unsigned int u32t;
typedef __attribute__((ext_vector_type(8))) short bf16x8;
typedef __attribute__((ext_vector_type(4))) float f32x4;

// pre-split weight buffer offsets (u16 elements)
#define RB0_W2A 0
#define RB0_W2B 4096
#define RB0_SW  8192
#define REG_BASE 12288
#define REG_STRIDE 24576   // per regular block: W1A,W2A,W1B,W2B (4096 each) + SW (8192)
#define WSPLIT_ELEMS 86016

static __device__ __forceinline__ u16 f2bs(float f) {
    u32t u = __float_as_uint(f);
    u32t r = (u + 0x7FFFu + ((u >> 16) & 1u)) >> 16;
    return (u16)r;
}
static __device__ __forceinline__ float b2f(u16 s) {
    return __uint_as_float(((u32t)s) << 16);
}
static __device__ __forceinline__ void split_bf(float a, u16& hi, u16& lo) {
    hi = f2bs(a);
    float r = a - b2f(hi);
    lo = f2bs(r);
}

// ---------------- adjacency scatter ----------------
__global__ void scatter_adj(const int* __restrict__ ei, const int* __restrict__ batch,
                            float* __restrict__ adj) {
    int e = blockIdx.x * blockDim.x + threadIdx.x;
    if (e >= NEDGE) return;
    int src = ei[e];
    int dst = ei[NEDGE + e];
    int g = batch[src];
    int lu = src - g * N;
    int lv = dst - g * N;
    atomicAdd(&adj[(size_t)g * NN + (size_t)lu * N + lv], 1.0f);
}

// ---------------- one-time weight pre-split ----------------
__global__ void prep_w(const float* __restrict__ rb0_m1w2, const float* __restrict__ rb0_m2w2,
                       const float* __restrict__ rb0_sw,
                       const float* __restrict__ rb_m1w1, const float* __restrict__ rb_m1w2,
                       const float* __restrict__ rb_m2w1, const float* __restrict__ rb_m2w2,
                       const float* __restrict__ rb_sw,
                       u16* __restrict__ wh, u16* __restrict__ wl) {
    int idx = blockIdx.x * 256 + threadIdx.x;
    if (idx >= WSPLIT_ELEMS) return;
    float v;
    if (idx < 4096) v = rb0_m1w2[idx];
    else if (idx < 8192) v = rb0_m2w2[idx - 4096];
    else if (idx < 12288) { int e = idx - 8192; v = rb0_sw[(e >> 6) * 66 + 2 + (e & 63)]; }
    else {
        int e = idx - REG_BASE;
        int blk = e / REG_STRIDE, r = e % REG_STRIDE;
        if (r < 4096) v = rb_m1w1[blk * 4096 + r];
        else if (r < 8192) v = rb_m1w2[blk * 4096 + r - 4096];
        else if (r < 12288) v = rb_m2w1[blk * 4096 + r - 8192];
        else if (r < 16384) v = rb_m2w2[blk * 4096 + r - 12288];
        else v = rb_sw[blk * 8192 + r - 16384];
    }
    u16 h, l;
    split_bf(v, h, l);
    wh[idx] = h; wl[idx] = l;
}

// ================= engine building blocks =================

__device__ __forceinline__ void stage_w64_512(const u16* __restrict__ Wh, const u16* __restrict__ Wl,
                                              u16* dh, u16* dl, int t) {
    int row = t >> 3, g = t & 7;
    int4 vh = *(const int4*)&Wh[row * 64 + g * 8];
    int4 vl = *(const int4*)&Wl[row * 64 + g * 8];
    int d = row * 64 + ((g ^ (row & 7)) << 3);
    *(int4*)&dh[d] = vh;
    *(int4*)&dl[d] = vl;
}
__device__ __forceinline__ void stage_w128s_512(const u16* __restrict__ Wh, const u16* __restrict__ Wl,
                                                u16* dh, u16* dl, int t) {
#pragma unroll
    for (int it = 0; it < 2; ++it) {
        int idx = it * 512 + t;
        int row = idx >> 4, g = idx & 15;
        int4 vh = *(const int4*)&Wh[row * 128 + g * 8];
        int4 vl = *(const int4*)&Wl[row * 128 + g * 8];
        int d = row * 128 + ((g ^ (row & 7)) << 3);
        *(int4*)&dh[d] = vh;
        *(int4*)&dl[d] = vl;
    }
}
__device__ __forceinline__ bf16x8 wfrag64(const u16* w, int row, int k0) {
    int g = k0 >> 3;
    return *(const bf16x8*)&w[row * 64 + ((g ^ (row & 7)) << 3)];
}
__device__ __forceinline__ bf16x8 wfrag128(const u16* w, int row, int k0) {
    int g = k0 >> 3;
    return *(const bf16x8*)&w[row * 128 + ((g ^ (row & 7)) << 3)];
}

// wave-local: stage this wave's 16-px band of bf16 mult (NCHW u16) into swizzled stride-64 rows
__device__ __forceinline__ void stage_band_m(const u16* __restrict__ src, int p0,
                                             u16* mb, int wband, int lane) {
    int q = lane >> 4, l15 = lane & 15;
    int px = wband * 16 + l15;
    int gpx = p0 + px;
#pragma unroll
    for (int it = 0; it < 8; ++it) {
        int c0 = it * 8 + q * 2;
        u16 v0 = src[(size_t)c0 * NN + gpx];
        u16 v1 = src[(size_t)(c0 + 1) * NN + gpx];
        int gaddr = px * 64 + ((it ^ (px & 7)) << 3) + q * 2;
        *(u32t*)&mb[gaddr] = (u32t)v0 | ((u32t)v1 << 16);
    }
}

// build this lane's z fragments (hi/lo) directly from NCHW fp32 global
__device__ __forceinline__ void zfrags_nchw(const float* __restrict__ zp, int px,
                                            int q, bf16x8 zfh[2], bf16x8 zfl[2]) {
#pragma unroll
    for (int ks = 0; ks < 2; ++ks)
#pragma unroll
        for (int j = 0; j < 8; ++j) {
            float v = zp[(size_t)(ks * 32 + q * 8 + j) * NN + px];
            u16 h, l; split_bf(v, h, l);
            zfh[ks][j] = (short)h;
            zfl[ks][j] = (short)l;
        }
}

__device__ __forceinline__ void init_bias(const float* __restrict__ Bb, f32x4* acc, int lane) {
    int q = lane >> 4;
#pragma unroll
    for (int ot = 0; ot < 4; ++ot)
#pragma unroll
        for (int j = 0; j < 4; ++j)
            acc[ot][j] = Bb[ot * 16 + q * 4 + j];
}

// f1 L1 (3-term: z split exact, W split): D[o][px] += W[o][k] * z[px][k]
__device__ __forceinline__ void mfma_L1_64(bf16x8 zfh[2], bf16x8 zfl[2],
                                           const u16* wh, const u16* wl,
                                           f32x4* acc, int lane) {
    int q = lane >> 4, l = lane & 15;
#pragma unroll
    for (int ks = 0; ks < 2; ++ks) {
        int k0 = ks * 32 + q * 8;
#pragma unroll
        for (int ot = 0; ot < 4; ++ot) {
            bf16x8 ahi = wfrag64(wh, ot * 16 + l, k0);
            bf16x8 alo = wfrag64(wl, ot * 16 + l, k0);
            acc[ot] = __builtin_amdgcn_mfma_f32_16x16x32_bf16(ahi, zfh[ks], acc[ot], 0, 0, 0);
            acc[ot] = __builtin_amdgcn_mfma_f32_16x16x32_bf16(ahi, zfl[ks], acc[ot], 0, 0, 0);
            acc[ot] = __builtin_amdgcn_mfma_f32_16x16x32_bf16(alo, zfh[ks], acc[ot], 0, 0, 0);
        }
    }
}
// f2 L1, W split (3-term), K-half of [64][128]
__device__ __forceinline__ void mfma_L1_128(bf16x8 zfh[2], bf16x8 zfl[2],
                                            const u16* wh, const u16* wl, int ak0,
                                            f32x4* acc, int lane) {
    int q = lane >> 4, l = lane & 15;
#pragma unroll
    for (int ks = 0; ks < 2; ++ks) {
        int k0 = ks * 32 + q * 8;
#pragma unroll
        for (int ot = 0; ot < 4; ++ot) {
            bf16x8 ahi = wfrag128(wh, ot * 16 + l, ak0 + k0);
            bf16x8 alo = wfrag128(wl, ot * 16 + l, ak0 + k0);
            acc[ot] = __builtin_amdgcn_mfma_f32_16x16x32_bf16(ahi, zfh[ks], acc[ot], 0, 0, 0);
            acc[ot] = __builtin_amdgcn_mfma_f32_16x16x32_bf16(ahi, zfl[ks], acc[ot], 0, 0, 0);
            acc[ot] = __builtin_amdgcn_mfma_f32_16x16x32_bf16(alo, zfh[ks], acc[ot], 0, 0, 0);
        }
    }
}

// f1 L2 (2-term: h bf16 exact, W split): h from swizzled stride-64 hbuf
__device__ __forceinline__ void layer_h2(const u16* hbuf,
                                         const u16* wh, const u16* wl,
                                         f32x4* acc, int wv, int lane) {
    int q = lane >> 4, l = lane & 15;
#pragma unroll
    for (int ks = 0; ks < 2; ++ks) {
        int k0 = ks * 32 + q * 8;
        bf16x8 b = wfrag64(hbuf, wv * 16 + l, k0);
#pragma unroll
        for (int ot = 0; ot < 4; ++ot) {
            bf16x8 ahi = wfrag64(wh, ot * 16 + l, k0);
            bf16x8 alo = wfrag64(wl, ot * 16 + l, k0);
            acc[ot] = __builtin_amdgcn_mfma_f32_16x16x32_bf16(ahi, b, acc[ot], 0, 0, 0);
            acc[ot] = __builtin_amdgcn_mfma_f32_16x16x32_bf16(alo, b, acc[ot], 0, 0, 0);
        }
    }
}
// f2 mult half (2-term), K-offset 64 of [64][128]
__device__ __forceinline__ void layer_m2_128(const u16* mb,
                                             const u16* wh, const u16* wl,
                                             f32x4* acc, int wv, int lane) {
    int q = lane >> 4, l = lane & 15;
#pragma unroll
    for (int ks = 0; ks < 2; ++ks) {
        int k0 = ks * 32 + q * 8;
        bf16x8 b = wfrag64(mb, wv * 16 + l, k0);
#pragma unroll
        for (int ot = 0; ot < 4; ++ot) {
            bf16x8 ahi = wfrag128(wh, ot * 16 + l, 64 + k0);
            bf16x8 alo = wfrag128(wl, ot * 16 + l, 64 + k0);
            acc[ot] = __builtin_amdgcn_mfma_f32_16x16x32_bf16(ahi, b, acc[ot], 0, 0, 0);
            acc[ot] = __builtin_amdgcn_mfma_f32_16x16x32_bf16(alo, b, acc[ot], 0, 0, 0);
        }
    }
}
// f2_rb0 mult (2-term, W split [64][64])
__device__ __forceinline__ void layer_m2_64(const u16* mb,
                                            const u16* wh, const u16* wl,
                                            f32x4* acc, int wv, int lane) {
    int q = lane >> 4, l = lane & 15;
#pragma unroll
    for (int ks = 0; ks < 2; ++ks) {
        int k0 = ks * 32 + q * 8;
        bf16x8 b = wfrag64(mb, wv * 16 + l, k0);
#pragma unroll
        for (int ot = 0; ot < 4; ++ot) {
            bf16x8 ahi = wfrag64(wh, ot * 16 + l, k0);
            bf16x8 alo = wfrag64(wl, ot * 16 + l, k0);
            acc[ot] = __builtin_amdgcn_mfma_f32_16x16x32_bf16(ahi, b, acc[ot], 0, 0, 0);
            acc[ot] = __builtin_amdgcn_mfma_f32_16x16x32_bf16(alo, b, acc[ot], 0, 0, 0);
        }
    }
}

// write h = relu(acc) as plain bf16 to SWIZZLED stride-64 own-band rows [px][o]
__device__ __forceinline__ void write_h_bf16(f32x4* acc, u16* hbuf, int wv, int lane) {
    int q = lane >> 4, l = lane & 15;
    int px = wv * 16 + l;
#pragma unroll
    for (int ot = 0; ot < 4; ++ot) {
#pragma unroll
        for (int jp = 0; jp < 2; ++jp) {
            int o = ot * 16 + q * 4 + jp * 2;
            int gaddr = px * 64 + (((o >> 3) ^ (px & 7)) << 3) + (o & 7);
            float v0 = acc[ot][jp * 2];     v0 = v0 > 0.f ? v0 : 0.f;
            float v1 = acc[ot][jp * 2 + 1]; v1 = v1 > 0.f ? v1 : 0.f;
            *(u32t*)&hbuf[gaddr] = (u32t)f2bs(v0) | ((u32t)f2bs(v1) << 16);
        }
    }
}

// store relu(acc) (D[o][px]) as plain bf16 to u16 NCHW plane set
__device__ __forceinline__ void write_m_bf16(f32x4* acc, u16* __restrict__ mh,
                                             int p0, int wv, int lane) {
    int q = lane >> 4, l = lane & 15;
    int px = p0 + wv * 16 + l;
#pragma unroll
    for (int ot = 0; ot < 4; ++ot)
#pragma unroll
        for (int j = 0; j < 4; ++j) {
            int o = ot * 16 + q * 4 + j;
            float v = acc[ot][j]; v = v > 0.f ? v : 0.f;
            mh[(size_t)o * NN + px] = f2bs(v);
        }
}

__device__ __forceinline__ void write_m_lin(f32x4* acc, float* mout,
                                            int p0, int wv, int lane) {
    int q = lane >> 4, l = lane & 15;
    int px = p0 + wv * 16 + l;
#pragma unroll
    for (int ot = 0; ot < 4; ++ot)
#pragma unroll
        for (int j = 0; j < 4; ++j) {
            int o = ot * 16 + q * 4 + j;
            mout[(size_t)o * NN + px] = acc[ot][j];
        }
}

// f1 phase body (shared by fused kernels): new-z frags from global (L2-hot) -> m1,m2
__device__ __forceinline__ void f1_phase(const float* zp, size_t gofs, int p0,
                                         const u16* Wbh, const u16* Wbl,
                                         const float* B1a, const float* B2a,
                                         const float* B1b, const float* B2b,
                                         u16* m1, u16* m2,
                                         u16* wsA, u16* wsB, u16* mbuf,
                                         int t, int lane, int wv, int q, int l15) {
    bf16x8 zfh[2], zfl[2];
    zfrags_nchw(zp, p0 + wv * 16 + l15, q, zfh, zfl);
    stage_w64_512(Wbh, Wbl, wsA, wsA + 4096, t);            // W1A
    stage_w64_512(Wbh + 4096, Wbl + 4096, wsB, wsB + 4096, t); // W2A
    __syncthreads();

    f32x4 acc[4];
    init_bias(B1a, acc, lane);
    mfma_L1_64(zfh, zfl, wsA, wsA + 4096, acc, lane);
    write_h_bf16(acc, mbuf, wv, lane);
    init_bias(B2a, acc, lane);
    layer_h2(mbuf, wsB, wsB + 4096, acc, wv, lane);
    write_m_bf16(acc, m1 + gofs, p0, wv, lane);

    __syncthreads();
    stage_w64_512(Wbh + 8192, Wbl + 8192, wsA, wsA + 4096, t);     // W1B
    stage_w64_512(Wbh + 12288, Wbl + 12288, wsB, wsB + 4096, t);   // W2B
    __syncthreads();

    init_bias(B1b, acc, lane);
    mfma_L1_64(zfh, zfl, wsA, wsA + 4096, acc, lane);
    write_h_bf16(acc, mbuf, wv, lane);
    init_bias(B2b, acc, lane);
    layer_h2(mbuf, wsB, wsB + 4096, acc, wv, lane);
    write_m_bf16(acc, m2 + gofs, p0, wv, lane);
}

// ---------------- f1 rb0: adj -> m1,m2 (bf16); 512 thr, 128 px/WG; 1 barrier ----------------
__global__ __launch_bounds__(512, 3) void f1_rb0(
    const float* __restrict__ adj, int b_base,
    const float* __restrict__ w1a, const float* __restrict__ b1a,
    const float* __restrict__ w1b, const float* __restrict__ b1b,
    const u16* __restrict__ wsh, const u16* __restrict__ wsl,
    const float* __restrict__ B2a, const float* __restrict__ B2b,
    u16* __restrict__ m1, u16* __restrict__ m2) {
    __shared__ u16 w1h[4096], w1l[4096], w2h[4096], w2l[4096];
    __shared__ u16 hbuf[8192];
    int bb = blockIdx.y, p0 = blockIdx.x * 128;
    int t = threadIdx.x, lane = t & 63, wv = t >> 6;
    int q = lane >> 4, l15 = lane & 15;
    size_t gofs = (size_t)bb * EMB * NN;
    int pxl = wv * 16 + l15;
    float a = adj[(size_t)(b_base + bb) * NN + p0 + pxl];

    stage_w64_512(wsh + RB0_W2A, wsl + RB0_W2A, w1h, w1l, t);
    stage_w64_512(wsh + RB0_W2B, wsl + RB0_W2B, w2h, w2l, t);
#pragma unroll
    for (int it = 0; it < 8; ++it) {
        int o0 = it * 8 + q * 2;
        int gaddr = pxl * 64 + ((it ^ (pxl & 7)) << 3) + q * 2;
        float v0 = w1a[o0 * 2] * a + b1a[o0];             v0 = v0 > 0.f ? v0 : 0.f;
        float v1 = w1a[(o0 + 1) * 2] * a + b1a[o0 + 1];   v1 = v1 > 0.f ? v1 : 0.f;
        *(u32t*)&hbuf[gaddr] = (u32t)f2bs(v0) | ((u32t)f2bs(v1) << 16);
    }
    __syncthreads();

    f32x4 acc[4];
    init_bias(B2a, acc, lane);
    layer_h2(hbuf, w1h, w1l, acc, wv, lane);
    write_m_bf16(acc, m1 + gofs, p0, wv, lane);

#pragma unroll
    for (int it = 0; it < 8; ++it) {
        int o0 = it * 8 + q * 2;
        int gaddr = pxl * 64 + ((it ^ (pxl & 7)) << 3) + q * 2;
        float v0 = w1b[o0 * 2] * a + b1b[o0];             v0 = v0 > 0.f ? v0 : 0.f;
        float v1 = w1b[(o0 + 1) * 2] * a + b1b[o0 + 1];   v1 = v1 > 0.f ? v1 : 0.f;
        *(u32t*)&hbuf[gaddr] = (u32t)f2bs(v0) | ((u32t)f2bs(v1) << 16);
    }
    init_bias(B2b, acc, lane);
    layer_h2(hbuf, w2h, w2l, acc, wv, lane);
    write_m_bf16(acc, m2 + gofs, p0, wv, lane);
}

// ---------------- per-channel NxN matmul: 128x128 tile, 16 MFMA/barrier-pair ----------------
__device__ __forceinline__ int soff(int row, int g) {
    return row * 64 + ((g ^ (row & 7) ^ ((row >> 3) & 7)) << 3);
}

__global__ __launch_bounds__(512) void chanmm_mfma(
    const u16* __restrict__ m1, const u16* __restrict__ m2,
    u16* __restrict__ mult) {
    __shared__ u16 Ah[128 * 64];    // 16 KB: A rows itile..+127, one 64-K slab
    __shared__ u16 Bh[128 * 64];    // 16 KB: B cols jtile..+127 stored [j][k]
    int t = threadIdx.x, lane = t & 63, wv = t >> 6;
    int l15 = lane & 15, q = lane >> 4;
    int wi = wv >> 2, wj = wv & 3;            // 2x4 wave grid; wave tile 64x32
    int tile = blockIdx.x;                    // 0..3
    int itile = (tile >> 1) * 128, jtile = (tile & 1) * 128;
    int ch = blockIdx.y, bb = blockIdx.z;
    size_t pb = ((size_t)bb * EMB + ch) * NN;
    const u16* A_h = m1 + pb;
    const u16* B_h = m2 + pb;

    int a_i = t >> 3;          // 0..63
    int a_g = t & 7;
    int b_k = t >> 3;          // 0..63
    int b_j8 = (t & 7) * 8;    // 0..56

    int4 rAh0, rAh1, rBh0, rBh1;
#define LOADK(K0)                                                              \
    {                                                                          \
        int k0_ = (K0);                                                        \
        rAh0 = *(const int4*)&A_h[(itile + a_i) * N + k0_ + a_g * 8];          \
        rAh1 = *(const int4*)&A_h[(itile + 64 + a_i) * N + k0_ + a_g * 8];     \
        rBh0 = *(const int4*)&B_h[(k0_ + b_k) * N + jtile + b_j8];             \
        rBh1 = *(const int4*)&B_h[(k0_ + b_k) * N + jtile + 64 + b_j8];        \
    }

    f32x4 acc[4][2] = {};
    LOADK(0);
#pragma unroll
    for (int s = 0; s < 4; ++s) {
        *(int4*)&Ah[soff(a_i, a_g)] = rAh0;
        *(int4*)&Ah[soff(a_i + 64, a_g)] = rAh1;
        {
            const u16* p0 = (const u16*)&rBh0;
            const u16* p1 = (const u16*)&rBh1;
            int G = b_k >> 3, kin = b_k & 7;
#pragma unroll
            for (int d = 0; d < 8; ++d) {
                Bh[soff(b_j8 + d, G) + kin] = p0[d];
                Bh[soff(64 + b_j8 + d, G) + kin] = p1[d];
            }
        }
        __syncthreads();
        if (s < 3) LOADK((s + 1) * 64);
#pragma unroll
        for (int ks = 0; ks < 2; ++ks) {
            int g = ks * 4 + q;
            bf16x8 bhi[2];
#pragma unroll
            for (int jt = 0; jt < 2; ++jt) {
                int rj = wj * 32 + jt * 16 + l15;
                bhi[jt] = *(const bf16x8*)&Bh[soff(rj, g)];
            }
#pragma unroll
            for (int it = 0; it < 4; ++it) {
                int ri = wi * 64 + it * 16 + l15;
                bf16x8 ahi = *(const bf16x8*)&Ah[soff(ri, g)];
#pragma unroll
                for (int jt = 0; jt < 2; ++jt)
                    acc[it][jt] = __builtin_amdgcn_mfma_f32_16x16x32_bf16(ahi, bhi[jt], acc[it][jt], 0, 0, 0);
            }
        }
        __syncthreads();
    }
#undef LOADK
    u16* O = mult + pb;
#pragma unroll
    for (int it = 0; it < 4; ++it)
#pragma unroll
        for (int jt = 0; jt < 2; ++jt)
#pragma unroll
            for (int r = 0; r < 4; ++r) {
                int i = itile + wi * 64 + it * 16 + q * 4 + r;
                int j = jtile + wj * 32 + jt * 16 + l15;
                O[(size_t)i * N + j] = f2bs(acc[it][jt][r]);
            }
}

// ---------------- FUSED: f2_reg(blk2) -> z, then f1_reg(blk1) reading L2-hot z ----------------
__global__ __launch_bounds__(512, 3) void f2f1(
    const u16* __restrict__ mult,   // NCHW bf16
    const u16* __restrict__ wsh, const u16* __restrict__ wsl,
    int blk2, const float* __restrict__ SB2,
    float* z,
    int blk1,
    const float* __restrict__ B1a, const float* __restrict__ B2a,
    const float* __restrict__ B1b, const float* __restrict__ B2b,
    u16* __restrict__ m1, u16* __restrict__ m2) {
    __shared__ u16 wsA[8192], wsB[8192];   // 32 KB
    __shared__ u16 mbuf[8192];             // 16 KB -> 48 KB total
    int bb = blockIdx.y, p0 = blockIdx.x * 128;
    int t = threadIdx.x, lane = t & 63, wv = t >> 6;
    int q = lane >> 4, l15 = lane & 15;
    size_t gofs = (size_t)bb * EMB * NN;
    const u16* mp = mult + gofs;
    float* zp = z + gofs;
    const u16* SWh = wsh + REG_BASE + blk2 * REG_STRIDE + 16384;
    const u16* SWl = wsl + REG_BASE + blk2 * REG_STRIDE + 16384;
    const u16* Wbh = wsh + REG_BASE + blk1 * REG_STRIDE;
    const u16* Wbl = wsl + REG_BASE + blk1 * REG_STRIDE;

    // ---- f2 phase ----
    {
        bf16x8 zfh[2], zfl[2];
        zfrags_nchw(zp, p0 + wv * 16 + l15, q, zfh, zfl);   // OLD z (read before overwrite)
        stage_w128s_512(SWh, SWl, wsA, wsB, t);
        stage_band_m(mp, p0, mbuf, wv, lane);
        __syncthreads();

        f32x4 acc[4];
        init_bias(SB2, acc, lane);
        mfma_L1_128(zfh, zfl, wsA, wsB, 0, acc, lane);
        layer_m2_128(mbuf, wsA, wsB, acc, wv, lane);
        write_m_lin(acc, zp, p0, wv, lane);                 // NEW z to global
    }
    __syncthreads();   // drains vmcnt: WG's z writes L2-visible; LDS free

    // ---- f1 phase (blk1), z re-read is L2-hot ----
    f1_phase(zp, gofs, p0, Wbh, Wbl, B1a, B2a, B1b, B2b, m1, m2,
             wsA, wsB, mbuf, t, lane, wv, q, l15);
}

// ---------------- FUSED: f2_rb0 -> z, then f1_reg(blk 0) ----------------
__global__ __launch_bounds__(512, 3) void f2rb0_f1(
    const float* __restrict__ adj, int b_base,
    const u16* __restrict__ mult,   // NCHW bf16
    const u16* __restrict__ wsh, const u16* __restrict__ wsl,
    const float* __restrict__ SWf, const float* __restrict__ SB2,
    float* z,
    const float* __restrict__ B1a, const float* __restrict__ B2a,
    const float* __restrict__ B1b, const float* __restrict__ B2b,
    u16* __restrict__ m1, u16* __restrict__ m2) {
    __shared__ u16 wsA[8192], wsB[8192];
    __shared__ u16 mbuf[8192];
    int bb = blockIdx.y, p0 = blockIdx.x * 128;
    int t = threadIdx.x, lane = t & 63, wv = t >> 6;
    int q = lane >> 4, l15 = lane & 15;
    size_t gofs = (size_t)bb * EMB * NN;
    const u16* mp = mult + gofs;
    float* zp = z + gofs;
    const u16* Wbh = wsh + REG_BASE;   // blk1 = 0
    const u16* Wbl = wsl + REG_BASE;

    // ---- f2_rb0 phase ----
    {
        stage_w64_512(wsh + RB0_SW, wsl + RB0_SW, wsA, wsA + 4096, t);
        stage_band_m(mp, p0, mbuf, wv, lane);
        __syncthreads();

        float a = adj[(size_t)(b_base + bb) * NN + p0 + wv * 16 + l15];
        f32x4 acc[4];
#pragma unroll
        for (int ot = 0; ot < 4; ++ot)
#pragma unroll
            for (int j = 0; j < 4; ++j) {
                int o = ot * 16 + q * 4 + j;
                acc[ot][j] = SB2[o] + SWf[o * 66] * a;
            }
        layer_m2_64(mbuf, wsA, wsA + 4096, acc, wv, lane);
        write_m_lin(acc, zp, p0, wv, lane);
    }
    __syncthreads();

    // ---- f1 phase (blk 0) ----
    f1_phase(zp, gofs, p0, Wbh, Wbl, B1a, B2a, B1b, B2b, m1, m2,
             wsA, wsB, mbuf, t, lane, wv, q, l15);
}

// ---------------- standalone f2 (last block): skip conv -> z ----------------
__global__ __launch_bounds__(512, 3) void f2_reg(
    const u16* __restrict__ mult,   // NCHW bf16
    const u16* __restrict__ wsh, const u16* __restrict__ wsl, int blk,
    const float* __restrict__ SB,
    float* __restrict__ z) {
    __shared__ u16 wh[8192], wl[8192];
    __shared__ u16 mb[8192];
    int bb = blockIdx.y, p0 = blockIdx.x * 128;
    int t = threadIdx.x, lane = t & 63, wv = t >> 6;
    int q = lane >> 4, l15 = lane & 15;
    const u16* mp = mult + (size_t)bb * EMB * NN;
    float* zp = z + (size_t)bb * EMB * NN;
    const u16* SWh = wsh + REG_BASE + blk * REG_STRIDE + 16384;
    const u16* SWl = wsl + REG_BASE + blk * REG_STRIDE + 16384;

    bf16x8 zfh[2], zfl[2];
    zfrags_nchw(zp, p0 + wv * 16 + l15, q, zfh, zfl);

    stage_w128s_512(SWh, SWl, wh, wl, t);
    stage_band_m(mp, p0, mb, wv, lane);
    __syncthreads();

    f32x4 acc[4];
    init_bias(SB, acc, lane);
    mfma_L1_128(zfh, zfl, wh, wl, 0, acc, lane);
    layer_m2_128(mb, wh, wl, acc, wv, lane);
    write_m_lin(acc, zp, p0, wv, lane);
}

// ---------------- pooling partials (float4 loads, branch-free diag) ----------------
__global__ void pool(const float* __restrict__ z, float* __restrict__ sums, int b_base) {
    int bb = blockIdx.x;
    int c = blockIdx.y;
    size_t base = ((size_t)bb * EMB + c) * NN;
    const float4* z4 = (const float4*)(z + base);
    int t = threadIdx.x;
    float s = 0.0f;
#pragma unroll 4
    for (int it = 0; it < 64; ++it) {
        float4 v = z4[it * 256 + t];
        s += v.x + v.y + v.z + v.w;
    }
    float d = z[base + (size_t)t * 257];
    for (int off = 32; off > 0; off >>= 1) {
        s += __shfl_down(s, off);
        d += __shfl_down(d, off);
    }
    __shared__ float ls[4], ld[4];
    int wid = t >> 6;
    if ((t & 63) == 0) { ls[wid] = s; ld[wid] = d; }
    __syncthreads();
    if (t == 0) {
        s = ls[0] + ls[1] + ls[2] + ls[3];
        d = ld[0] + ld[1] + ld[2] + ld[3];
        int b = b_base + bb;
        sums[b * EMB + c] = s;
        sums[BATCH * EMB + b * EMB + c] = d;
    }
}

// ---------------- final pooled FC ----------------
__global__ void fc(const float* __restrict__ sums,
                   const float* __restrict__ fcw1, const float* __restrict__ fcb1,
                   const float* __restrict__ fcw2, const float* __restrict__ fcb2,
                   float* __restrict__ out) {
    int b = blockIdx.x;
    __shared__ float h[128];
    __shared__ float hh2[64];
    int t = threadIdx.x;
    if (t < 64) {
        h[t] = sums[BATCH * EMB + b * EMB + t] / (float)N;
    } else {
        int c = t - 64;
        float sall = sums[b * EMB + c];
        float sd = sums[BATCH * EMB + b * EMB + c];
        h[t] = (sall - sd) / (float)(N * (N - 1));
    }
    __syncthreads();
    if (t < 64) {
        float acc = fcb1[t];
        for (int k = 0; k < 128; ++k) acc += fcw1[t * 128 + k] * h[k];
        hh2[t] = acc > 0.0f ? acc : 0.0f;
    }
    __syncthreads();
    if (t == 0) {
        float acc = fcb2[0];
        for (int k = 0; k < 64; ++k) acc += fcw2[k] * hh2[k];
        out[b] = acc;
    }
}

extern "C" void kernel_launch(void* const* d_in, const int* in_sizes, int n_in,
                              void* d_out, int out_size, void* d_ws, size_t ws_size,
                              hipStream_t stream) {
    const int* ei       = (const int*)d_in[0];
    const int* batchv   = (const int*)d_in[1];
    const float* rb0_m1w1 = (const float*)d_in[2];
    const float* rb0_m1b1 = (const float*)d_in[3];
    const float* rb0_m1w2 = (const float*)d_in[4];
    const float* rb0_m1b2 = (const float*)d_in[5];
    const float* rb0_m2w1 = (const float*)d_in[6];
    const float* rb0_m2b1 = (const float*)d_in[7];
    const float* rb0_m2w2 = (const float*)d_in[8];
    const float* rb0_m2b2 = (const float*)d_in[9];
    const float* rb0_sw   = (const float*)d_in[10];
    const float* rb0_sb   = (const float*)d_in[11];
    const float* rb_m1w1  = (const float*)d_in[12];
    const float* rb_m1b1  = (const float*)d_in[13];
    const float* rb_m1w2  = (const float*)d_in[14];
    const float* rb_m1b2  = (const float*)d_in[15];
    const float* rb_m2w1  = (const float*)d_in[16];
    const float* rb_m2b1  = (const float*)d_in[17];
    const float* rb_m2w2  = (const float*)d_in[18];
    const float* rb_m2b2  = (const float*)d_in[19];
    const float* rb_sw    = (const float*)d_in[20];
    const float* rb_sb    = (const float*)d_in[21];
    const float* fcw1     = (const float*)d_in[22];
    const float* fcb1     = (const float*)d_in[23];
    const float* fcw2     = (const float*)d_in[24];
    const float* fcb2     = (const float*)d_in[25];

    const size_t P = (size_t)EMB * NN;               // 4,194,304 elems
    const size_t WB = (size_t)WSPLIT_ELEMS * 2ull;
    const size_t fixedBytes = 524288ull * 4ull + 4096ull + 2ull * WB;
    const size_t perGraphBytes = 2ull * P * 2ull + P * 2ull + P * 4ull;
    int g = BATCH;
    while (g > 1) {
        if (fixedBytes + (size_t)g * perGraphBytes <= ws_size) break;
        g >>= 1;
    }

    char* w = (char*)d_ws;
    float* adj   = (float*)w;  w += 524288ull * 4ull;
    float* sums  = (float*)w;  w += 4096;
    u16* wsh     = (u16*)w;    w += WB;
    u16* wsl     = (u16*)w;    w += WB;
    u16* m1      = (u16*)w;    w += (size_t)g * P * 2ull;
    u16* m2      = (u16*)w;    w += (size_t)g * P * 2ull;
    u16* mult    = (u16*)w;    w += (size_t)g * P * 2ull;
    float* znchw = (float*)w;  w += (size_t)g * P * 4ull;

    hipMemsetAsync(adj, 0, 524288ull * 4ull, stream);
    scatter_adj<<<NEDGE / 256, 256, 0, stream>>>(ei, batchv, adj);
    prep_w<<<(WSPLIT_ELEMS + 255) / 256, 256, 0, stream>>>(
        rb0_m1w2, rb0_m2w2, rb0_sw, rb_m1w1, rb_m1w2, rb_m2w1, rb_m2w2, rb_sw, wsh, wsl);

    for (int b_base = 0; b_base < BATCH; b_base += g) {
        dim3 gridF(NN / 128, g);
        dim3 gridM(4, EMB, g);

        f1_rb0<<<gridF, 512, 0, stream>>>(adj, b_base,
            rb0_m1w1, rb0_m1b1, rb0_m2w1, rb0_m2b1,
            wsh, wsl, rb0_m1b2, rb0_m2b2, m1, m2);
        chanmm_mfma<<<gridM, 512, 0, stream>>>(m1, m2, mult);

        // fused: f2_rb0 -> z, then f1(block 0)
        f2rb0_f1<<<gridF, 512, 0, stream>>>(adj, b_base, mult, wsh, wsl,
            rb0_sw, rb0_sb, znchw,
            rb_m1b1, rb_m1b2, rb_m2b1, rb_m2b2, m1, m2);
        chanmm_mfma<<<gridM, 512, 0, stream>>>(m1, m2, mult);

        // fused: f2(block 0) -> z, then f1(block 1)
        f2f1<<<gridF, 512, 0, stream>>>(mult, wsh, wsl, 0, rb_sb, znchw, 1,
            rb_m1b1 + 64, rb_m1b2 + 64, rb_m2b1 + 64, rb_m2b2 + 64, m1, m2);
        chanmm_mfma<<<gridM, 512, 0, stream>>>(m1, m2, mult);

        // fused: f2(block 1) -> z, then f1(block 2)
        f2f1<<<gridF, 512, 0, stream>>>(mult, wsh, wsl, 1, rb_sb + 64, znchw, 2,
            rb_m1b1 + 128, rb_m1b2 + 128, rb_m2b1 + 128, rb_m2b2 + 128, m1, m2);
        chanmm_mfma<<<gridM, 512, 0, stream>>>(m1, m2, mult);

        // last skip conv (block 2) standalone
        f2_reg<<<gridF, 512, 0, stream>>>(mult, wsh, wsl, 2, rb_sb + 128, znchw);

        pool<<<dim3(g, EMB), 256, 0, stream>>>(znchw, sums, b_base);
    }
    fc<<<BATCH, 128, 0, stream>>>(sums, fcw1, fcb1, fcw2, fcb2, (float*)d_out);
}